// Round 5
// baseline (1651.445 us; speedup 1.0000x reference)
//
#include <hip/hip_runtime.h>
#include <math.h>

// Decoder forward, MI355X gfx950. Round 4: fix k_gemmH A-staging to be
// lane-linear (global_load_lds writes wave-uniform base + lane*16 — m104);
// source-side swizzle per-lane; sched_barrier pins A-before-B issue order.
//
// Dims (fixed): V=32000 D=1024 DEPTH=4 H=16 DH=64 FF=4096 B=1 N=2048

#define NSEQ 2048
#define DMODEL 1024
#define NH 16
#define DHEAD 64
#define FFD 4096
#define VOC 32000
#define NLAYER 4

typedef unsigned short u16;
typedef short bf16x8 __attribute__((ext_vector_type(8)));   // 8 bf16 in 4 VGPRs
typedef float f32x4 __attribute__((ext_vector_type(4)));

__device__ __forceinline__ u16 f2bf(float f) {
  unsigned int u = __builtin_bit_cast(unsigned int, f);
  u += 0x7fffu + ((u >> 16) & 1u);   // RNE
  return (u16)(u >> 16);
}

__device__ __forceinline__ void gload16(const void* g, void* l) {
  __builtin_amdgcn_global_load_lds((__attribute__((address_space(1))) void*)g,
                                   (__attribute__((address_space(3))) void*)l,
                                   16, 0, 0);
}

__device__ __forceinline__ f32x4 mfma16x32(bf16x8 a, bf16x8 b, f32x4 c) {
  return __builtin_amdgcn_mfma_f32_16x16x32_bf16(a, b, c, 0, 0, 0);
}

// ---------------------------------------------------------------- prep kernels

__global__ __launch_bounds__(256) void k_embed(const int* __restrict__ x,
                                               const float* __restrict__ emb,
                                               float* __restrict__ h) {
  const int n = blockIdx.x, t = threadIdx.x;
  const int tok = x[n];
  reinterpret_cast<float4*>(h + (size_t)n * DMODEL)[t] =
      reinterpret_cast<const float4*>(emb + (size_t)tok * DMODEL)[t];
}

__global__ void k_rope(float* __restrict__ ct, float* __restrict__ st) {
  const int n = blockIdx.x, p = threadIdx.x;  // 32 freq pairs
  const double inv = exp(-(double)(2 * p) / 64.0 * log(10000.0));
  const double a = (double)n * inv;
  ct[n * 32 + p] = (float)cos(a);
  st[n * 32 + p] = (float)sin(a);
}

// f32 [K][Nc] -> bf16. TILED=false: [Nc][K] row-major. TILED=true: MFMA-native
// B-tile layout [Nc/16][K/32][64 lanes][8 elems]: elem(n,k) at
// ((n>>4)*(K>>5)+(k>>5))*512 + ((n&15)+((k>>3)&3)*16)*8 + (k&7).
template <bool TILED>
__global__ __launch_bounds__(256) void k_transpose(const float* __restrict__ in0,
                                                   u16* __restrict__ out0,
                                                   int K, int Nc,
                                                   size_t ls_in, size_t ls_out) {
  const float* in = in0 + blockIdx.z * ls_in;
  u16* out = out0 + blockIdx.z * ls_out;
  __shared__ float tile[64][65];
  const int kb = blockIdx.x * 64, nb = blockIdx.y * 64;
  const int tr = threadIdx.x >> 4;       // 0..15
  const int tc = threadIdx.x & 15;       // 0..15
#pragma unroll
  for (int r = 0; r < 64; r += 16) {
    const float4 v = *reinterpret_cast<const float4*>(
        &in[(size_t)(kb + r + tr) * Nc + nb + tc * 4]);
    tile[r + tr][tc * 4 + 0] = v.x;
    tile[r + tr][tc * 4 + 1] = v.y;
    tile[r + tr][tc * 4 + 2] = v.z;
    tile[r + tr][tc * 4 + 3] = v.w;
  }
  __syncthreads();
#pragma unroll
  for (int r = 0; r < 64; r += 16) {
    const int n = r + tr;
    ushort4 o;
    o.x = f2bf(tile[tc * 4 + 0][n]);
    o.y = f2bf(tile[tc * 4 + 1][n]);
    o.z = f2bf(tile[tc * 4 + 2][n]);
    o.w = f2bf(tile[tc * 4 + 3][n]);
    if (TILED) {
      const int ng = nb + n, kg = kb + tc * 4;
      const size_t off = ((size_t)(ng >> 4) * (K >> 5) + (kg >> 5)) * 512 +
                         ((ng & 15) + ((kg >> 3) & 3) * 16) * 8 + (kg & 7);
      *reinterpret_cast<ushort4*>(&out[off]) = o;
    } else {
      *reinterpret_cast<ushort4*>(&out[(size_t)(nb + n) * K + kb + tc * 4]) = o;
    }
  }
}

// rms_norm(h)*gamma -> bf16 (GEMM A input). One row per block (256 thr, float4).
__global__ __launch_bounds__(256) void k_rmsnorm(const float* __restrict__ h,
                                                 const float* __restrict__ gamma,
                                                 u16* __restrict__ out) {
  __shared__ float red[4];
  const int n = blockIdx.x, t = threadIdx.x;
  const float4 v = reinterpret_cast<const float4*>(h + (size_t)n * DMODEL)[t];
  float ss = v.x * v.x + v.y * v.y + v.z * v.z + v.w * v.w;
#pragma unroll
  for (int off = 32; off; off >>= 1) ss += __shfl_down(ss, off);
  if ((t & 63) == 0) red[t >> 6] = ss;
  __syncthreads();
  const float tot = red[0] + red[1] + red[2] + red[3];
  const float inv = 32.0f / fmaxf(sqrtf(tot), 1e-12f);  // sqrt(1024)=32
  const float4 g = reinterpret_cast<const float4*>(gamma)[t];
  ushort4 o;
  o.x = f2bf(v.x * inv * g.x);
  o.y = f2bf(v.y * inv * g.y);
  o.z = f2bf(v.z * inv * g.z);
  o.w = f2bf(v.w * inv * g.w);
  reinterpret_cast<ushort4*>(out + (size_t)n * DMODEL)[t] = o;
}

// qkv f32 [N][3072] -> roped Q,K bf16 [H][N][64], V^T bf16 [H][64][N]
__global__ __launch_bounds__(256) void k_qkv_post(const float* __restrict__ qkv,
                                                  const float* __restrict__ ct,
                                                  const float* __restrict__ st,
                                                  u16* __restrict__ Qr,
                                                  u16* __restrict__ Kr,
                                                  u16* __restrict__ VT) {
  const int n = blockIdx.x;
  const int hh = blockIdx.y * 4 + (threadIdx.x >> 6);
  const int d = threadIdx.x & 63;  // == lane
  const float* base = qkv + (size_t)n * 3072 + hh * DHEAD + d;
  const float q = base[0], k = base[DMODEL], v = base[2 * DMODEL];
  const int p = d >> 1;
  const float c = ct[n * 32 + p], s = st[n * 32 + p];
  const float qp = __shfl_xor(q, 1);
  const float kp = __shfl_xor(k, 1);
  const float sgn = (d & 1) ? 1.0f : -1.0f;
  Qr[((size_t)hh * NSEQ + n) * DHEAD + d] = f2bf(q * c + sgn * qp * s);
  Kr[((size_t)hh * NSEQ + n) * DHEAD + d] = f2bf(k * c + sgn * kp * s);
  VT[((size_t)hh * DHEAD + d) * NSEQ + n] = f2bf(v);
}

// ---------------------------------------------------------------- GEMM epilogues
#define EPI_STORE 0
#define EPI_ADD 1
#define EPI_GELU 2
#define EPI_BIAS_ADD 3

// ---------------- 128x128 m97-structure GEMM (N=1024 shapes: attn_out, ff2) ---
// LDS rows = 32 bf16 = 64 B = 4 slots; 2-bit XOR swizzle (slot ^= row&3).
// Staging dest = tid*16 (lane-linear: gload_lds HW requirement), source slot
// pre-swizzled per-lane.
template <int EPI>
__global__ __launch_bounds__(256) void k_gemm(const u16* __restrict__ A,
                                              const u16* __restrict__ BT,
                                              int K, int Nc,
                                              const float* __restrict__ bias,
                                              const float* __restrict__ add,
                                              float* __restrict__ outf,
                                              u16* __restrict__ outb) {
  __shared__ alignas(16) u16 Asm[128 * 32];
  __shared__ alignas(16) u16 Bsm[128 * 32];
  const int tid = threadIdx.x;
  const int m0 = blockIdx.x * 128, n0 = blockIdx.y * 128;
  const int w = tid >> 6, lane = tid & 63;
  const int wr = (w >> 1) * 64, wc = (w & 1) * 64;
  const int lr = lane & 15, lg = lane >> 4;

  f32x4 acc[4][4] = {};

  const int rowA = tid >> 2;
  const int sslot = tid & 3;
  const int gslot = sslot ^ (rowA & 3);          // pre-swizzled source slot
  const int colE = gslot * 8;
  const u16* Ag0 = A + (size_t)(m0 + rowA) * K + colE;
  const u16* Ag1 = A + (size_t)(m0 + rowA + 64) * K + colE;
  const u16* Bg0 = BT + (size_t)(n0 + rowA) * K + colE;
  const u16* Bg1 = BT + (size_t)(n0 + rowA + 64) * K + colE;
  char* lA = (char*)Asm + tid * 16;              // lane-linear dest
  char* lB = (char*)Bsm + tid * 16;

  for (int kt = 0; kt < K; kt += 32) {
    __syncthreads();
    gload16(Ag0 + kt, lA);
    gload16(Ag1 + kt, lA + 4096);
    gload16(Bg0 + kt, lB);
    gload16(Bg1 + kt, lB + 4096);
    __syncthreads();
    bf16x8 af[4], bfr[4];
#pragma unroll
    for (int i = 0; i < 4; ++i) {
      const int ra = wr + i * 16 + lr, rb = wc + i * 16 + lr;
      af[i] = *reinterpret_cast<const bf16x8*>(&Asm[ra * 32 + (lg ^ (ra & 3)) * 8]);
      bfr[i] = *reinterpret_cast<const bf16x8*>(&Bsm[rb * 32 + (lg ^ (rb & 3)) * 8]);
    }
#pragma unroll
    for (int mi = 0; mi < 4; ++mi)
#pragma unroll
      for (int ni = 0; ni < 4; ++ni)
        acc[mi][ni] = mfma16x32(af[mi], bfr[ni], acc[mi][ni]);
  }

#pragma unroll
  for (int mi = 0; mi < 4; ++mi) {
#pragma unroll
    for (int ni = 0; ni < 4; ++ni) {
      const int col = n0 + wc + ni * 16 + lr;
#pragma unroll
      for (int r = 0; r < 4; ++r) {
        const int row = m0 + wr + mi * 16 + lg * 4 + r;
        const size_t idx = (size_t)row * Nc + col;
        float v = acc[mi][ni][r];
        if (EPI == EPI_GELU) {
          v += bias[col];
          v = 0.5f * v * (1.0f + erff(v * 0.70710678118654752f));
          outb[idx] = f2bf(v);
        } else if (EPI == EPI_ADD) {
          outf[idx] = v + add[idx];
        } else if (EPI == EPI_BIAS_ADD) {
          outf[idx] = v + bias[col] + add[idx];
        } else {
          outf[idx] = v;
        }
      }
    }
  }
}

// ---------------- hybrid GEMM: A via LDS (swizzled dbuf), B global->reg ------
// 128x256xBK64, 512 thr = 8 waves (2x4), wave tile 64x64. B pre-tiled
// MFMA-native: one frag = one coalesced 1KB wave-load, reg-dbuf 1 K-tile
// ahead. A staged 1 ahead via gload_lds into LDS dbuf.
// A-staging is LANE-LINEAR (m104): wave w writes rows 8w..8w+7 (1KB region,
// lane i at +i*16); 3-bit XOR swizzle applied on the per-lane GLOBAL source;
// read side applies the same involution. vmcnt(8) at tile end retires exactly
// this tile's 2 A-writes (A issued before B, pinned by sched_barrier) while
// the 8 B loads stay in flight across the barrier.
template <int EPI>
__global__ __launch_bounds__(512, 2) void k_gemmH(const u16* __restrict__ A,
                                                  const u16* __restrict__ Bt,
                                                  int K, int Nc, int NMB,
                                                  const float* __restrict__ bias,
                                                  float* __restrict__ outf,
                                                  u16* __restrict__ outb) {
  __shared__ alignas(16) u16 Asm[2][128 * 64];   // 2 x 16 KB
  const int nt = K >> 6;
  const int nwg = gridDim.x, bid = blockIdx.x;
  int swz = bid;
  if ((nwg & 7) == 0) swz = (bid & 7) * (nwg >> 3) + (bid >> 3);
  const int mb = swz % NMB, nb = swz / NMB;      // m-fast: B panel L2-resident
  const int m0 = mb * 128, n0 = nb * 256;

  const int tid = threadIdx.x;
  const int w = tid >> 6, lane = tid & 63;
  const int wr = w >> 2, wc = w & 3;             // 2 x 4 waves
  const int lr = lane & 15, lg = lane >> 4;

  // A staging (lane-linear): wave w region rows 8w..8w+7 (load0), +64 (load1)
  const int sr = w * 8 + (lane >> 3);            // 0..63
  const int sd = lane & 7;                       // dest slot (lane-linear)
  const int gs = sd ^ (sr & 7);                  // swizzled source slot
  const u16* gA0 = A + (size_t)(m0 + sr) * K + gs * 8;
  const u16* gA1 = A + (size_t)(m0 + 64 + sr) * K + gs * 8;  // (64+sr)&7==sr&7
  u16* lA0 = &Asm[0][sr * 64 + sd * 8];
  u16* lA1 = &Asm[0][(64 + sr) * 64 + sd * 8];

  // B frag bases: frag(nj, ks) at ktile t -> gB[nj] + (2t+ks)*512 elems
  const int kt32 = K >> 5;
  const u16* gB[4];
#pragma unroll
  for (int nj = 0; nj < 4; ++nj)
    gB[nj] = Bt + (size_t)((n0 + wc * 64 + nj * 16) >> 4) * kt32 * 512 + lane * 8;

  // prologue: stage A(0) -> buf0 (issue first, pinned); load B(0) -> bE
  gload16(gA0, (char*)lA0);
  gload16(gA1, (char*)lA1);
  __builtin_amdgcn_sched_barrier(0);
  bf16x8 bE[4][2], bO[4][2];
#pragma unroll
  for (int nj = 0; nj < 4; ++nj)
#pragma unroll
    for (int ks = 0; ks < 2; ++ks)
      bE[nj][ks] = *reinterpret_cast<const bf16x8*>(gB[nj] + (size_t)ks * 512);
  asm volatile("s_waitcnt vmcnt(8)" ::: "memory");  // A(0) landed; B(0) in flight
  __builtin_amdgcn_s_barrier();

  f32x4 acc[4][4] = {};

#define GH_BODY(T, BUSE, BALT, PF)                                             \
  {                                                                            \
    if (PF) {                                                                  \
      const int nk = (T) + 1;                                                  \
      gload16(gA0 + (size_t)nk * 64, (char*)(lA0 + (nk & 1) * (128 * 64)));    \
      gload16(gA1 + (size_t)nk * 64, (char*)(lA1 + (nk & 1) * (128 * 64)));    \
      __builtin_amdgcn_sched_barrier(0);                                       \
      _Pragma("unroll") for (int nj = 0; nj < 4; ++nj)                         \
          _Pragma("unroll") for (int ks = 0; ks < 2; ++ks)                     \
              BALT[nj][ks] = *reinterpret_cast<const bf16x8*>(                 \
                  gB[nj] + (size_t)(2 * nk + ks) * 512);                       \
    }                                                                          \
    bf16x8 af[4][2];                                                           \
    _Pragma("unroll") for (int mi = 0; mi < 4; ++mi)                           \
        _Pragma("unroll") for (int ks = 0; ks < 2; ++ks) {                     \
      const int row = wr * 64 + mi * 16 + lr;                                  \
      const int slot = (ks * 4 + lg) ^ (row & 7);                              \
      af[mi][ks] = *reinterpret_cast<const bf16x8*>(                           \
          &Asm[(T) & 1][row * 64 + slot * 8]);                                 \
    }                                                                          \
    __builtin_amdgcn_s_setprio(1);                                             \
    _Pragma("unroll") for (int mi = 0; mi < 4; ++mi)                           \
        _Pragma("unroll") for (int nj = 0; nj < 4; ++nj) {                     \
      acc[mi][nj] = mfma16x32(af[mi][0], BUSE[nj][0], acc[mi][nj]);            \
      acc[mi][nj] = mfma16x32(af[mi][1], BUSE[nj][1], acc[mi][nj]);            \
    }                                                                          \
    __builtin_amdgcn_s_setprio(0);                                             \
    if (PF) asm volatile("s_waitcnt vmcnt(8)" ::: "memory");                   \
    else asm volatile("s_waitcnt vmcnt(0)" ::: "memory");                      \
    __builtin_amdgcn_s_barrier();                                              \
  }

  for (int t = 0; t < nt; t += 2) {        // nt even for all uses (K%128==0)
    GH_BODY(t, bE, bO, true)
    GH_BODY(t + 1, bO, bE, (t + 2 < nt))
  }
#undef GH_BODY

#pragma unroll
  for (int mi = 0; mi < 4; ++mi) {
#pragma unroll
    for (int nj = 0; nj < 4; ++nj) {
      const int col = n0 + wc * 64 + nj * 16 + lr;
#pragma unroll
      for (int r = 0; r < 4; ++r) {
        const int row = m0 + wr * 64 + mi * 16 + lg * 4 + r;
        float v = acc[mi][nj][r];
        if (EPI == EPI_GELU) {
          v += bias[col];
          v = 0.5f * v * (1.0f + erff(v * 0.70710678118654752f));
          outb[(size_t)row * Nc + col] = f2bf(v);
        } else {
          outf[(size_t)row * Nc + col] = v;
        }
      }
    }
  }
}

// ---------------------------------------------------------------- attention
__global__ __launch_bounds__(256) void k_attn(const u16* __restrict__ Qr,
                                              const u16* __restrict__ Kr,
                                              const u16* __restrict__ VT,
                                              u16* __restrict__ O) {
  __shared__ alignas(16) u16 Pl[4][16 * 32];
  const int hh = blockIdx.y;
  const int w = threadIdx.x >> 6, lane = threadIdx.x & 63;
  const int lr = lane & 15, lg = lane >> 4;
  const int q0 = blockIdx.x * 64 + w * 16;
  const u16* Qh = Qr + (size_t)hh * NSEQ * DHEAD;
  const u16* Kh = Kr + (size_t)hh * NSEQ * DHEAD;
  const u16* Vh = VT + (size_t)hh * DHEAD * NSEQ;
  u16* Pw = Pl[w];

  const bf16x8 aq0 = *reinterpret_cast<const bf16x8*>(Qh + (q0 + lr) * DHEAD + lg * 8);
  const bf16x8 aq1 = *reinterpret_cast<const bf16x8*>(Qh + (q0 + lr) * DHEAD + 32 + lg * 8);

  f32x4 o0 = {}, o1 = {}, o2 = {}, o3 = {};
  float m[4], l[4];
#pragma unroll
  for (int r = 0; r < 4; ++r) { m[r] = -1e30f; l[r] = 0.0f; }

  const int jend = q0 + 15;
  for (int j0 = 0; j0 <= jend; j0 += 32) {
    f32x4 s0 = {}, s1 = {};
    {
      bf16x8 bk;
      bk = *reinterpret_cast<const bf16x8*>(Kh + (j0 + lr) * DHEAD + lg * 8);
      s0 = mfma16x32(aq0, bk, s0);
      bk = *reinterpret_cast<const bf16x8*>(Kh + (j0 + lr) * DHEAD + 32 + lg * 8);
      s0 = mfma16x32(aq1, bk, s0);
      bk = *reinterpret_cast<const bf16x8*>(Kh + (j0 + 16 + lr) * DHEAD + lg * 8);
      s1 = mfma16x32(aq0, bk, s1);
      bk = *reinterpret_cast<const bf16x8*>(Kh + (j0 + 16 + lr) * DHEAD + 32 + lg * 8);
      s1 = mfma16x32(aq1, bk, s1);
    }
    float sv0[4], sv1[4], pm[4];
#pragma unroll
    for (int r = 0; r < 4; ++r) {
      const int irow = q0 + lg * 4 + r;
      sv0[r] = (j0 + lr > irow) ? -1e30f : s0[r] * 0.125f;
      sv1[r] = (j0 + 16 + lr > irow) ? -1e30f : s1[r] * 0.125f;
      pm[r] = fmaxf(sv0[r], sv1[r]);
    }
#pragma unroll
    for (int off = 1; off < 16; off <<= 1)
#pragma unroll
      for (int r = 0; r < 4; ++r) pm[r] = fmaxf(pm[r], __shfl_xor(pm[r], off));
    float p0[4], p1[4], rs[4];
    f32x4 fv;
#pragma unroll
    for (int r = 0; r < 4; ++r) {
      const float mn = fmaxf(m[r], pm[r]);
      fv[r] = __expf(m[r] - mn);
      m[r] = mn;
      p0[r] = __expf(sv0[r] - mn);
      p1[r] = __expf(sv1[r] - mn);
      rs[r] = p0[r] + p1[r];
    }
#pragma unroll
    for (int off = 1; off < 16; off <<= 1)
#pragma unroll
      for (int r = 0; r < 4; ++r) rs[r] += __shfl_xor(rs[r], off);
#pragma unroll
    for (int r = 0; r < 4; ++r) l[r] = l[r] * fv[r] + rs[r];
    o0 *= fv; o1 *= fv; o2 *= fv; o3 *= fv;

#pragma unroll
    for (int r = 0; r < 4; ++r) {
      Pw[(lg * 4 + r) * 32 + lr] = f2bf(p0[r]);
      Pw[(lg * 4 + r) * 32 + 16 + lr] = f2bf(p1[r]);
    }
    const bf16x8 pa = *reinterpret_cast<const bf16x8*>(Pw + lr * 32 + lg * 8);
    const u16* vb = Vh + j0 + lg * 8;
    o0 = mfma16x32(pa, *reinterpret_cast<const bf16x8*>(vb + (0 + lr) * NSEQ), o0);
    o1 = mfma16x32(pa, *reinterpret_cast<const bf16x8*>(vb + (16 + lr) * NSEQ), o1);
    o2 = mfma16x32(pa, *reinterpret_cast<const bf16x8*>(vb + (32 + lr) * NSEQ), o2);
    o3 = mfma16x32(pa, *reinterpret_cast<const bf16x8*>(vb + (48 + lr) * NSEQ), o3);
  }

#pragma unroll
  for (int r = 0; r < 4; ++r) {
    const int row = q0 + lg * 4 + r;
    const float invl = 1.0f / l[r];
    u16* orow = O + (size_t)row * DMODEL + hh * DHEAD;
    orow[0 * 16 + lr] = f2bf(o0[r] * invl);
    orow[1 * 16 + lr] = f2bf(o1[r] * invl);
    orow[2 * 16 + lr] = f2bf(o2[r] * invl);
    orow[3 * 16 + lr] = f2bf(o3[r] * invl);
  }
}

// ---------------------------------------------------------------- launch

extern "C" void kernel_launch(void* const* d_in, const int* in_sizes, int n_in,
                              void* d_out, int out_size, void* d_ws, size_t ws_size,
                              hipStream_t stream) {
  (void)in_sizes; (void)n_in;
  const int* x = (const int*)d_in[0];
  const float* emb = (const float*)d_in[1];
  const float* attn_gamma = (const float*)d_in[2];
  const float* w_qkv = (const float*)d_in[3];
  const float* w_attn_out = (const float*)d_in[4];
  const float* ff_gamma = (const float*)d_in[5];
  const float* w_ff1 = (const float*)d_in[6];
  const float* b_ff1 = (const float*)d_in[7];
  const float* w_ff2 = (const float*)d_in[8];
  const float* b_ff2 = (const float*)d_in[9];
  const float* final_gamma = (const float*)d_in[10];
  const float* w_logits = (const float*)d_in[11];
  float* out = (float*)d_out;

  const size_t EARLY_NEED = 176ull << 20;
  const size_t FINAL_NEED = 72ull << 20;
  char* earlyBase;
  char* finalBase;
  if (ws_size >= EARLY_NEED + FINAL_NEED) {
    earlyBase = (char*)d_ws;
    finalBase = (char*)d_ws + EARLY_NEED;
  } else if (ws_size >= FINAL_NEED && (size_t)out_size * 4 >= EARLY_NEED) {
    earlyBase = (char*)d_out;
    finalBase = (char*)d_ws;
  } else {
    return;
  }
  size_t eoff = 0, foff = 0;
  auto ealloc = [&](size_t b) { void* p = earlyBase + eoff; eoff += (b + 255) & ~(size_t)255; return p; };
  auto falloc = [&](size_t b) { void* p = finalBase + foff; foff += (b + 255) & ~(size_t)255; return p; };

  u16* wqkvT = (u16*)ealloc((size_t)NLAYER * 3072 * DMODEL * 2);   // tiled
  u16* wattnT = (u16*)ealloc((size_t)NLAYER * DMODEL * DMODEL * 2); // [N][K]
  u16* wff1T = (u16*)ealloc((size_t)NLAYER * FFD * DMODEL * 2);    // tiled
  u16* wff2T = (u16*)ealloc((size_t)NLAYER * DMODEL * FFD * 2);    // [N][K]
  float* h = (float*)ealloc((size_t)NSEQ * DMODEL * 4);
  float* qkv = (float*)ealloc((size_t)NSEQ * 3072 * 4);
  u16* Qr = (u16*)ealloc((size_t)NH * NSEQ * DHEAD * 2);
  u16* Kr = (u16*)ealloc((size_t)NH * NSEQ * DHEAD * 2);
  u16* VTb = (u16*)ealloc((size_t)NH * NSEQ * DHEAD * 2);
  u16* Ob = (u16*)ealloc((size_t)NSEQ * DMODEL * 2);
  u16* ff1b = (u16*)ealloc((size_t)NSEQ * FFD * 2);
  float* ct = (float*)ealloc((size_t)NSEQ * 32 * 4);
  float* st = (float*)ealloc((size_t)NSEQ * 32 * 4);
  u16* wlogT = (u16*)falloc((size_t)VOC * DMODEL * 2);             // tiled
  u16* xn = (u16*)falloc((size_t)NSEQ * DMODEL * 2);

  k_rope<<<dim3(NSEQ), dim3(32), 0, stream>>>(ct, st);
  // weight transposes, batched over layers via grid.z
  k_transpose<true><<<dim3(16, 48, NLAYER), 256, 0, stream>>>(
      w_qkv, wqkvT, DMODEL, 3072, (size_t)DMODEL * 3072, (size_t)3072 * DMODEL);
  k_transpose<false><<<dim3(16, 16, NLAYER), 256, 0, stream>>>(
      w_attn_out, wattnT, DMODEL, DMODEL, (size_t)DMODEL * DMODEL, (size_t)DMODEL * DMODEL);
  k_transpose<true><<<dim3(16, 64, NLAYER), 256, 0, stream>>>(
      w_ff1, wff1T, DMODEL, FFD, (size_t)DMODEL * FFD, (size_t)FFD * DMODEL);
  k_transpose<false><<<dim3(64, 16, NLAYER), 256, 0, stream>>>(
      w_ff2, wff2T, FFD, DMODEL, (size_t)FFD * DMODEL, (size_t)DMODEL * FFD);
  k_transpose<true><<<dim3(16, 500, 1), 256, 0, stream>>>(
      w_logits, wlogT, DMODEL, VOC, 0, 0);

  k_embed<<<dim3(NSEQ), 256, 0, stream>>>(x, emb, h);

  for (int lyr = 0; lyr < NLAYER; ++lyr) {
    k_rmsnorm<<<dim3(NSEQ), 256, 0, stream>>>(h, attn_gamma + (size_t)lyr * DMODEL, xn);
    k_gemmH<EPI_STORE><<<dim3(16 * 12), 512, 0, stream>>>(
        xn, wqkvT + (size_t)lyr * 3072 * DMODEL, DMODEL, 3072, 16, nullptr, qkv, nullptr);
    k_qkv_post<<<dim3(NSEQ, NH / 4), 256, 0, stream>>>(qkv, ct, st, Qr, Kr, VTb);
    k_attn<<<dim3(NSEQ / 64, NH), 256, 0, stream>>>(Qr, Kr, VTb, Ob);
    k_gemm<EPI_ADD><<<dim3(16, 8), 256, 0, stream>>>(
        Ob, wattnT + (size_t)lyr * DMODEL * DMODEL, DMODEL, DMODEL, nullptr, h, h, nullptr);
    k_rmsnorm<<<dim3(NSEQ), 256, 0, stream>>>(h, ff_gamma + (size_t)lyr * DMODEL, xn);
    k_gemmH<EPI_GELU><<<dim3(16 * 16), 512, 0, stream>>>(
        xn, wff1T + (size_t)lyr * FFD * DMODEL, DMODEL, FFD, 16, b_ff1 + (size_t)lyr * FFD, nullptr, ff1b);
    k_gemm<EPI_BIAS_ADD><<<dim3(16, 8), 256, 0, stream>>>(
        ff1b, wff2T + (size_t)lyr * DMODEL * FFD, FFD, DMODEL, b_ff2 + (size_t)lyr * DMODEL, h, h, nullptr);
  }

  k_rmsnorm<<<dim3(NSEQ), 256, 0, stream>>>(h, final_gamma, xn);
  k_gemmH<EPI_STORE><<<dim3(16 * 125), 512, 0, stream>>>(
      xn, wlogT, DMODEL, VOC, 16, nullptr, out, nullptr);
}

// Round 6
// 1573.747 us; speedup vs baseline: 1.0494x; 1.0494x over previous
//
#include <hip/hip_runtime.h>
#include <math.h>

// Decoder forward, MI355X gfx950. Round 5: k_gemm8p (verified R2/R3 sync
// structure) with FULL 3-bit both-sides XOR swizzle (R5 measured 0 conflicts
// for this pattern). k_gemmH dropped (latency-bound: 1 blk/CU + B-from-HBM).
//
// Dims (fixed): V=32000 D=1024 DEPTH=4 H=16 DH=64 FF=4096 B=1 N=2048

#define NSEQ 2048
#define DMODEL 1024
#define NH 16
#define DHEAD 64
#define FFD 4096
#define VOC 32000
#define NLAYER 4

typedef unsigned short u16;
typedef short bf16x8 __attribute__((ext_vector_type(8)));   // 8 bf16 in 4 VGPRs
typedef float f32x4 __attribute__((ext_vector_type(4)));

__device__ __forceinline__ u16 f2bf(float f) {
  unsigned int u = __builtin_bit_cast(unsigned int, f);
  u += 0x7fffu + ((u >> 16) & 1u);   // RNE
  return (u16)(u >> 16);
}

__device__ __forceinline__ void gload16(const void* g, void* l) {
  __builtin_amdgcn_global_load_lds((__attribute__((address_space(1))) void*)g,
                                   (__attribute__((address_space(3))) void*)l,
                                   16, 0, 0);
}

__device__ __forceinline__ f32x4 mfma16x32(bf16x8 a, bf16x8 b, f32x4 c) {
  return __builtin_amdgcn_mfma_f32_16x16x32_bf16(a, b, c, 0, 0, 0);
}

// ---------------------------------------------------------------- prep kernels

__global__ __launch_bounds__(256) void k_embed(const int* __restrict__ x,
                                               const float* __restrict__ emb,
                                               float* __restrict__ h) {
  const int n = blockIdx.x, t = threadIdx.x;
  const int tok = x[n];
  reinterpret_cast<float4*>(h + (size_t)n * DMODEL)[t] =
      reinterpret_cast<const float4*>(emb + (size_t)tok * DMODEL)[t];
}

__global__ void k_rope(float* __restrict__ ct, float* __restrict__ st) {
  const int n = blockIdx.x, p = threadIdx.x;  // 32 freq pairs
  const double inv = exp(-(double)(2 * p) / 64.0 * log(10000.0));
  const double a = (double)n * inv;
  ct[n * 32 + p] = (float)cos(a);
  st[n * 32 + p] = (float)sin(a);
}

// f32 [K][Nc] -> bf16 [Nc][K]; 64x64 tiles, float4 reads, ushort4 writes.
__global__ __launch_bounds__(256) void k_transpose(const float* __restrict__ in0,
                                                   u16* __restrict__ out0,
                                                   int K, int Nc,
                                                   size_t ls_in, size_t ls_out) {
  const float* in = in0 + blockIdx.z * ls_in;
  u16* out = out0 + blockIdx.z * ls_out;
  __shared__ float tile[64][65];
  const int kb = blockIdx.x * 64, nb = blockIdx.y * 64;
  const int tr = threadIdx.x >> 4;       // 0..15
  const int tc = threadIdx.x & 15;       // 0..15
#pragma unroll
  for (int r = 0; r < 64; r += 16) {
    const float4 v = *reinterpret_cast<const float4*>(
        &in[(size_t)(kb + r + tr) * Nc + nb + tc * 4]);
    tile[r + tr][tc * 4 + 0] = v.x;
    tile[r + tr][tc * 4 + 1] = v.y;
    tile[r + tr][tc * 4 + 2] = v.z;
    tile[r + tr][tc * 4 + 3] = v.w;
  }
  __syncthreads();
#pragma unroll
  for (int r = 0; r < 64; r += 16) {
    const int n = r + tr;
    ushort4 o;
    o.x = f2bf(tile[tc * 4 + 0][n]);
    o.y = f2bf(tile[tc * 4 + 1][n]);
    o.z = f2bf(tile[tc * 4 + 2][n]);
    o.w = f2bf(tile[tc * 4 + 3][n]);
    *reinterpret_cast<ushort4*>(&out[(size_t)(nb + n) * K + kb + tc * 4]) = o;
  }
}

// rms_norm(h)*gamma -> bf16 (GEMM A input). One row per block (256 thr, float4).
__global__ __launch_bounds__(256) void k_rmsnorm(const float* __restrict__ h,
                                                 const float* __restrict__ gamma,
                                                 u16* __restrict__ out) {
  __shared__ float red[4];
  const int n = blockIdx.x, t = threadIdx.x;
  const float4 v = reinterpret_cast<const float4*>(h + (size_t)n * DMODEL)[t];
  float ss = v.x * v.x + v.y * v.y + v.z * v.z + v.w * v.w;
#pragma unroll
  for (int off = 32; off; off >>= 1) ss += __shfl_down(ss, off);
  if ((t & 63) == 0) red[t >> 6] = ss;
  __syncthreads();
  const float tot = red[0] + red[1] + red[2] + red[3];
  const float inv = 32.0f / fmaxf(sqrtf(tot), 1e-12f);  // sqrt(1024)=32
  const float4 g = reinterpret_cast<const float4*>(gamma)[t];
  ushort4 o;
  o.x = f2bf(v.x * inv * g.x);
  o.y = f2bf(v.y * inv * g.y);
  o.z = f2bf(v.z * inv * g.z);
  o.w = f2bf(v.w * inv * g.w);
  reinterpret_cast<ushort4*>(out + (size_t)n * DMODEL)[t] = o;
}

// qkv f32 [N][3072] -> roped Q,K bf16 [H][N][64], V^T bf16 [H][64][N]
__global__ __launch_bounds__(256) void k_qkv_post(const float* __restrict__ qkv,
                                                  const float* __restrict__ ct,
                                                  const float* __restrict__ st,
                                                  u16* __restrict__ Qr,
                                                  u16* __restrict__ Kr,
                                                  u16* __restrict__ VT) {
  const int n = blockIdx.x;
  const int hh = blockIdx.y * 4 + (threadIdx.x >> 6);
  const int d = threadIdx.x & 63;  // == lane
  const float* base = qkv + (size_t)n * 3072 + hh * DHEAD + d;
  const float q = base[0], k = base[DMODEL], v = base[2 * DMODEL];
  const int p = d >> 1;
  const float c = ct[n * 32 + p], s = st[n * 32 + p];
  const float qp = __shfl_xor(q, 1);
  const float kp = __shfl_xor(k, 1);
  const float sgn = (d & 1) ? 1.0f : -1.0f;
  Qr[((size_t)hh * NSEQ + n) * DHEAD + d] = f2bf(q * c + sgn * qp * s);
  Kr[((size_t)hh * NSEQ + n) * DHEAD + d] = f2bf(k * c + sgn * kp * s);
  VT[((size_t)hh * DHEAD + d) * NSEQ + n] = f2bf(v);
}

// ---------------------------------------------------------------- GEMM epilogues
#define EPI_STORE 0
#define EPI_ADD 1
#define EPI_GELU 2
#define EPI_BIAS_ADD 3

// ---------------- 128x128 m97-structure GEMM (N=1024 shapes: attn_out, ff2) ---
// LDS rows = 32 bf16 = 64 B = 4 slots; 2-bit XOR swizzle (slot ^= row&3).
template <int EPI>
__global__ __launch_bounds__(256) void k_gemm(const u16* __restrict__ A,
                                              const u16* __restrict__ BT,
                                              int K, int Nc,
                                              const float* __restrict__ bias,
                                              const float* __restrict__ add,
                                              float* __restrict__ outf,
                                              u16* __restrict__ outb) {
  __shared__ alignas(16) u16 Asm[128 * 32];
  __shared__ alignas(16) u16 Bsm[128 * 32];
  const int tid = threadIdx.x;
  const int m0 = blockIdx.x * 128, n0 = blockIdx.y * 128;
  const int w = tid >> 6, lane = tid & 63;
  const int wr = (w >> 1) * 64, wc = (w & 1) * 64;
  const int lr = lane & 15, lg = lane >> 4;

  f32x4 acc[4][4] = {};

  const int rowA = tid >> 2;
  const int sslot = tid & 3;
  const int gslot = sslot ^ (rowA & 3);          // pre-swizzled source slot
  const int colE = gslot * 8;
  const u16* Ag0 = A + (size_t)(m0 + rowA) * K + colE;
  const u16* Ag1 = A + (size_t)(m0 + rowA + 64) * K + colE;
  const u16* Bg0 = BT + (size_t)(n0 + rowA) * K + colE;
  const u16* Bg1 = BT + (size_t)(n0 + rowA + 64) * K + colE;
  char* lA = (char*)Asm + tid * 16;              // lane-linear dest
  char* lB = (char*)Bsm + tid * 16;

  for (int kt = 0; kt < K; kt += 32) {
    __syncthreads();
    gload16(Ag0 + kt, lA);
    gload16(Ag1 + kt, lA + 4096);
    gload16(Bg0 + kt, lB);
    gload16(Bg1 + kt, lB + 4096);
    __syncthreads();
    bf16x8 af[4], bfr[4];
#pragma unroll
    for (int i = 0; i < 4; ++i) {
      const int ra = wr + i * 16 + lr, rb = wc + i * 16 + lr;
      af[i] = *reinterpret_cast<const bf16x8*>(&Asm[ra * 32 + (lg ^ (ra & 3)) * 8]);
      bfr[i] = *reinterpret_cast<const bf16x8*>(&Bsm[rb * 32 + (lg ^ (rb & 3)) * 8]);
    }
#pragma unroll
    for (int mi = 0; mi < 4; ++mi)
#pragma unroll
      for (int ni = 0; ni < 4; ++ni)
        acc[mi][ni] = mfma16x32(af[mi], bfr[ni], acc[mi][ni]);
  }

#pragma unroll
  for (int mi = 0; mi < 4; ++mi) {
#pragma unroll
    for (int ni = 0; ni < 4; ++ni) {
      const int col = n0 + wc + ni * 16 + lr;
#pragma unroll
      for (int r = 0; r < 4; ++r) {
        const int row = m0 + wr + mi * 16 + lg * 4 + r;
        const size_t idx = (size_t)row * Nc + col;
        float v = acc[mi][ni][r];
        if (EPI == EPI_GELU) {
          v += bias[col];
          v = 0.5f * v * (1.0f + erff(v * 0.70710678118654752f));
          outb[idx] = f2bf(v);
        } else if (EPI == EPI_ADD) {
          outf[idx] = v + add[idx];
        } else if (EPI == EPI_BIAS_ADD) {
          outf[idx] = v + bias[col] + add[idx];
        } else {
          outf[idx] = v;
        }
      }
    }
  }
}

// ---------------- 8-phase counted-vmcnt GEMM, 128x256xBK64, triple-buffer -----
// Invariant: tile t read from buf[t%3]; tile t+2 staged into buf[(t+2)%3].
// Boundary vmcnt(6) retires exactly tile t+1's 6 loads (counted, never 0 in
// steady state). FULL 3-bit both-sides swizzle: LDS dest lane-linear (tid*16,
// m104), global SOURCE slot = sslot ^ (srow&7), read slot = slot ^ (row&7).
// R5 measured this exact read pattern at 0 bank conflicts.

#define GP_ABYTES (128 * 64 * 2)                  // 16 KB
#define GP_BBYTES (256 * 64 * 2)                  // 32 KB
#define GP_BUFB (GP_ABYTES + GP_BBYTES)           // 48 KB/buffer, x3 = 144 KB

__device__ __forceinline__ bf16x8 lds_frag(const char* base, int row, int slot) {
  // row within region; 128 B rows = 8 slots of 16 B; full 3-bit involution
  return *reinterpret_cast<const bf16x8*>(
      base + row * 128 + ((slot ^ (row & 7)) << 4));
}

template <int EPI>
__global__ __launch_bounds__(512, 2) void k_gemm8p(const u16* __restrict__ A,
                                                   const u16* __restrict__ BT,
                                                   int K, int Nc, int NMB,
                                                   const float* __restrict__ bias,
                                                   float* __restrict__ outf,
                                                   u16* __restrict__ outb) {
  __shared__ alignas(16) char sm[3 * GP_BUFB];
  const int nt = K >> 6;

  // XCD chunking, m-fast: 16 m-blocks sharing a B panel run on one XCD.
  const int nwg = gridDim.x;
  const int bid = blockIdx.x;
  int swz = bid;
  if ((nwg & 7) == 0) swz = (bid & 7) * (nwg >> 3) + (bid >> 3);
  const int mb = swz % NMB, nb = swz / NMB;
  const int m0 = mb * 128, n0 = nb * 256;

  const int tid = threadIdx.x;
  const int w = tid >> 6, lane = tid & 63;
  const int wr = w >> 2, wc = w & 3;  // 2 x 4 wave grid
  const int lr = lane & 15, lg = lane >> 4;

  // staging: thread covers 16B chunk (srow, sslot); source slot pre-swizzled
  const int srow = tid >> 3;                       // 0..63
  const int sslot = tid & 7;                       // 16B slot
  const int gslot = sslot ^ (srow & 7);            // 3-bit involution
  const int scol = gslot * 8;                      // k elems
  const u16* ga0 = A + (size_t)(m0 + srow) * K + scol;
  const u16* ga1 = A + (size_t)(m0 + 64 + srow) * K + scol;
  const u16* gb0 = BT + (size_t)(n0 + srow) * K + scol;
  const u16* gb1 = BT + (size_t)(n0 + 64 + srow) * K + scol;
  const u16* gb2 = BT + (size_t)(n0 + 128 + srow) * K + scol;
  const u16* gb3 = BT + (size_t)(n0 + 192 + srow) * K + scol;
  const int ldOff = srow * 128 + sslot * 16;       // == tid*16, lane-linear

#define GP_STAGE_A(b)                                   \
  {                                                     \
    gload16(ga0, sm + (b)*GP_BUFB + ldOff);             \
    gload16(ga1, sm + (b)*GP_BUFB + ldOff + 8192);      \
  }
#define GP_STAGE_B01(b)                                         \
  {                                                             \
    gload16(gb0, sm + (b)*GP_BUFB + GP_ABYTES + ldOff);         \
    gload16(gb1, sm + (b)*GP_BUFB + GP_ABYTES + ldOff + 8192);  \
  }
#define GP_STAGE_B23(b)                                          \
  {                                                              \
    gload16(gb2, sm + (b)*GP_BUFB + GP_ABYTES + ldOff + 16384);  \
    gload16(gb3, sm + (b)*GP_BUFB + GP_ABYTES + ldOff + 24576);  \
  }
#define GP_ADV() \
  { ga0 += 64; ga1 += 64; gb0 += 64; gb1 += 64; gb2 += 64; gb3 += 64; }

  // prologue: stage tiles 0,1; wait tile0 (6 of tile1's stay in flight)
  GP_STAGE_A(0) GP_STAGE_B01(0) GP_STAGE_B23(0) GP_ADV();
  GP_STAGE_A(1) GP_STAGE_B01(1) GP_STAGE_B23(1) GP_ADV();
  asm volatile("s_waitcnt vmcnt(6)" ::: "memory");
  __builtin_amdgcn_s_barrier();

  f32x4 acc[4][4] = {};
  int cur = 0, nx2 = 2;
  for (int t = 0; t < nt; ++t) {
    const char* Ab = sm + cur * GP_BUFB;
    const char* Bb = sm + cur * GP_BUFB + GP_ABYTES;
    const bool pf = (t + 2 < nt);
    bf16x8 bf[4][2];
#pragma unroll
    for (int p = 0; p < 4; ++p) {
      // ds-load this phase's A frags (mi = p); all B frags at p==0
      bf16x8 af0 = lds_frag(Ab, wr * 64 + p * 16 + lr, lg);
      bf16x8 af1 = lds_frag(Ab, wr * 64 + p * 16 + lr, 4 + lg);
      if (p == 0) {
#pragma unroll
        for (int nj = 0; nj < 4; ++nj) {
#pragma unroll
          for (int ks = 0; ks < 2; ++ks)
            bf[nj][ks] = lds_frag(Bb, wc * 64 + nj * 16 + lr, ks * 4 + lg);
        }
      }
      // stage tile t+2's share for this phase
      if (pf) {
        if (p == 0) GP_STAGE_A(nx2)
        else if (p == 1) GP_STAGE_B01(nx2)
        else if (p == 2) GP_STAGE_B23(nx2)
      }
      __builtin_amdgcn_s_barrier();
      __builtin_amdgcn_s_setprio(1);
#pragma unroll
      for (int nj = 0; nj < 4; ++nj) {
        acc[p][nj] = mfma16x32(af0, bf[nj][0], acc[p][nj]);
        acc[p][nj] = mfma16x32(af1, bf[nj][1], acc[p][nj]);
      }
      __builtin_amdgcn_s_setprio(0);
    }
    if (pf) GP_ADV();
    if (t + 1 < nt) {
      __builtin_amdgcn_sched_barrier(0);
      if (pf) asm volatile("s_waitcnt vmcnt(6)" ::: "memory");
      else    asm volatile("s_waitcnt vmcnt(0)" ::: "memory");
      __builtin_amdgcn_s_barrier();
      __builtin_amdgcn_sched_barrier(0);
    }
    cur = (cur == 2) ? 0 : cur + 1;
    nx2 = (nx2 == 2) ? 0 : nx2 + 1;
  }

#pragma unroll
  for (int mi = 0; mi < 4; ++mi) {
#pragma unroll
    for (int nj = 0; nj < 4; ++nj) {
      const int col = n0 + wc * 64 + nj * 16 + lr;
#pragma unroll
      for (int r = 0; r < 4; ++r) {
        const int row = m0 + wr * 64 + mi * 16 + lg * 4 + r;
        float v = acc[mi][nj][r];
        if (EPI == EPI_GELU) {
          v += bias[col];
          v = 0.5f * v * (1.0f + erff(v * 0.70710678118654752f));
          outb[(size_t)row * Nc + col] = f2bf(v);
        } else {
          outf[(size_t)row * Nc + col] = v;
        }
      }
    }
  }
#undef GP_STAGE_A
#undef GP_STAGE_B01
#undef GP_STAGE_B23
#undef GP_ADV
}

// ---------------------------------------------------------------- attention
__global__ __launch_bounds__(256) void k_attn(const u16* __restrict__ Qr,
                                              const u16* __restrict__ Kr,
                                              const u16* __restrict__ VT,
                                              u16* __restrict__ O) {
  __shared__ alignas(16) u16 Pl[4][16 * 32];
  const int hh = blockIdx.y;
  const int w = threadIdx.x >> 6, lane = threadIdx.x & 63;
  const int lr = lane & 15, lg = lane >> 4;
  const int q0 = blockIdx.x * 64 + w * 16;
  const u16* Qh = Qr + (size_t)hh * NSEQ * DHEAD;
  const u16* Kh = Kr + (size_t)hh * NSEQ * DHEAD;
  const u16* Vh = VT + (size_t)hh * DHEAD * NSEQ;
  u16* Pw = Pl[w];

  const bf16x8 aq0 = *reinterpret_cast<const bf16x8*>(Qh + (q0 + lr) * DHEAD + lg * 8);
  const bf16x8 aq1 = *reinterpret_cast<const bf16x8*>(Qh + (q0 + lr) * DHEAD + 32 + lg * 8);

  f32x4 o0 = {}, o1 = {}, o2 = {}, o3 = {};
  float m[4], l[4];
#pragma unroll
  for (int r = 0; r < 4; ++r) { m[r] = -1e30f; l[r] = 0.0f; }

  const int jend = q0 + 15;
  for (int j0 = 0; j0 <= jend; j0 += 32) {
    f32x4 s0 = {}, s1 = {};
    {
      bf16x8 bk;
      bk = *reinterpret_cast<const bf16x8*>(Kh + (j0 + lr) * DHEAD + lg * 8);
      s0 = mfma16x32(aq0, bk, s0);
      bk = *reinterpret_cast<const bf16x8*>(Kh + (j0 + lr) * DHEAD + 32 + lg * 8);
      s0 = mfma16x32(aq1, bk, s0);
      bk = *reinterpret_cast<const bf16x8*>(Kh + (j0 + 16 + lr) * DHEAD + lg * 8);
      s1 = mfma16x32(aq0, bk, s1);
      bk = *reinterpret_cast<const bf16x8*>(Kh + (j0 + 16 + lr) * DHEAD + 32 + lg * 8);
      s1 = mfma16x32(aq1, bk, s1);
    }
    float sv0[4], sv1[4], pm[4];
#pragma unroll
    for (int r = 0; r < 4; ++r) {
      const int irow = q0 + lg * 4 + r;
      sv0[r] = (j0 + lr > irow) ? -1e30f : s0[r] * 0.125f;
      sv1[r] = (j0 + 16 + lr > irow) ? -1e30f : s1[r] * 0.125f;
      pm[r] = fmaxf(sv0[r], sv1[r]);
    }
#pragma unroll
    for (int off = 1; off < 16; off <<= 1)
#pragma unroll
      for (int r = 0; r < 4; ++r) pm[r] = fmaxf(pm[r], __shfl_xor(pm[r], off));
    float p0[4], p1[4], rs[4];
    f32x4 fv;
#pragma unroll
    for (int r = 0; r < 4; ++r) {
      const float mn = fmaxf(m[r], pm[r]);
      fv[r] = __expf(m[r] - mn);
      m[r] = mn;
      p0[r] = __expf(sv0[r] - mn);
      p1[r] = __expf(sv1[r] - mn);
      rs[r] = p0[r] + p1[r];
    }
#pragma unroll
    for (int off = 1; off < 16; off <<= 1)
#pragma unroll
      for (int r = 0; r < 4; ++r) rs[r] += __shfl_xor(rs[r], off);
#pragma unroll
    for (int r = 0; r < 4; ++r) l[r] = l[r] * fv[r] + rs[r];
    o0 *= fv; o1 *= fv; o2 *= fv; o3 *= fv;

#pragma unroll
    for (int r = 0; r < 4; ++r) {
      Pw[(lg * 4 + r) * 32 + lr] = f2bf(p0[r]);
      Pw[(lg * 4 + r) * 32 + 16 + lr] = f2bf(p1[r]);
    }
    const bf16x8 pa = *reinterpret_cast<const bf16x8*>(Pw + lr * 32 + lg * 8);
    const u16* vb = Vh + j0 + lg * 8;
    o0 = mfma16x32(pa, *reinterpret_cast<const bf16x8*>(vb + (0 + lr) * NSEQ), o0);
    o1 = mfma16x32(pa, *reinterpret_cast<const bf16x8*>(vb + (16 + lr) * NSEQ), o1);
    o2 = mfma16x32(pa, *reinterpret_cast<const bf16x8*>(vb + (32 + lr) * NSEQ), o2);
    o3 = mfma16x32(pa, *reinterpret_cast<const bf16x8*>(vb + (48 + lr) * NSEQ), o3);
  }

#pragma unroll
  for (int r = 0; r < 4; ++r) {
    const int row = q0 + lg * 4 + r;
    const float invl = 1.0f / l[r];
    u16* orow = O + (size_t)row * DMODEL + hh * DHEAD;
    orow[0 * 16 + lr] = f2bf(o0[r] * invl);
    orow[1 * 16 + lr] = f2bf(o1[r] * invl);
    orow[2 * 16 + lr] = f2bf(o2[r] * invl);
    orow[3 * 16 + lr] = f2bf(o3[r] * invl);
  }
}

// ---------------------------------------------------------------- launch

extern "C" void kernel_launch(void* const* d_in, const int* in_sizes, int n_in,
                              void* d_out, int out_size, void* d_ws, size_t ws_size,
                              hipStream_t stream) {
  (void)in_sizes; (void)n_in;
  const int* x = (const int*)d_in[0];
  const float* emb = (const float*)d_in[1];
  const float* attn_gamma = (const float*)d_in[2];
  const float* w_qkv = (const float*)d_in[3];
  const float* w_attn_out = (const float*)d_in[4];
  const float* ff_gamma = (const float*)d_in[5];
  const float* w_ff1 = (const float*)d_in[6];
  const float* b_ff1 = (const float*)d_in[7];
  const float* w_ff2 = (const float*)d_in[8];
  const float* b_ff2 = (const float*)d_in[9];
  const float* final_gamma = (const float*)d_in[10];
  const float* w_logits = (const float*)d_in[11];
  float* out = (float*)d_out;

  const size_t EARLY_NEED = 176ull << 20;
  const size_t FINAL_NEED = 72ull << 20;
  char* earlyBase;
  char* finalBase;
  if (ws_size >= EARLY_NEED + FINAL_NEED) {
    earlyBase = (char*)d_ws;
    finalBase = (char*)d_ws + EARLY_NEED;
  } else if (ws_size >= FINAL_NEED && (size_t)out_size * 4 >= EARLY_NEED) {
    earlyBase = (char*)d_out;
    finalBase = (char*)d_ws;
  } else {
    return;
  }
  size_t eoff = 0, foff = 0;
  auto ealloc = [&](size_t b) { void* p = earlyBase + eoff; eoff += (b + 255) & ~(size_t)255; return p; };
  auto falloc = [&](size_t b) { void* p = finalBase + foff; foff += (b + 255) & ~(size_t)255; return p; };

  u16* wqkvT = (u16*)ealloc((size_t)NLAYER * 3072 * DMODEL * 2);
  u16* wattnT = (u16*)ealloc((size_t)NLAYER * DMODEL * DMODEL * 2);
  u16* wff1T = (u16*)ealloc((size_t)NLAYER * FFD * DMODEL * 2);
  u16* wff2T = (u16*)ealloc((size_t)NLAYER * DMODEL * FFD * 2);
  float* h = (float*)ealloc((size_t)NSEQ * DMODEL * 4);
  float* qkv = (float*)ealloc((size_t)NSEQ * 3072 * 4);
  u16* Qr = (u16*)ealloc((size_t)NH * NSEQ * DHEAD * 2);
  u16* Kr = (u16*)ealloc((size_t)NH * NSEQ * DHEAD * 2);
  u16* VTb = (u16*)ealloc((size_t)NH * NSEQ * DHEAD * 2);
  u16* Ob = (u16*)ealloc((size_t)NSEQ * DMODEL * 2);
  u16* ff1b = (u16*)ealloc((size_t)NSEQ * FFD * 2);
  float* ct = (float*)ealloc((size_t)NSEQ * 32 * 4);
  float* st = (float*)ealloc((size_t)NSEQ * 32 * 4);
  u16* wlogT = (u16*)falloc((size_t)VOC * DMODEL * 2);
  u16* xn = (u16*)falloc((size_t)NSEQ * DMODEL * 2);

  k_rope<<<dim3(NSEQ), dim3(32), 0, stream>>>(ct, st);
  // weight transposes, batched over layers via grid.z
  k_transpose<<<dim3(16, 48, NLAYER), 256, 0, stream>>>(
      w_qkv, wqkvT, DMODEL, 3072, (size_t)DMODEL * 3072, (size_t)3072 * DMODEL);
  k_transpose<<<dim3(16, 16, NLAYER), 256, 0, stream>>>(
      w_attn_out, wattnT, DMODEL, DMODEL, (size_t)DMODEL * DMODEL, (size_t)DMODEL * DMODEL);
  k_transpose<<<dim3(16, 64, NLAYER), 256, 0, stream>>>(
      w_ff1, wff1T, DMODEL, FFD, (size_t)DMODEL * FFD, (size_t)FFD * DMODEL);
  k_transpose<<<dim3(64, 16, NLAYER), 256, 0, stream>>>(
      w_ff2, wff2T, FFD, DMODEL, (size_t)FFD * DMODEL, (size_t)DMODEL * FFD);
  k_transpose<<<dim3(16, 500, 1), 256, 0, stream>>>(
      w_logits, wlogT, DMODEL, VOC, 0, 0);

  k_embed<<<dim3(NSEQ), 256, 0, stream>>>(x, emb, h);

  for (int lyr = 0; lyr < NLAYER; ++lyr) {
    k_rmsnorm<<<dim3(NSEQ), 256, 0, stream>>>(h, attn_gamma + (size_t)lyr * DMODEL, xn);
    k_gemm8p<EPI_STORE><<<dim3(16 * 12), 512, 0, stream>>>(
        xn, wqkvT + (size_t)lyr * 3072 * DMODEL, DMODEL, 3072, 16, nullptr, qkv, nullptr);
    k_qkv_post<<<dim3(NSEQ, NH / 4), 256, 0, stream>>>(qkv, ct, st, Qr, Kr, VTb);
    k_attn<<<dim3(NSEQ / 64, NH), 256, 0, stream>>>(Qr, Kr, VTb, Ob);
    k_gemm<EPI_ADD><<<dim3(16, 8), 256, 0, stream>>>(
        Ob, wattnT + (size_t)lyr * DMODEL * DMODEL, DMODEL, DMODEL, nullptr, h, h, nullptr);
    k_rmsnorm<<<dim3(NSEQ), 256, 0, stream>>>(h, ff_gamma + (size_t)lyr * DMODEL, xn);
    k_gemm8p<EPI_GELU><<<dim3(16 * 16), 512, 0, stream>>>(
        xn, wff1T + (size_t)lyr * FFD * DMODEL, DMODEL, FFD, 16, b_ff1 + (size_t)lyr * FFD, nullptr, ff1b);
    k_gemm<EPI_BIAS_ADD><<<dim3(16, 8), 256, 0, stream>>>(
        ff1b, wff2T + (size_t)lyr * DMODEL * FFD, FFD, DMODEL, b_ff2 + (size_t)lyr * DMODEL, h, h, nullptr);
  }

  k_rmsnorm<<<dim3(NSEQ), 256, 0, stream>>>(h, final_gamma, xn);
  k_gemm8p<EPI_STORE><<<dim3(16 * 125), 512, 0, stream>>>(
      xn, wlogT, DMODEL, VOC, 16, nullptr, out, nullptr);
}

// Round 7
// 1556.407 us; speedup vs baseline: 1.0611x; 1.0111x over previous
//
#include <hip/hip_runtime.h>
#include <math.h>

// Decoder forward, MI355X gfx950. Round 6: k_gemm8p intra-tile barriers
// removed (triple-buffer makes them unnecessary: reads and stages always hit
// different buffers; one vmcnt(6)+barrier per K-tile boundary is the full
// sync requirement). 16-MFMA clusters, reads split 12/4 across two halves.
//
// Dims (fixed): V=32000 D=1024 DEPTH=4 H=16 DH=64 FF=4096 B=1 N=2048

#define NSEQ 2048
#define DMODEL 1024
#define NH 16
#define DHEAD 64
#define FFD 4096
#define VOC 32000
#define NLAYER 4

typedef unsigned short u16;
typedef short bf16x8 __attribute__((ext_vector_type(8)));   // 8 bf16 in 4 VGPRs
typedef float f32x4 __attribute__((ext_vector_type(4)));

__device__ __forceinline__ u16 f2bf(float f) {
  unsigned int u = __builtin_bit_cast(unsigned int, f);
  u += 0x7fffu + ((u >> 16) & 1u);   // RNE
  return (u16)(u >> 16);
}

__device__ __forceinline__ void gload16(const void* g, void* l) {
  __builtin_amdgcn_global_load_lds((__attribute__((address_space(1))) void*)g,
                                   (__attribute__((address_space(3))) void*)l,
                                   16, 0, 0);
}

__device__ __forceinline__ f32x4 mfma16x32(bf16x8 a, bf16x8 b, f32x4 c) {
  return __builtin_amdgcn_mfma_f32_16x16x32_bf16(a, b, c, 0, 0, 0);
}

// ---------------------------------------------------------------- prep kernels

__global__ __launch_bounds__(256) void k_embed(const int* __restrict__ x,
                                               const float* __restrict__ emb,
                                               float* __restrict__ h) {
  const int n = blockIdx.x, t = threadIdx.x;
  const int tok = x[n];
  reinterpret_cast<float4*>(h + (size_t)n * DMODEL)[t] =
      reinterpret_cast<const float4*>(emb + (size_t)tok * DMODEL)[t];
}

__global__ void k_rope(float* __restrict__ ct, float* __restrict__ st) {
  const int n = blockIdx.x, p = threadIdx.x;  // 32 freq pairs
  const double inv = exp(-(double)(2 * p) / 64.0 * log(10000.0));
  const double a = (double)n * inv;
  ct[n * 32 + p] = (float)cos(a);
  st[n * 32 + p] = (float)sin(a);
}

// f32 [K][Nc] -> bf16 [Nc][K]; 64x64 tiles, float4 reads, ushort4 writes.
__global__ __launch_bounds__(256) void k_transpose(const float* __restrict__ in0,
                                                   u16* __restrict__ out0,
                                                   int K, int Nc,
                                                   size_t ls_in, size_t ls_out) {
  const float* in = in0 + blockIdx.z * ls_in;
  u16* out = out0 + blockIdx.z * ls_out;
  __shared__ float tile[64][65];
  const int kb = blockIdx.x * 64, nb = blockIdx.y * 64;
  const int tr = threadIdx.x >> 4;       // 0..15
  const int tc = threadIdx.x & 15;       // 0..15
#pragma unroll
  for (int r = 0; r < 64; r += 16) {
    const float4 v = *reinterpret_cast<const float4*>(
        &in[(size_t)(kb + r + tr) * Nc + nb + tc * 4]);
    tile[r + tr][tc * 4 + 0] = v.x;
    tile[r + tr][tc * 4 + 1] = v.y;
    tile[r + tr][tc * 4 + 2] = v.z;
    tile[r + tr][tc * 4 + 3] = v.w;
  }
  __syncthreads();
#pragma unroll
  for (int r = 0; r < 64; r += 16) {
    const int n = r + tr;
    ushort4 o;
    o.x = f2bf(tile[tc * 4 + 0][n]);
    o.y = f2bf(tile[tc * 4 + 1][n]);
    o.z = f2bf(tile[tc * 4 + 2][n]);
    o.w = f2bf(tile[tc * 4 + 3][n]);
    *reinterpret_cast<ushort4*>(&out[(size_t)(nb + n) * K + kb + tc * 4]) = o;
  }
}

// rms_norm(h)*gamma -> bf16 (GEMM A input). One row per block (256 thr, float4).
__global__ __launch_bounds__(256) void k_rmsnorm(const float* __restrict__ h,
                                                 const float* __restrict__ gamma,
                                                 u16* __restrict__ out) {
  __shared__ float red[4];
  const int n = blockIdx.x, t = threadIdx.x;
  const float4 v = reinterpret_cast<const float4*>(h + (size_t)n * DMODEL)[t];
  float ss = v.x * v.x + v.y * v.y + v.z * v.z + v.w * v.w;
#pragma unroll
  for (int off = 32; off; off >>= 1) ss += __shfl_down(ss, off);
  if ((t & 63) == 0) red[t >> 6] = ss;
  __syncthreads();
  const float tot = red[0] + red[1] + red[2] + red[3];
  const float inv = 32.0f / fmaxf(sqrtf(tot), 1e-12f);  // sqrt(1024)=32
  const float4 g = reinterpret_cast<const float4*>(gamma)[t];
  ushort4 o;
  o.x = f2bf(v.x * inv * g.x);
  o.y = f2bf(v.y * inv * g.y);
  o.z = f2bf(v.z * inv * g.z);
  o.w = f2bf(v.w * inv * g.w);
  reinterpret_cast<ushort4*>(out + (size_t)n * DMODEL)[t] = o;
}

// qkv f32 [N][3072] -> roped Q,K bf16 [H][N][64], V^T bf16 [H][64][N]
__global__ __launch_bounds__(256) void k_qkv_post(const float* __restrict__ qkv,
                                                  const float* __restrict__ ct,
                                                  const float* __restrict__ st,
                                                  u16* __restrict__ Qr,
                                                  u16* __restrict__ Kr,
                                                  u16* __restrict__ VT) {
  const int n = blockIdx.x;
  const int hh = blockIdx.y * 4 + (threadIdx.x >> 6);
  const int d = threadIdx.x & 63;  // == lane
  const float* base = qkv + (size_t)n * 3072 + hh * DHEAD + d;
  const float q = base[0], k = base[DMODEL], v = base[2 * DMODEL];
  const int p = d >> 1;
  const float c = ct[n * 32 + p], s = st[n * 32 + p];
  const float qp = __shfl_xor(q, 1);
  const float kp = __shfl_xor(k, 1);
  const float sgn = (d & 1) ? 1.0f : -1.0f;
  Qr[((size_t)hh * NSEQ + n) * DHEAD + d] = f2bf(q * c + sgn * qp * s);
  Kr[((size_t)hh * NSEQ + n) * DHEAD + d] = f2bf(k * c + sgn * kp * s);
  VT[((size_t)hh * DHEAD + d) * NSEQ + n] = f2bf(v);
}

// ---------------------------------------------------------------- GEMM epilogues
#define EPI_STORE 0
#define EPI_ADD 1
#define EPI_GELU 2
#define EPI_BIAS_ADD 3

// ---------------- 128x128 m97-structure GEMM (N=1024 shapes: attn_out, ff2) ---
// LDS rows = 32 bf16 = 64 B = 4 slots; 2-bit XOR swizzle (slot ^= row&3).
template <int EPI>
__global__ __launch_bounds__(256) void k_gemm(const u16* __restrict__ A,
                                              const u16* __restrict__ BT,
                                              int K, int Nc,
                                              const float* __restrict__ bias,
                                              const float* __restrict__ add,
                                              float* __restrict__ outf,
                                              u16* __restrict__ outb) {
  __shared__ alignas(16) u16 Asm[128 * 32];
  __shared__ alignas(16) u16 Bsm[128 * 32];
  const int tid = threadIdx.x;
  const int m0 = blockIdx.x * 128, n0 = blockIdx.y * 128;
  const int w = tid >> 6, lane = tid & 63;
  const int wr = (w >> 1) * 64, wc = (w & 1) * 64;
  const int lr = lane & 15, lg = lane >> 4;

  f32x4 acc[4][4] = {};

  const int rowA = tid >> 2;
  const int sslot = tid & 3;
  const int gslot = sslot ^ (rowA & 3);          // pre-swizzled source slot
  const int colE = gslot * 8;
  const u16* Ag0 = A + (size_t)(m0 + rowA) * K + colE;
  const u16* Ag1 = A + (size_t)(m0 + rowA + 64) * K + colE;
  const u16* Bg0 = BT + (size_t)(n0 + rowA) * K + colE;
  const u16* Bg1 = BT + (size_t)(n0 + rowA + 64) * K + colE;
  char* lA = (char*)Asm + tid * 16;              // lane-linear dest
  char* lB = (char*)Bsm + tid * 16;

  for (int kt = 0; kt < K; kt += 32) {
    __syncthreads();
    gload16(Ag0 + kt, lA);
    gload16(Ag1 + kt, lA + 4096);
    gload16(Bg0 + kt, lB);
    gload16(Bg1 + kt, lB + 4096);
    __syncthreads();
    bf16x8 af[4], bfr[4];
#pragma unroll
    for (int i = 0; i < 4; ++i) {
      const int ra = wr + i * 16 + lr, rb = wc + i * 16 + lr;
      af[i] = *reinterpret_cast<const bf16x8*>(&Asm[ra * 32 + (lg ^ (ra & 3)) * 8]);
      bfr[i] = *reinterpret_cast<const bf16x8*>(&Bsm[rb * 32 + (lg ^ (rb & 3)) * 8]);
    }
#pragma unroll
    for (int mi = 0; mi < 4; ++mi)
#pragma unroll
      for (int ni = 0; ni < 4; ++ni)
        acc[mi][ni] = mfma16x32(af[mi], bfr[ni], acc[mi][ni]);
  }

#pragma unroll
  for (int mi = 0; mi < 4; ++mi) {
#pragma unroll
    for (int ni = 0; ni < 4; ++ni) {
      const int col = n0 + wc + ni * 16 + lr;
#pragma unroll
      for (int r = 0; r < 4; ++r) {
        const int row = m0 + wr + mi * 16 + lg * 4 + r;
        const size_t idx = (size_t)row * Nc + col;
        float v = acc[mi][ni][r];
        if (EPI == EPI_GELU) {
          v += bias[col];
          v = 0.5f * v * (1.0f + erff(v * 0.70710678118654752f));
          outb[idx] = f2bf(v);
        } else if (EPI == EPI_ADD) {
          outf[idx] = v + add[idx];
        } else if (EPI == EPI_BIAS_ADD) {
          outf[idx] = v + bias[col] + add[idx];
        } else {
          outf[idx] = v;
        }
      }
    }
  }
}

// ---------------- counted-vmcnt GEMM, 128x256xBK64, triple-buffer ------------
// Sync invariant (verified R5/R6): tile t read from buf[t%3]; tile t+2 staged
// into buf[(t+2)%3] (never the read buffer). ONE barrier per K-tile boundary;
// vmcnt(6) there retires exactly tile t+1's 6 loads (never drains to 0 in
// steady state). No intra-tile barriers: triple-buffering makes them
// unnecessary, and removing them cuts 9 rendezvous/K-tile to 1 (we run
// 1 block/CU, so every barrier stalls the whole CU).
// Full 3-bit both-sides swizzle (0 conflicts measured R6).

#define GP_ABYTES (128 * 64 * 2)                  // 16 KB
#define GP_BBYTES (256 * 64 * 2)                  // 32 KB
#define GP_BUFB (GP_ABYTES + GP_BBYTES)           // 48 KB/buffer, x3 = 144 KB

__device__ __forceinline__ bf16x8 lds_frag(const char* base, int row, int slot) {
  // row within region; 128 B rows = 8 slots of 16 B; full 3-bit involution
  return *reinterpret_cast<const bf16x8*>(
      base + row * 128 + ((slot ^ (row & 7)) << 4));
}

template <int EPI>
__global__ __launch_bounds__(512, 2) void k_gemm8p(const u16* __restrict__ A,
                                                   const u16* __restrict__ BT,
                                                   int K, int Nc, int NMB,
                                                   const float* __restrict__ bias,
                                                   float* __restrict__ outf,
                                                   u16* __restrict__ outb) {
  __shared__ alignas(16) char sm[3 * GP_BUFB];
  const int nt = K >> 6;

  // XCD chunking, m-fast: 16 m-blocks sharing a B panel run on one XCD.
  const int nwg = gridDim.x;
  const int bid = blockIdx.x;
  int swz = bid;
  if ((nwg & 7) == 0) swz = (bid & 7) * (nwg >> 3) + (bid >> 3);
  const int mb = swz % NMB, nb = swz / NMB;
  const int m0 = mb * 128, n0 = nb * 256;

  const int tid = threadIdx.x;
  const int w = tid >> 6, lane = tid & 63;
  const int wr = w >> 2, wc = w & 3;  // 2 x 4 wave grid
  const int lr = lane & 15, lg = lane >> 4;

  // staging: thread covers 16B chunk (srow, sslot); source slot pre-swizzled
  const int srow = tid >> 3;                       // 0..63
  const int sslot = tid & 7;                       // 16B slot
  const int gslot = sslot ^ (srow & 7);            // 3-bit involution
  const int scol = gslot * 8;                      // k elems
  const u16* ga0 = A + (size_t)(m0 + srow) * K + scol;
  const u16* ga1 = A + (size_t)(m0 + 64 + srow) * K + scol;
  const u16* gb0 = BT + (size_t)(n0 + srow) * K + scol;
  const u16* gb1 = BT + (size_t)(n0 + 64 + srow) * K + scol;
  const u16* gb2 = BT + (size_t)(n0 + 128 + srow) * K + scol;
  const u16* gb3 = BT + (size_t)(n0 + 192 + srow) * K + scol;
  const int ldOff = srow * 128 + sslot * 16;       // == tid*16, lane-linear

#define GP_STAGE_A(b)                                   \
  {                                                     \
    gload16(ga0, sm + (b)*GP_BUFB + ldOff);             \
    gload16(ga1, sm + (b)*GP_BUFB + ldOff + 8192);      \
  }
#define GP_STAGE_B01(b)                                         \
  {                                                             \
    gload16(gb0, sm + (b)*GP_BUFB + GP_ABYTES + ldOff);         \
    gload16(gb1, sm + (b)*GP_BUFB + GP_ABYTES + ldOff + 8192);  \
  }
#define GP_STAGE_B23(b)                                          \
  {                                                              \
    gload16(gb2, sm + (b)*GP_BUFB + GP_ABYTES + ldOff + 16384);  \
    gload16(gb3, sm + (b)*GP_BUFB + GP_ABYTES + ldOff + 24576);  \
  }
#define GP_ADV() \
  { ga0 += 64; ga1 += 64; gb0 += 64; gb1 += 64; gb2 += 64; gb3 += 64; }

  // prologue: stage tiles 0,1; wait tile0 (6 of tile1's stay in flight)
  GP_STAGE_A(0) GP_STAGE_B01(0) GP_STAGE_B23(0) GP_ADV();
  GP_STAGE_A(1) GP_STAGE_B01(1) GP_STAGE_B23(1) GP_ADV();
  asm volatile("s_waitcnt vmcnt(6)" ::: "memory");
  __builtin_amdgcn_s_barrier();

  f32x4 acc[4][4] = {};
  int cur = 0, nx2 = 2;
  for (int t = 0; t < nt; ++t) {
    const char* Ab = sm + cur * GP_BUFB;
    const char* Bb = sm + cur * GP_BUFB + GP_ABYTES;
    const bool pf = (t + 2 < nt);

    // half 1: A frags (8 reads) + B nj=0,1 (4 reads); stage A + B01
    bf16x8 af[4][2], bfr[2][2];
#pragma unroll
    for (int mi = 0; mi < 4; ++mi)
#pragma unroll
      for (int ks = 0; ks < 2; ++ks)
        af[mi][ks] = lds_frag(Ab, wr * 64 + mi * 16 + lr, ks * 4 + lg);
#pragma unroll
    for (int nj = 0; nj < 2; ++nj)
#pragma unroll
      for (int ks = 0; ks < 2; ++ks)
        bfr[nj][ks] = lds_frag(Bb, wc * 64 + nj * 16 + lr, ks * 4 + lg);
    if (pf) { GP_STAGE_A(nx2) GP_STAGE_B01(nx2) }
    __builtin_amdgcn_s_setprio(1);
#pragma unroll
    for (int mi = 0; mi < 4; ++mi)
#pragma unroll
      for (int nj = 0; nj < 2; ++nj) {
        acc[mi][nj] = mfma16x32(af[mi][0], bfr[nj][0], acc[mi][nj]);
        acc[mi][nj] = mfma16x32(af[mi][1], bfr[nj][1], acc[mi][nj]);
      }
    __builtin_amdgcn_s_setprio(0);

    // half 2: B nj=2,3 (4 reads); stage B23
    bf16x8 bf2[2][2];
#pragma unroll
    for (int nj = 0; nj < 2; ++nj)
#pragma unroll
      for (int ks = 0; ks < 2; ++ks)
        bf2[nj][ks] = lds_frag(Bb, wc * 64 + (2 + nj) * 16 + lr, ks * 4 + lg);
    if (pf) { GP_STAGE_B23(nx2) }
    __builtin_amdgcn_s_setprio(1);
#pragma unroll
    for (int mi = 0; mi < 4; ++mi)
#pragma unroll
      for (int nj = 0; nj < 2; ++nj) {
        acc[mi][2 + nj] = mfma16x32(af[mi][0], bf2[nj][0], acc[mi][2 + nj]);
        acc[mi][2 + nj] = mfma16x32(af[mi][1], bf2[nj][1], acc[mi][2 + nj]);
      }
    __builtin_amdgcn_s_setprio(0);

    if (pf) GP_ADV();
    if (t + 1 < nt) {
      __builtin_amdgcn_sched_barrier(0);
      if (pf) asm volatile("s_waitcnt vmcnt(6)" ::: "memory");
      else    asm volatile("s_waitcnt vmcnt(0)" ::: "memory");
      __builtin_amdgcn_s_barrier();
      __builtin_amdgcn_sched_barrier(0);
    }
    cur = (cur == 2) ? 0 : cur + 1;
    nx2 = (nx2 == 2) ? 0 : nx2 + 1;
  }

#pragma unroll
  for (int mi = 0; mi < 4; ++mi) {
#pragma unroll
    for (int nj = 0; nj < 4; ++nj) {
      const int col = n0 + wc * 64 + nj * 16 + lr;
#pragma unroll
      for (int r = 0; r < 4; ++r) {
        const int row = m0 + wr * 64 + mi * 16 + lg * 4 + r;
        float v = acc[mi][nj][r];
        if (EPI == EPI_GELU) {
          v += bias[col];
          v = 0.5f * v * (1.0f + erff(v * 0.70710678118654752f));
          outb[(size_t)row * Nc + col] = f2bf(v);
        } else {
          outf[(size_t)row * Nc + col] = v;
        }
      }
    }
  }
#undef GP_STAGE_A
#undef GP_STAGE_B01
#undef GP_STAGE_B23
#undef GP_ADV
}

// ---------------------------------------------------------------- attention
__global__ __launch_bounds__(256) void k_attn(const u16* __restrict__ Qr,
                                              const u16* __restrict__ Kr,
                                              const u16* __restrict__ VT,
                                              u16* __restrict__ O) {
  __shared__ alignas(16) u16 Pl[4][16 * 32];
  const int hh = blockIdx.y;
  const int w = threadIdx.x >> 6, lane = threadIdx.x & 63;
  const int lr = lane & 15, lg = lane >> 4;
  const int q0 = blockIdx.x * 64 + w * 16;
  const u16* Qh = Qr + (size_t)hh * NSEQ * DHEAD;
  const u16* Kh = Kr + (size_t)hh * NSEQ * DHEAD;
  const u16* Vh = VT + (size_t)hh * DHEAD * NSEQ;
  u16* Pw = Pl[w];

  const bf16x8 aq0 = *reinterpret_cast<const bf16x8*>(Qh + (q0 + lr) * DHEAD + lg * 8);
  const bf16x8 aq1 = *reinterpret_cast<const bf16x8*>(Qh + (q0 + lr) * DHEAD + 32 + lg * 8);

  f32x4 o0 = {}, o1 = {}, o2 = {}, o3 = {};
  float m[4], l[4];
#pragma unroll
  for (int r = 0; r < 4; ++r) { m[r] = -1e30f; l[r] = 0.0f; }

  const int jend = q0 + 15;
  for (int j0 = 0; j0 <= jend; j0 += 32) {
    f32x4 s0 = {}, s1 = {};
    {
      bf16x8 bk;
      bk = *reinterpret_cast<const bf16x8*>(Kh + (j0 + lr) * DHEAD + lg * 8);
      s0 = mfma16x32(aq0, bk, s0);
      bk = *reinterpret_cast<const bf16x8*>(Kh + (j0 + lr) * DHEAD + 32 + lg * 8);
      s0 = mfma16x32(aq1, bk, s0);
      bk = *reinterpret_cast<const bf16x8*>(Kh + (j0 + 16 + lr) * DHEAD + lg * 8);
      s1 = mfma16x32(aq0, bk, s1);
      bk = *reinterpret_cast<const bf16x8*>(Kh + (j0 + 16 + lr) * DHEAD + 32 + lg * 8);
      s1 = mfma16x32(aq1, bk, s1);
    }
    float sv0[4], sv1[4], pm[4];
#pragma unroll
    for (int r = 0; r < 4; ++r) {
      const int irow = q0 + lg * 4 + r;
      sv0[r] = (j0 + lr > irow) ? -1e30f : s0[r] * 0.125f;
      sv1[r] = (j0 + 16 + lr > irow) ? -1e30f : s1[r] * 0.125f;
      pm[r] = fmaxf(sv0[r], sv1[r]);
    }
#pragma unroll
    for (int off = 1; off < 16; off <<= 1)
#pragma unroll
      for (int r = 0; r < 4; ++r) pm[r] = fmaxf(pm[r], __shfl_xor(pm[r], off));
    float p0[4], p1[4], rs[4];
    f32x4 fv;
#pragma unroll
    for (int r = 0; r < 4; ++r) {
      const float mn = fmaxf(m[r], pm[r]);
      fv[r] = __expf(m[r] - mn);
      m[r] = mn;
      p0[r] = __expf(sv0[r] - mn);
      p1[r] = __expf(sv1[r] - mn);
      rs[r] = p0[r] + p1[r];
    }
#pragma unroll
    for (int off = 1; off < 16; off <<= 1)
#pragma unroll
      for (int r = 0; r < 4; ++r) rs[r] += __shfl_xor(rs[r], off);
#pragma unroll
    for (int r = 0; r < 4; ++r) l[r] = l[r] * fv[r] + rs[r];
    o0 *= fv; o1 *= fv; o2 *= fv; o3 *= fv;

#pragma unroll
    for (int r = 0; r < 4; ++r) {
      Pw[(lg * 4 + r) * 32 + lr] = f2bf(p0[r]);
      Pw[(lg * 4 + r) * 32 + 16 + lr] = f2bf(p1[r]);
    }
    const bf16x8 pa = *reinterpret_cast<const bf16x8*>(Pw + lr * 32 + lg * 8);
    const u16* vb = Vh + j0 + lg * 8;
    o0 = mfma16x32(pa, *reinterpret_cast<const bf16x8*>(vb + (0 + lr) * NSEQ), o0);
    o1 = mfma16x32(pa, *reinterpret_cast<const bf16x8*>(vb + (16 + lr) * NSEQ), o1);
    o2 = mfma16x32(pa, *reinterpret_cast<const bf16x8*>(vb + (32 + lr) * NSEQ), o2);
    o3 = mfma16x32(pa, *reinterpret_cast<const bf16x8*>(vb + (48 + lr) * NSEQ), o3);
  }

#pragma unroll
  for (int r = 0; r < 4; ++r) {
    const int row = q0 + lg * 4 + r;
    const float invl = 1.0f / l[r];
    u16* orow = O + (size_t)row * DMODEL + hh * DHEAD;
    orow[0 * 16 + lr] = f2bf(o0[r] * invl);
    orow[1 * 16 + lr] = f2bf(o1[r] * invl);
    orow[2 * 16 + lr] = f2bf(o2[r] * invl);
    orow[3 * 16 + lr] = f2bf(o3[r] * invl);
  }
}

// ---------------------------------------------------------------- launch

extern "C" void kernel_launch(void* const* d_in, const int* in_sizes, int n_in,
                              void* d_out, int out_size, void* d_ws, size_t ws_size,
                              hipStream_t stream) {
  (void)in_sizes; (void)n_in;
  const int* x = (const int*)d_in[0];
  const float* emb = (const float*)d_in[1];
  const float* attn_gamma = (const float*)d_in[2];
  const float* w_qkv = (const float*)d_in[3];
  const float* w_attn_out = (const float*)d_in[4];
  const float* ff_gamma = (const float*)d_in[5];
  const float* w_ff1 = (const float*)d_in[6];
  const float* b_ff1 = (const float*)d_in[7];
  const float* w_ff2 = (const float*)d_in[8];
  const float* b_ff2 = (const float*)d_in[9];
  const float* final_gamma = (const float*)d_in[10];
  const float* w_logits = (const float*)d_in[11];
  float* out = (float*)d_out;

  const size_t EARLY_NEED = 176ull << 20;
  const size_t FINAL_NEED = 72ull << 20;
  char* earlyBase;
  char* finalBase;
  if (ws_size >= EARLY_NEED + FINAL_NEED) {
    earlyBase = (char*)d_ws;
    finalBase = (char*)d_ws + EARLY_NEED;
  } else if (ws_size >= FINAL_NEED && (size_t)out_size * 4 >= EARLY_NEED) {
    earlyBase = (char*)d_out;
    finalBase = (char*)d_ws;
  } else {
    return;
  }
  size_t eoff = 0, foff = 0;
  auto ealloc = [&](size_t b) { void* p = earlyBase + eoff; eoff += (b + 255) & ~(size_t)255; return p; };
  auto falloc = [&](size_t b) { void* p = finalBase + foff; foff += (b + 255) & ~(size_t)255; return p; };

  u16* wqkvT = (u16*)ealloc((size_t)NLAYER * 3072 * DMODEL * 2);
  u16* wattnT = (u16*)ealloc((size_t)NLAYER * DMODEL * DMODEL * 2);
  u16* wff1T = (u16*)ealloc((size_t)NLAYER * FFD * DMODEL * 2);
  u16* wff2T = (u16*)ealloc((size_t)NLAYER * DMODEL * FFD * 2);
  float* h = (float*)ealloc((size_t)NSEQ * DMODEL * 4);
  float* qkv = (float*)ealloc((size_t)NSEQ * 3072 * 4);
  u16* Qr = (u16*)ealloc((size_t)NH * NSEQ * DHEAD * 2);
  u16* Kr = (u16*)ealloc((size_t)NH * NSEQ * DHEAD * 2);
  u16* VTb = (u16*)ealloc((size_t)NH * NSEQ * DHEAD * 2);
  u16* Ob = (u16*)ealloc((size_t)NSEQ * DMODEL * 2);
  u16* ff1b = (u16*)ealloc((size_t)NSEQ * FFD * 2);
  float* ct = (float*)ealloc((size_t)NSEQ * 32 * 4);
  float* st = (float*)ealloc((size_t)NSEQ * 32 * 4);
  u16* wlogT = (u16*)falloc((size_t)VOC * DMODEL * 2);
  u16* xn = (u16*)falloc((size_t)NSEQ * DMODEL * 2);

  k_rope<<<dim3(NSEQ), dim3(32), 0, stream>>>(ct, st);
  // weight transposes, batched over layers via grid.z
  k_transpose<<<dim3(16, 48, NLAYER), 256, 0, stream>>>(
      w_qkv, wqkvT, DMODEL, 3072, (size_t)DMODEL * 3072, (size_t)3072 * DMODEL);
  k_transpose<<<dim3(16, 16, NLAYER), 256, 0, stream>>>(
      w_attn_out, wattnT, DMODEL, DMODEL, (size_t)DMODEL * DMODEL, (size_t)DMODEL * DMODEL);
  k_transpose<<<dim3(16, 64, NLAYER), 256, 0, stream>>>(
      w_ff1, wff1T, DMODEL, FFD, (size_t)DMODEL * FFD, (size_t)FFD * DMODEL);
  k_transpose<<<dim3(64, 16, NLAYER), 256, 0, stream>>>(
      w_ff2, wff2T, FFD, DMODEL, (size_t)FFD * DMODEL, (size_t)DMODEL * FFD);
  k_transpose<<<dim3(16, 500, 1), 256, 0, stream>>>(
      w_logits, wlogT, DMODEL, VOC, 0, 0);

  k_embed<<<dim3(NSEQ), 256, 0, stream>>>(x, emb, h);

  for (int lyr = 0; lyr < NLAYER; ++lyr) {
    k_rmsnorm<<<dim3(NSEQ), 256, 0, stream>>>(h, attn_gamma + (size_t)lyr * DMODEL, xn);
    k_gemm8p<EPI_STORE><<<dim3(16 * 12), 512, 0, stream>>>(
        xn, wqkvT + (size_t)lyr * 3072 * DMODEL, DMODEL, 3072, 16, nullptr, qkv, nullptr);
    k_qkv_post<<<dim3(NSEQ, NH / 4), 256, 0, stream>>>(qkv, ct, st, Qr, Kr, VTb);
    k_attn<<<dim3(NSEQ / 64, NH), 256, 0, stream>>>(Qr, Kr, VTb, Ob);
    k_gemm<EPI_ADD><<<dim3(16, 8), 256, 0, stream>>>(
        Ob, wattnT + (size_t)lyr * DMODEL * DMODEL, DMODEL, DMODEL, nullptr, h, h, nullptr);
    k_rmsnorm<<<dim3(NSEQ), 256, 0, stream>>>(h, ff_gamma + (size_t)lyr * DMODEL, xn);
    k_gemm8p<EPI_GELU><<<dim3(16 * 16), 512, 0, stream>>>(
        xn, wff1T + (size_t)lyr * FFD * DMODEL, DMODEL, FFD, 16, b_ff1 + (size_t)lyr * FFD, nullptr, ff1b);
    k_gemm<EPI_BIAS_ADD><<<dim3(16, 8), 256, 0, stream>>>(
        ff1b, wff2T + (size_t)lyr * DMODEL * FFD, FFD, DMODEL, b_ff2 + (size_t)lyr * DMODEL, h, h, nullptr);
  }

  k_rmsnorm<<<dim3(NSEQ), 256, 0, stream>>>(h, final_gamma, xn);
  k_gemm8p<EPI_STORE><<<dim3(16 * 125), 512, 0, stream>>>(
      xn, wlogT, DMODEL, VOC, 16, nullptr, out, nullptr);
}

// Round 8
// 1373.720 us; speedup vs baseline: 1.2022x; 1.1330x over previous
//
#include <hip/hip_runtime.h>
#include <math.h>

// Decoder forward, MI355X gfx950. Round 7: single unified GEMM (k_gemmT):
// 128x128xBK32, triple-buffer 48KB LDS -> 3 blocks/CU (TLP!), counted vmcnt(4),
// 1 barrier/K-tile, 2-level 2-bit both-sides swizzle. qkv rope/split fused
// into the qkv GEMM epilogue (qkv_post kernel + f32 buffer eliminated).
//
// Dims (fixed): V=32000 D=1024 DEPTH=4 H=16 DH=64 FF=4096 B=1 N=2048

#define NSEQ 2048
#define DMODEL 1024
#define NH 16
#define DHEAD 64
#define FFD 4096
#define VOC 32000
#define NLAYER 4

typedef unsigned short u16;
typedef short bf16x8 __attribute__((ext_vector_type(8)));   // 8 bf16 in 4 VGPRs
typedef float f32x4 __attribute__((ext_vector_type(4)));

__device__ __forceinline__ u16 f2bf(float f) {
  unsigned int u = __builtin_bit_cast(unsigned int, f);
  u += 0x7fffu + ((u >> 16) & 1u);   // RNE
  return (u16)(u >> 16);
}

__device__ __forceinline__ void gload16(const void* g, void* l) {
  __builtin_amdgcn_global_load_lds((__attribute__((address_space(1))) void*)g,
                                   (__attribute__((address_space(3))) void*)l,
                                   16, 0, 0);
}

__device__ __forceinline__ f32x4 mfma16x32(bf16x8 a, bf16x8 b, f32x4 c) {
  return __builtin_amdgcn_mfma_f32_16x16x32_bf16(a, b, c, 0, 0, 0);
}

// ---------------------------------------------------------------- prep kernels

__global__ __launch_bounds__(256) void k_embed(const int* __restrict__ x,
                                               const float* __restrict__ emb,
                                               float* __restrict__ h) {
  const int n = blockIdx.x, t = threadIdx.x;
  const int tok = x[n];
  reinterpret_cast<float4*>(h + (size_t)n * DMODEL)[t] =
      reinterpret_cast<const float4*>(emb + (size_t)tok * DMODEL)[t];
}

__global__ void k_rope(float* __restrict__ ct, float* __restrict__ st) {
  const int n = blockIdx.x, p = threadIdx.x;  // 32 freq pairs
  const double inv = exp(-(double)(2 * p) / 64.0 * log(10000.0));
  const double a = (double)n * inv;
  ct[n * 32 + p] = (float)cos(a);
  st[n * 32 + p] = (float)sin(a);
}

// f32 [K][Nc] -> bf16 [Nc][K]; 64x64 tiles, float4 reads, ushort4 writes.
__global__ __launch_bounds__(256) void k_transpose(const float* __restrict__ in0,
                                                   u16* __restrict__ out0,
                                                   int K, int Nc,
                                                   size_t ls_in, size_t ls_out) {
  const float* in = in0 + blockIdx.z * ls_in;
  u16* out = out0 + blockIdx.z * ls_out;
  __shared__ float tile[64][65];
  const int kb = blockIdx.x * 64, nb = blockIdx.y * 64;
  const int tr = threadIdx.x >> 4;       // 0..15
  const int tc = threadIdx.x & 15;       // 0..15
#pragma unroll
  for (int r = 0; r < 64; r += 16) {
    const float4 v = *reinterpret_cast<const float4*>(
        &in[(size_t)(kb + r + tr) * Nc + nb + tc * 4]);
    tile[r + tr][tc * 4 + 0] = v.x;
    tile[r + tr][tc * 4 + 1] = v.y;
    tile[r + tr][tc * 4 + 2] = v.z;
    tile[r + tr][tc * 4 + 3] = v.w;
  }
  __syncthreads();
#pragma unroll
  for (int r = 0; r < 64; r += 16) {
    const int n = r + tr;
    ushort4 o;
    o.x = f2bf(tile[tc * 4 + 0][n]);
    o.y = f2bf(tile[tc * 4 + 1][n]);
    o.z = f2bf(tile[tc * 4 + 2][n]);
    o.w = f2bf(tile[tc * 4 + 3][n]);
    *reinterpret_cast<ushort4*>(&out[(size_t)(nb + n) * K + kb + tc * 4]) = o;
  }
}

// rms_norm(h)*gamma -> bf16 (GEMM A input). One row per block (256 thr, float4).
__global__ __launch_bounds__(256) void k_rmsnorm(const float* __restrict__ h,
                                                 const float* __restrict__ gamma,
                                                 u16* __restrict__ out) {
  __shared__ float red[4];
  const int n = blockIdx.x, t = threadIdx.x;
  const float4 v = reinterpret_cast<const float4*>(h + (size_t)n * DMODEL)[t];
  float ss = v.x * v.x + v.y * v.y + v.z * v.z + v.w * v.w;
#pragma unroll
  for (int off = 32; off; off >>= 1) ss += __shfl_down(ss, off);
  if ((t & 63) == 0) red[t >> 6] = ss;
  __syncthreads();
  const float tot = red[0] + red[1] + red[2] + red[3];
  const float inv = 32.0f / fmaxf(sqrtf(tot), 1e-12f);  // sqrt(1024)=32
  const float4 g = reinterpret_cast<const float4*>(gamma)[t];
  ushort4 o;
  o.x = f2bf(v.x * inv * g.x);
  o.y = f2bf(v.y * inv * g.y);
  o.z = f2bf(v.z * inv * g.z);
  o.w = f2bf(v.w * inv * g.w);
  reinterpret_cast<ushort4*>(out + (size_t)n * DMODEL)[t] = o;
}

// ---------------------------------------------------------------- GEMM epilogues
#define EPI_STORE 0
#define EPI_ADD 1
#define EPI_GELU 2
#define EPI_BIAS_ADD 3
#define EPI_QKV 4

// ---------------- unified GEMM: 128x128xBK32, tri-buffer, counted vmcnt ------
// 256 thr = 4 waves (2x2), wave tile 64x64, acc 4x4 f32x4 (64 VGPR).
// LDS: 3 bufs x (A 8KB + B 8KB) = 48KB -> 3 blocks/CU (12 waves/CU TLP).
// Sync invariant (R5-R7 verified): tile t reads buf[t%3], stages buf[(t+2)%3];
// one vmcnt(4)+barrier per tile boundary (retires exactly tile t+1's 4 loads,
// tile t+2's 4 stay in flight; vmcnt(0) only at the tail).
// Staging dest lane-linear tid*16 (m104). 64B rows = 4 slots of 16B; 2-level
// swizzle slot ^ (row&3) ^ ((row>>2)&3) on SOURCE addr and READ addr (both
// sides, rule #21) -> 2 lanes/bank on frag reads (free, m136).

__device__ __forceinline__ bf16x8 ldsfragT(const char* base, int row, int lg) {
  return *reinterpret_cast<const bf16x8*>(
      base + row * 64 + (((lg ^ (row & 3) ^ ((row >> 2) & 3)) & 3) << 4));
}

template <int EPI>
__global__ __launch_bounds__(256, 3) void k_gemmT(
    const u16* __restrict__ A, const u16* __restrict__ BT, int K, int Nc,
    const float* __restrict__ bias, const float* __restrict__ add,
    float* __restrict__ outf, u16* __restrict__ outb,
    u16* __restrict__ Qr, u16* __restrict__ Kr, u16* __restrict__ VT,
    const float* __restrict__ ct, const float* __restrict__ st) {
  __shared__ alignas(16) char sm[3 * 16384];
  const int nt = K >> 5;
  const int NMB = 16;                      // M=2048 always: 16 m-blocks
  const int nwg = gridDim.x;
  int swz = blockIdx.x;
  if ((nwg & 7) == 0) swz = (swz & 7) * (nwg >> 3) + (swz >> 3);
  const int mb = swz % NMB, nb = swz / NMB;  // m-fast: B panel L2-resident
  const int m0 = mb * 128, n0 = nb * 128;

  const int tid = threadIdx.x, w = tid >> 6, lane = tid & 63;
  const int wr = w >> 1, wc = w & 1;       // 2x2 waves of 64x64
  const int lr = lane & 15, lg = lane >> 4;

  // staging: srow = tid>>2 (0..63), sslot = tid&3; dest tid*16 (lane-linear)
  const int srow = tid >> 2;
  const int gslot = (tid & 3) ^ (srow & 3) ^ ((srow >> 2) & 3);
  const u16* ga0 = A + (size_t)(m0 + srow) * K + gslot * 8;
  const u16* ga1 = A + (size_t)(m0 + 64 + srow) * K + gslot * 8;  // same swz
  const u16* gb0 = BT + (size_t)(n0 + srow) * K + gslot * 8;
  const u16* gb1 = BT + (size_t)(n0 + 64 + srow) * K + gslot * 8;
  const int ldOff = tid * 16;

#define GT_STAGE(b)                                    \
  {                                                    \
    gload16(ga0, sm + (b) * 16384 + ldOff);            \
    gload16(ga1, sm + (b) * 16384 + 4096 + ldOff);     \
    gload16(gb0, sm + (b) * 16384 + 8192 + ldOff);     \
    gload16(gb1, sm + (b) * 16384 + 12288 + ldOff);    \
    ga0 += 32; ga1 += 32; gb0 += 32; gb1 += 32;        \
  }

  GT_STAGE(0)
  GT_STAGE(1)
  asm volatile("s_waitcnt vmcnt(4)" ::: "memory");  // tile0 landed, tile1 flying
  __builtin_amdgcn_s_barrier();

  f32x4 acc[4][4] = {};
  int cur = 0, nx2 = 2;
  for (int t = 0; t < nt; ++t) {
    const char* Ab = sm + cur * 16384;
    const char* Bb = Ab + 8192;
    const bool pf = (t + 2 < nt);
    bf16x8 af[4], bf[4];
#pragma unroll
    for (int i = 0; i < 4; ++i) {
      af[i] = ldsfragT(Ab, wr * 64 + i * 16 + lr, lg);
      bf[i] = ldsfragT(Bb, wc * 64 + i * 16 + lr, lg);
    }
    if (pf) GT_STAGE(nx2)
    __builtin_amdgcn_s_setprio(1);
#pragma unroll
    for (int mi = 0; mi < 4; ++mi)
#pragma unroll
      for (int nj = 0; nj < 4; ++nj)
        acc[mi][nj] = mfma16x32(af[mi], bf[nj], acc[mi][nj]);
    __builtin_amdgcn_s_setprio(0);
    if (t + 1 < nt) {
      __builtin_amdgcn_sched_barrier(0);
      if (pf) asm volatile("s_waitcnt vmcnt(4)" ::: "memory");
      else    asm volatile("s_waitcnt vmcnt(0)" ::: "memory");
      __builtin_amdgcn_s_barrier();
      __builtin_amdgcn_sched_barrier(0);
    }
    cur = (cur == 2) ? 0 : cur + 1;
    nx2 = (nx2 == 2) ? 0 : nx2 + 1;
  }
#undef GT_STAGE

  // epilogue
  if (EPI == EPI_QKV) {
    // qkv: Nc=3072. which = col/1024 (uniform/block); wave tile = one head.
    const int which = n0 >> 10;
    const int hh = ((n0 & 1023) >> 6) + wc;       // head index
#pragma unroll
    for (int mi = 0; mi < 4; ++mi) {
#pragma unroll
      for (int nj = 0; nj < 4; ++nj) {
        const int d = nj * 16 + lr;               // 0..63 head dim
#pragma unroll
        for (int r = 0; r < 4; ++r) {
          const int row = m0 + wr * 64 + mi * 16 + lg * 4 + r;
          const float v = acc[mi][nj][r];
          if (which == 2) {
            VT[((size_t)hh * DHEAD + d) * NSEQ + row] = f2bf(v);
          } else {
            const float part = __shfl_xor(v, 1);
            const float sgn = (d & 1) ? 1.0f : -1.0f;
            const float c = ct[row * 32 + (d >> 1)];
            const float s_ = st[row * 32 + (d >> 1)];
            const u16 o = f2bf(v * c + sgn * part * s_);
            u16* dst = (which == 0) ? Qr : Kr;
            dst[((size_t)hh * NSEQ + row) * DHEAD + d] = o;
          }
        }
      }
    }
    return;
  }
#pragma unroll
  for (int mi = 0; mi < 4; ++mi) {
#pragma unroll
    for (int nj = 0; nj < 4; ++nj) {
      const int col = n0 + wc * 64 + nj * 16 + lr;
#pragma unroll
      for (int r = 0; r < 4; ++r) {
        const int row = m0 + wr * 64 + mi * 16 + lg * 4 + r;
        const size_t idx = (size_t)row * Nc + col;
        float v = acc[mi][nj][r];
        if (EPI == EPI_GELU) {
          v += bias[col];
          v = 0.5f * v * (1.0f + erff(v * 0.70710678118654752f));
          outb[idx] = f2bf(v);
        } else if (EPI == EPI_ADD) {
          outf[idx] = v + add[idx];
        } else if (EPI == EPI_BIAS_ADD) {
          outf[idx] = v + bias[col] + add[idx];
        } else {
          outf[idx] = v;
        }
      }
    }
  }
}

// ---------------------------------------------------------------- attention
__global__ __launch_bounds__(256) void k_attn(const u16* __restrict__ Qr,
                                              const u16* __restrict__ Kr,
                                              const u16* __restrict__ VT,
                                              u16* __restrict__ O) {
  __shared__ alignas(16) u16 Pl[4][16 * 32];
  const int hh = blockIdx.y;
  const int w = threadIdx.x >> 6, lane = threadIdx.x & 63;
  const int lr = lane & 15, lg = lane >> 4;
  const int q0 = blockIdx.x * 64 + w * 16;
  const u16* Qh = Qr + (size_t)hh * NSEQ * DHEAD;
  const u16* Kh = Kr + (size_t)hh * NSEQ * DHEAD;
  const u16* Vh = VT + (size_t)hh * DHEAD * NSEQ;
  u16* Pw = Pl[w];

  const bf16x8 aq0 = *reinterpret_cast<const bf16x8*>(Qh + (q0 + lr) * DHEAD + lg * 8);
  const bf16x8 aq1 = *reinterpret_cast<const bf16x8*>(Qh + (q0 + lr) * DHEAD + 32 + lg * 8);

  f32x4 o0 = {}, o1 = {}, o2 = {}, o3 = {};
  float m[4], l[4];
#pragma unroll
  for (int r = 0; r < 4; ++r) { m[r] = -1e30f; l[r] = 0.0f; }

  const int jend = q0 + 15;
  for (int j0 = 0; j0 <= jend; j0 += 32) {
    f32x4 s0 = {}, s1 = {};
    {
      bf16x8 bk;
      bk = *reinterpret_cast<const bf16x8*>(Kh + (j0 + lr) * DHEAD + lg * 8);
      s0 = mfma16x32(aq0, bk, s0);
      bk = *reinterpret_cast<const bf16x8*>(Kh + (j0 + lr) * DHEAD + 32 + lg * 8);
      s0 = mfma16x32(aq1, bk, s0);
      bk = *reinterpret_cast<const bf16x8*>(Kh + (j0 + 16 + lr) * DHEAD + lg * 8);
      s1 = mfma16x32(aq0, bk, s1);
      bk = *reinterpret_cast<const bf16x8*>(Kh + (j0 + 16 + lr) * DHEAD + 32 + lg * 8);
      s1 = mfma16x32(aq1, bk, s1);
    }
    float sv0[4], sv1[4], pm[4];
#pragma unroll
    for (int r = 0; r < 4; ++r) {
      const int irow = q0 + lg * 4 + r;
      sv0[r] = (j0 + lr > irow) ? -1e30f : s0[r] * 0.125f;
      sv1[r] = (j0 + 16 + lr > irow) ? -1e30f : s1[r] * 0.125f;
      pm[r] = fmaxf(sv0[r], sv1[r]);
    }
#pragma unroll
    for (int off = 1; off < 16; off <<= 1)
#pragma unroll
      for (int r = 0; r < 4; ++r) pm[r] = fmaxf(pm[r], __shfl_xor(pm[r], off));
    float p0[4], p1[4], rs[4];
    f32x4 fv;
#pragma unroll
    for (int r = 0; r < 4; ++r) {
      const float mn = fmaxf(m[r], pm[r]);
      fv[r] = __expf(m[r] - mn);
      m[r] = mn;
      p0[r] = __expf(sv0[r] - mn);
      p1[r] = __expf(sv1[r] - mn);
      rs[r] = p0[r] + p1[r];
    }
#pragma unroll
    for (int off = 1; off < 16; off <<= 1)
#pragma unroll
      for (int r = 0; r < 4; ++r) rs[r] += __shfl_xor(rs[r], off);
#pragma unroll
    for (int r = 0; r < 4; ++r) l[r] = l[r] * fv[r] + rs[r];
    o0 *= fv; o1 *= fv; o2 *= fv; o3 *= fv;

#pragma unroll
    for (int r = 0; r < 4; ++r) {
      Pw[(lg * 4 + r) * 32 + lr] = f2bf(p0[r]);
      Pw[(lg * 4 + r) * 32 + 16 + lr] = f2bf(p1[r]);
    }
    const bf16x8 pa = *reinterpret_cast<const bf16x8*>(Pw + lr * 32 + lg * 8);
    const u16* vb = Vh + j0 + lg * 8;
    o0 = mfma16x32(pa, *reinterpret_cast<const bf16x8*>(vb + (0 + lr) * NSEQ), o0);
    o1 = mfma16x32(pa, *reinterpret_cast<const bf16x8*>(vb + (16 + lr) * NSEQ), o1);
    o2 = mfma16x32(pa, *reinterpret_cast<const bf16x8*>(vb + (32 + lr) * NSEQ), o2);
    o3 = mfma16x32(pa, *reinterpret_cast<const bf16x8*>(vb + (48 + lr) * NSEQ), o3);
  }

#pragma unroll
  for (int r = 0; r < 4; ++r) {
    const int row = q0 + lg * 4 + r;
    const float invl = 1.0f / l[r];
    u16* orow = O + (size_t)row * DMODEL + hh * DHEAD;
    orow[0 * 16 + lr] = f2bf(o0[r] * invl);
    orow[1 * 16 + lr] = f2bf(o1[r] * invl);
    orow[2 * 16 + lr] = f2bf(o2[r] * invl);
    orow[3 * 16 + lr] = f2bf(o3[r] * invl);
  }
}

// ---------------------------------------------------------------- launch

extern "C" void kernel_launch(void* const* d_in, const int* in_sizes, int n_in,
                              void* d_out, int out_size, void* d_ws, size_t ws_size,
                              hipStream_t stream) {
  (void)in_sizes; (void)n_in;
  const int* x = (const int*)d_in[0];
  const float* emb = (const float*)d_in[1];
  const float* attn_gamma = (const float*)d_in[2];
  const float* w_qkv = (const float*)d_in[3];
  const float* w_attn_out = (const float*)d_in[4];
  const float* ff_gamma = (const float*)d_in[5];
  const float* w_ff1 = (const float*)d_in[6];
  const float* b_ff1 = (const float*)d_in[7];
  const float* w_ff2 = (const float*)d_in[8];
  const float* b_ff2 = (const float*)d_in[9];
  const float* final_gamma = (const float*)d_in[10];
  const float* w_logits = (const float*)d_in[11];
  float* out = (float*)d_out;

  const size_t EARLY_NEED = 176ull << 20;
  const size_t FINAL_NEED = 72ull << 20;
  char* earlyBase;
  char* finalBase;
  if (ws_size >= EARLY_NEED + FINAL_NEED) {
    earlyBase = (char*)d_ws;
    finalBase = (char*)d_ws + EARLY_NEED;
  } else if (ws_size >= FINAL_NEED && (size_t)out_size * 4 >= EARLY_NEED) {
    earlyBase = (char*)d_out;
    finalBase = (char*)d_ws;
  } else {
    return;
  }
  size_t eoff = 0, foff = 0;
  auto ealloc = [&](size_t b) { void* p = earlyBase + eoff; eoff += (b + 255) & ~(size_t)255; return p; };
  auto falloc = [&](size_t b) { void* p = finalBase + foff; foff += (b + 255) & ~(size_t)255; return p; };

  u16* wqkvT = (u16*)ealloc((size_t)NLAYER * 3072 * DMODEL * 2);
  u16* wattnT = (u16*)ealloc((size_t)NLAYER * DMODEL * DMODEL * 2);
  u16* wff1T = (u16*)ealloc((size_t)NLAYER * FFD * DMODEL * 2);
  u16* wff2T = (u16*)ealloc((size_t)NLAYER * DMODEL * FFD * 2);
  float* h = (float*)ealloc((size_t)NSEQ * DMODEL * 4);
  u16* Qr = (u16*)ealloc((size_t)NH * NSEQ * DHEAD * 2);
  u16* Kr = (u16*)ealloc((size_t)NH * NSEQ * DHEAD * 2);
  u16* VTb = (u16*)ealloc((size_t)NH * NSEQ * DHEAD * 2);
  u16* Ob = (u16*)ealloc((size_t)NSEQ * DMODEL * 2);
  u16* ff1b = (u16*)ealloc((size_t)NSEQ * FFD * 2);
  float* ct = (float*)ealloc((size_t)NSEQ * 32 * 4);
  float* st = (float*)ealloc((size_t)NSEQ * 32 * 4);
  u16* wlogT = (u16*)falloc((size_t)VOC * DMODEL * 2);
  u16* xn = (u16*)falloc((size_t)NSEQ * DMODEL * 2);

  k_rope<<<dim3(NSEQ), dim3(32), 0, stream>>>(ct, st);
  k_transpose<<<dim3(16, 48, NLAYER), 256, 0, stream>>>(
      w_qkv, wqkvT, DMODEL, 3072, (size_t)DMODEL * 3072, (size_t)3072 * DMODEL);
  k_transpose<<<dim3(16, 16, NLAYER), 256, 0, stream>>>(
      w_attn_out, wattnT, DMODEL, DMODEL, (size_t)DMODEL * DMODEL, (size_t)DMODEL * DMODEL);
  k_transpose<<<dim3(16, 64, NLAYER), 256, 0, stream>>>(
      w_ff1, wff1T, DMODEL, FFD, (size_t)DMODEL * FFD, (size_t)FFD * DMODEL);
  k_transpose<<<dim3(64, 16, NLAYER), 256, 0, stream>>>(
      w_ff2, wff2T, FFD, DMODEL, (size_t)FFD * DMODEL, (size_t)DMODEL * FFD);
  k_transpose<<<dim3(16, 500, 1), 256, 0, stream>>>(
      w_logits, wlogT, DMODEL, VOC, 0, 0);

  k_embed<<<dim3(NSEQ), 256, 0, stream>>>(x, emb, h);

  for (int lyr = 0; lyr < NLAYER; ++lyr) {
    k_rmsnorm<<<dim3(NSEQ), 256, 0, stream>>>(h, attn_gamma + (size_t)lyr * DMODEL, xn);
    k_gemmT<EPI_QKV><<<dim3(16 * 24), 256, 0, stream>>>(
        xn, wqkvT + (size_t)lyr * 3072 * DMODEL, DMODEL, 3072,
        nullptr, nullptr, nullptr, nullptr, Qr, Kr, VTb, ct, st);
    k_attn<<<dim3(NSEQ / 64, NH), 256, 0, stream>>>(Qr, Kr, VTb, Ob);
    k_gemmT<EPI_ADD><<<dim3(16 * 8), 256, 0, stream>>>(
        Ob, wattnT + (size_t)lyr * DMODEL * DMODEL, DMODEL, DMODEL,
        nullptr, h, h, nullptr, nullptr, nullptr, nullptr, nullptr, nullptr);
    k_rmsnorm<<<dim3(NSEQ), 256, 0, stream>>>(h, ff_gamma + (size_t)lyr * DMODEL, xn);
    k_gemmT<EPI_GELU><<<dim3(16 * 32), 256, 0, stream>>>(
        xn, wff1T + (size_t)lyr * FFD * DMODEL, DMODEL, FFD,
        b_ff1 + (size_t)lyr * FFD, nullptr, nullptr, ff1b,
        nullptr, nullptr, nullptr, nullptr, nullptr);
    k_gemmT<EPI_BIAS_ADD><<<dim3(16 * 8), 256, 0, stream>>>(
        ff1b, wff2T + (size_t)lyr * DMODEL * FFD, FFD, DMODEL,
        b_ff2 + (size_t)lyr * DMODEL, h, h, nullptr,
        nullptr, nullptr, nullptr, nullptr, nullptr);
  }

  k_rmsnorm<<<dim3(NSEQ), 256, 0, stream>>>(h, final_gamma, xn);
  k_gemmT<EPI_STORE><<<dim3(16 * 250), 256, 0, stream>>>(
      xn, wlogT, DMODEL, VOC,
      nullptr, nullptr, out, nullptr, nullptr, nullptr, nullptr, nullptr, nullptr);
}

// Round 9
// 1370.741 us; speedup vs baseline: 1.2048x; 1.0022x over previous
//
#include <hip/hip_runtime.h>
#include <math.h>

// Decoder forward, MI355X gfx950. Round 9: k_gemmW (wave tile 64x128, better
// FLOP/LDS-byte) for logits+ff1; k_gemmT<BM=64> for N=1024 GEMMs (full-GPU
// 256-block grids). Same verified triple-buffer counted-vmcnt skeleton.
//
// Dims (fixed): V=32000 D=1024 DEPTH=4 H=16 DH=64 FF=4096 B=1 N=2048

#define NSEQ 2048
#define DMODEL 1024
#define NH 16
#define DHEAD 64
#define FFD 4096
#define VOC 32000
#define NLAYER 4

typedef unsigned short u16;
typedef short bf16x8 __attribute__((ext_vector_type(8)));   // 8 bf16 in 4 VGPRs
typedef float f32x4 __attribute__((ext_vector_type(4)));

__device__ __forceinline__ u16 f2bf(float f) {
  unsigned int u = __builtin_bit_cast(unsigned int, f);
  u += 0x7fffu + ((u >> 16) & 1u);   // RNE
  return (u16)(u >> 16);
}

__device__ __forceinline__ void gload16(const void* g, void* l) {
  __builtin_amdgcn_global_load_lds((__attribute__((address_space(1))) void*)g,
                                   (__attribute__((address_space(3))) void*)l,
                                   16, 0, 0);
}

__device__ __forceinline__ f32x4 mfma16x32(bf16x8 a, bf16x8 b, f32x4 c) {
  return __builtin_amdgcn_mfma_f32_16x16x32_bf16(a, b, c, 0, 0, 0);
}

template <int N>
__device__ __forceinline__ void waitvm() {
  if constexpr (N == 0) asm volatile("s_waitcnt vmcnt(0)" ::: "memory");
  else if constexpr (N == 3) asm volatile("s_waitcnt vmcnt(3)" ::: "memory");
  else if constexpr (N == 4) asm volatile("s_waitcnt vmcnt(4)" ::: "memory");
  else if constexpr (N == 6) asm volatile("s_waitcnt vmcnt(6)" ::: "memory");
}

// ---------------------------------------------------------------- prep kernels

__global__ __launch_bounds__(256) void k_embed(const int* __restrict__ x,
                                               const float* __restrict__ emb,
                                               float* __restrict__ h) {
  const int n = blockIdx.x, t = threadIdx.x;
  const int tok = x[n];
  reinterpret_cast<float4*>(h + (size_t)n * DMODEL)[t] =
      reinterpret_cast<const float4*>(emb + (size_t)tok * DMODEL)[t];
}

__global__ void k_rope(float* __restrict__ ct, float* __restrict__ st) {
  const int n = blockIdx.x, p = threadIdx.x;  // 32 freq pairs
  const double inv = exp(-(double)(2 * p) / 64.0 * log(10000.0));
  const double a = (double)n * inv;
  ct[n * 32 + p] = (float)cos(a);
  st[n * 32 + p] = (float)sin(a);
}

// f32 [K][Nc] -> bf16 [Nc][K]; 64x64 tiles, float4 reads, ushort4 writes.
__global__ __launch_bounds__(256) void k_transpose(const float* __restrict__ in0,
                                                   u16* __restrict__ out0,
                                                   int K, int Nc,
                                                   size_t ls_in, size_t ls_out) {
  const float* in = in0 + blockIdx.z * ls_in;
  u16* out = out0 + blockIdx.z * ls_out;
  __shared__ float tile[64][65];
  const int kb = blockIdx.x * 64, nb = blockIdx.y * 64;
  const int tr = threadIdx.x >> 4;       // 0..15
  const int tc = threadIdx.x & 15;       // 0..15
#pragma unroll
  for (int r = 0; r < 64; r += 16) {
    const float4 v = *reinterpret_cast<const float4*>(
        &in[(size_t)(kb + r + tr) * Nc + nb + tc * 4]);
    tile[r + tr][tc * 4 + 0] = v.x;
    tile[r + tr][tc * 4 + 1] = v.y;
    tile[r + tr][tc * 4 + 2] = v.z;
    tile[r + tr][tc * 4 + 3] = v.w;
  }
  __syncthreads();
#pragma unroll
  for (int r = 0; r < 64; r += 16) {
    const int n = r + tr;
    ushort4 o;
    o.x = f2bf(tile[tc * 4 + 0][n]);
    o.y = f2bf(tile[tc * 4 + 1][n]);
    o.z = f2bf(tile[tc * 4 + 2][n]);
    o.w = f2bf(tile[tc * 4 + 3][n]);
    *reinterpret_cast<ushort4*>(&out[(size_t)(nb + n) * K + kb + tc * 4]) = o;
  }
}

// rms_norm(h)*gamma -> bf16 (GEMM A input). One row per block (256 thr, float4).
__global__ __launch_bounds__(256) void k_rmsnorm(const float* __restrict__ h,
                                                 const float* __restrict__ gamma,
                                                 u16* __restrict__ out) {
  __shared__ float red[4];
  const int n = blockIdx.x, t = threadIdx.x;
  const float4 v = reinterpret_cast<const float4*>(h + (size_t)n * DMODEL)[t];
  float ss = v.x * v.x + v.y * v.y + v.z * v.z + v.w * v.w;
#pragma unroll
  for (int off = 32; off; off >>= 1) ss += __shfl_down(ss, off);
  if ((t & 63) == 0) red[t >> 6] = ss;
  __syncthreads();
  const float tot = red[0] + red[1] + red[2] + red[3];
  const float inv = 32.0f / fmaxf(sqrtf(tot), 1e-12f);  // sqrt(1024)=32
  const float4 g = reinterpret_cast<const float4*>(gamma)[t];
  ushort4 o;
  o.x = f2bf(v.x * inv * g.x);
  o.y = f2bf(v.y * inv * g.y);
  o.z = f2bf(v.z * inv * g.z);
  o.w = f2bf(v.w * inv * g.w);
  reinterpret_cast<ushort4*>(out + (size_t)n * DMODEL)[t] = o;
}

// ---------------------------------------------------------------- GEMM epilogues
#define EPI_STORE 0
#define EPI_ADD 1
#define EPI_GELU 2
#define EPI_BIAS_ADD 3
#define EPI_QKV 4

// 64B rows = 4 slots of 16B; 2-level swizzle on SOURCE and READ (both sides).
__device__ __forceinline__ bf16x8 ldsfragT(const char* base, int row, int lg) {
  return *reinterpret_cast<const bf16x8*>(
      base + row * 64 + (((lg ^ (row & 3) ^ ((row >> 2) & 3)) & 3) << 4));
}

// ---------------- k_gemmT: BMx128xBK32, tri-buffer, counted vmcnt ------------
// BM=128: 4 waves 2x2, wave 64x64, LDS 48KB -> 3 blk/CU. BM=64: wave 32x64,
// LDS 36KB -> 4 blk/CU (full-GPU grids for N=1024 shapes).
// Sync invariant (R5-R8 verified): tile t reads buf[t%3], stages buf[(t+2)%3];
// one vmcnt(NLD)+barrier per boundary; vmcnt(0) only at tail.
template <int EPI, int BM>
__global__ __launch_bounds__(256) void k_gemmT(
    const u16* __restrict__ A, const u16* __restrict__ BT, int K, int Nc,
    int NMB, const float* __restrict__ bias, const float* __restrict__ add,
    float* __restrict__ outf, u16* __restrict__ outb,
    u16* __restrict__ Qr, u16* __restrict__ Kr, u16* __restrict__ VT,
    const float* __restrict__ ct, const float* __restrict__ st) {
  constexpr int MFR = BM / 32;            // A frags per wave
  constexpr int ABYTES = BM * 64;         // BM rows x 32 k x 2B
  constexpr int BUFB = ABYTES + 8192;
  constexpr int NLD = (BM == 128) ? 4 : 3;
  __shared__ alignas(16) char sm[3 * BUFB];
  const int nt = K >> 5;
  const int nwg = gridDim.x;
  int swz = blockIdx.x;
  if ((nwg & 7) == 0) swz = (swz & 7) * (nwg >> 3) + (swz >> 3);
  const int mb = swz % NMB, nb = swz / NMB;  // m-fast: B panel L2-resident
  const int m0 = mb * BM, n0 = nb * 128;

  const int tid = threadIdx.x, w = tid >> 6, lane = tid & 63;
  const int wr = w >> 1, wc = w & 1;
  const int lr = lane & 15, lg = lane >> 4;

  const int srow = tid >> 2;
  const int gslot = (tid & 3) ^ (srow & 3) ^ ((srow >> 2) & 3);
  const u16* ga0 = A + (size_t)(m0 + srow) * K + gslot * 8;
  const u16* ga1 = A + (size_t)(m0 + (BM == 128 ? 64 : 0) + srow) * K + gslot * 8;
  const u16* gb0 = BT + (size_t)(n0 + srow) * K + gslot * 8;
  const u16* gb1 = BT + (size_t)(n0 + 64 + srow) * K + gslot * 8;
  const int ldOff = tid * 16;             // lane-linear dest (m104)

  auto stage = [&](int b) {
    char* base = sm + b * BUFB;
    gload16(ga0, base + ldOff);
    if constexpr (BM == 128) gload16(ga1, base + 4096 + ldOff);
    gload16(gb0, base + ABYTES + ldOff);
    gload16(gb1, base + ABYTES + 4096 + ldOff);
    ga0 += 32; gb0 += 32; gb1 += 32;
    if constexpr (BM == 128) ga1 += 32;
  };

  stage(0);
  stage(1);
  waitvm<NLD>();
  __builtin_amdgcn_s_barrier();

  f32x4 acc[MFR][4] = {};
  int cur = 0, nx2 = 2;
  for (int t = 0; t < nt; ++t) {
    const char* Ab = sm + cur * BUFB;
    const char* Bb = Ab + ABYTES;
    const bool pf = (t + 2 < nt);
    bf16x8 af[MFR], bf[4];
#pragma unroll
    for (int i = 0; i < MFR; ++i)
      af[i] = ldsfragT(Ab, wr * (BM / 2) + i * 16 + lr, lg);
#pragma unroll
    for (int i = 0; i < 4; ++i)
      bf[i] = ldsfragT(Bb, wc * 64 + i * 16 + lr, lg);
    if (pf) stage(nx2);
    __builtin_amdgcn_s_setprio(1);
#pragma unroll
    for (int mi = 0; mi < MFR; ++mi)
#pragma unroll
      for (int nj = 0; nj < 4; ++nj)
        acc[mi][nj] = mfma16x32(af[mi], bf[nj], acc[mi][nj]);
    __builtin_amdgcn_s_setprio(0);
    if (t + 1 < nt) {
      __builtin_amdgcn_sched_barrier(0);
      if (pf) waitvm<NLD>();
      else    waitvm<0>();
      __builtin_amdgcn_s_barrier();
      __builtin_amdgcn_sched_barrier(0);
    }
    cur = (cur == 2) ? 0 : cur + 1;
    nx2 = (nx2 == 2) ? 0 : nx2 + 1;
  }

  if constexpr (EPI == EPI_QKV) {
    // qkv: Nc=3072; wave tile = one head (64 cols). which = col block /1024.
    const int which = n0 >> 10;
    const int hh = ((n0 & 1023) >> 6) + wc;
#pragma unroll
    for (int mi = 0; mi < MFR; ++mi) {
#pragma unroll
      for (int nj = 0; nj < 4; ++nj) {
        const int d = nj * 16 + lr;
#pragma unroll
        for (int r = 0; r < 4; ++r) {
          const int row = m0 + wr * (BM / 2) + mi * 16 + lg * 4 + r;
          const float v = acc[mi][nj][r];
          if (which == 2) {
            VT[((size_t)hh * DHEAD + d) * NSEQ + row] = f2bf(v);
          } else {
            const float part = __shfl_xor(v, 1);
            const float sgn = (d & 1) ? 1.0f : -1.0f;
            const float c = ct[row * 32 + (d >> 1)];
            const float s_ = st[row * 32 + (d >> 1)];
            const u16 o = f2bf(v * c + sgn * part * s_);
            u16* dst = (which == 0) ? Qr : Kr;
            dst[((size_t)hh * NSEQ + row) * DHEAD + d] = o;
          }
        }
      }
    }
    return;
  }
#pragma unroll
  for (int mi = 0; mi < MFR; ++mi) {
#pragma unroll
    for (int nj = 0; nj < 4; ++nj) {
      const int col = n0 + wc * 64 + nj * 16 + lr;
#pragma unroll
      for (int r = 0; r < 4; ++r) {
        const int row = m0 + wr * (BM / 2) + mi * 16 + lg * 4 + r;
        const size_t idx = (size_t)row * Nc + col;
        float v = acc[mi][nj][r];
        if (EPI == EPI_GELU) {
          v += bias[col];
          v = 0.5f * v * (1.0f + erff(v * 0.70710678118654752f));
          outb[idx] = f2bf(v);
        } else if (EPI == EPI_ADD) {
          outf[idx] = v + add[idx];
        } else if (EPI == EPI_BIAS_ADD) {
          outf[idx] = v + bias[col] + add[idx];
        } else {
          outf[idx] = v;
        }
      }
    }
  }
}

// ---------------- k_gemmW: 128x256xBK32, wave tile 64x128 --------------------
// 4 waves 2x2; acc[4][8]; 12 LDS reads per 32 MFMAs (0.375 KB/MFMA vs 0.5 in
// k_gemmT). LDS 3 x 24KB = 72KB -> 2 blk/CU. Same sync skeleton, vmcnt(6).
template <int EPI>
__global__ __launch_bounds__(256, 2) void k_gemmW(
    const u16* __restrict__ A, const u16* __restrict__ BT, int K, int Nc,
    const float* __restrict__ bias, float* __restrict__ outf,
    u16* __restrict__ outb) {
  constexpr int ABYTES = 8192;            // 128 rows x 32 k x 2B
  constexpr int BUFB = ABYTES + 16384;    // + 256 rows B
  __shared__ alignas(16) char sm[3 * BUFB];
  const int nt = K >> 5;
  const int NMB = 16;
  const int nwg = gridDim.x;
  int swz = blockIdx.x;
  if ((nwg & 7) == 0) swz = (swz & 7) * (nwg >> 3) + (swz >> 3);
  const int mb = swz % NMB, nb = swz / NMB;
  const int m0 = mb * 128, n0 = nb * 256;

  const int tid = threadIdx.x, w = tid >> 6, lane = tid & 63;
  const int wr = w >> 1, wc = w & 1;      // wave tile 64 x 128
  const int lr = lane & 15, lg = lane >> 4;

  const int srow = tid >> 2;
  const int gslot = (tid & 3) ^ (srow & 3) ^ ((srow >> 2) & 3);
  const u16* ga0 = A + (size_t)(m0 + srow) * K + gslot * 8;
  const u16* ga1 = A + (size_t)(m0 + 64 + srow) * K + gslot * 8;
  const u16* gb0 = BT + (size_t)(n0 + srow) * K + gslot * 8;
  const u16* gb1 = BT + (size_t)(n0 + 64 + srow) * K + gslot * 8;
  const u16* gb2 = BT + (size_t)(n0 + 128 + srow) * K + gslot * 8;
  const u16* gb3 = BT + (size_t)(n0 + 192 + srow) * K + gslot * 8;
  const int ldOff = tid * 16;

  auto stage = [&](int b) {
    char* base = sm + b * BUFB;
    gload16(ga0, base + ldOff);
    gload16(ga1, base + 4096 + ldOff);
    gload16(gb0, base + ABYTES + ldOff);
    gload16(gb1, base + ABYTES + 4096 + ldOff);
    gload16(gb2, base + ABYTES + 8192 + ldOff);
    gload16(gb3, base + ABYTES + 12288 + ldOff);
    ga0 += 32; ga1 += 32; gb0 += 32; gb1 += 32; gb2 += 32; gb3 += 32;
  };

  stage(0);
  stage(1);
  waitvm<6>();
  __builtin_amdgcn_s_barrier();

  f32x4 acc[4][8] = {};
  int cur = 0, nx2 = 2;
  for (int t = 0; t < nt; ++t) {
    const char* Ab = sm + cur * BUFB;
    const char* Bb = Ab + ABYTES;
    const bool pf = (t + 2 < nt);
    bf16x8 af[4], bf[8];
#pragma unroll
    for (int i = 0; i < 4; ++i)
      af[i] = ldsfragT(Ab, wr * 64 + i * 16 + lr, lg);
#pragma unroll
    for (int i = 0; i < 8; ++i)
      bf[i] = ldsfragT(Bb, wc * 128 + i * 16 + lr, lg);
    if (pf) stage(nx2);
    __builtin_amdgcn_s_setprio(1);
#pragma unroll
    for (int mi = 0; mi < 4; ++mi)
#pragma unroll
      for (int nj = 0; nj < 8; ++nj)
        acc[mi][nj] = mfma16x32(af[mi], bf[nj], acc[mi][nj]);
    __builtin_amdgcn_s_setprio(0);
    if (t + 1 < nt) {
      __builtin_amdgcn_sched_barrier(0);
      if (pf) waitvm<6>();
      else    waitvm<0>();
      __builtin_amdgcn_s_barrier();
      __builtin_amdgcn_sched_barrier(0);
    }
    cur = (cur == 2) ? 0 : cur + 1;
    nx2 = (nx2 == 2) ? 0 : nx2 + 1;
  }

#pragma unroll
  for (int mi = 0; mi < 4; ++mi) {
#pragma unroll
    for (int nj = 0; nj < 8; ++nj) {
      const int col = n0 + wc * 128 + nj * 16 + lr;
#pragma unroll
      for (int r = 0; r < 4; ++r) {
        const int row = m0 + wr * 64 + mi * 16 + lg * 4 + r;
        const size_t idx = (size_t)row * Nc + col;
        float v = acc[mi][nj][r];
        if (EPI == EPI_GELU) {
          v += bias[col];
          v = 0.5f * v * (1.0f + erff(v * 0.70710678118654752f));
          outb[idx] = f2bf(v);
        } else {
          outf[idx] = v;
        }
      }
    }
  }
}

// ---------------------------------------------------------------- attention
__global__ __launch_bounds__(256) void k_attn(const u16* __restrict__ Qr,
                                              const u16* __restrict__ Kr,
                                              const u16* __restrict__ VT,
                                              u16* __restrict__ O) {
  __shared__ alignas(16) u16 Pl[4][16 * 32];
  const int hh = blockIdx.y;
  const int w = threadIdx.x >> 6, lane = threadIdx.x & 63;
  const int lr = lane & 15, lg = lane >> 4;
  const int q0 = blockIdx.x * 64 + w * 16;
  const u16* Qh = Qr + (size_t)hh * NSEQ * DHEAD;
  const u16* Kh = Kr + (size_t)hh * NSEQ * DHEAD;
  const u16* Vh = VT + (size_t)hh * DHEAD * NSEQ;
  u16* Pw = Pl[w];

  const bf16x8 aq0 = *reinterpret_cast<const bf16x8*>(Qh + (q0 + lr) * DHEAD + lg * 8);
  const bf16x8 aq1 = *reinterpret_cast<const bf16x8*>(Qh + (q0 + lr) * DHEAD + 32 + lg * 8);

  f32x4 o0 = {}, o1 = {}, o2 = {}, o3 = {};
  float m[4], l[4];
#pragma unroll
  for (int r = 0; r < 4; ++r) { m[r] = -1e30f; l[r] = 0.0f; }

  const int jend = q0 + 15;
  for (int j0 = 0; j0 <= jend; j0 += 32) {
    f32x4 s0 = {}, s1 = {};
    {
      bf16x8 bk;
      bk = *reinterpret_cast<const bf16x8*>(Kh + (j0 + lr) * DHEAD + lg * 8);
      s0 = mfma16x32(aq0, bk, s0);
      bk = *reinterpret_cast<const bf16x8*>(Kh + (j0 + lr) * DHEAD + 32 + lg * 8);
      s0 = mfma16x32(aq1, bk, s0);
      bk = *reinterpret_cast<const bf16x8*>(Kh + (j0 + 16 + lr) * DHEAD + lg * 8);
      s1 = mfma16x32(aq0, bk, s1);
      bk = *reinterpret_cast<const bf16x8*>(Kh + (j0 + 16 + lr) * DHEAD + 32 + lg * 8);
      s1 = mfma16x32(aq1, bk, s1);
    }
    float sv0[4], sv1[4], pm[4];
#pragma unroll
    for (int r = 0; r < 4; ++r) {
      const int irow = q0 + lg * 4 + r;
      sv0[r] = (j0 + lr > irow) ? -1e30f : s0[r] * 0.125f;
      sv1[r] = (j0 + 16 + lr > irow) ? -1e30f : s1[r] * 0.125f;
      pm[r] = fmaxf(sv0[r], sv1[r]);
    }
#pragma unroll
    for (int off = 1; off < 16; off <<= 1)
#pragma unroll
      for (int r = 0; r < 4; ++r) pm[r] = fmaxf(pm[r], __shfl_xor(pm[r], off));
    float p0[4], p1[4], rs[4];
    f32x4 fv;
#pragma unroll
    for (int r = 0; r < 4; ++r) {
      const float mn = fmaxf(m[r], pm[r]);
      fv[r] = __expf(m[r] - mn);
      m[r] = mn;
      p0[r] = __expf(sv0[r] - mn);
      p1[r] = __expf(sv1[r] - mn);
      rs[r] = p0[r] + p1[r];
    }
#pragma unroll
    for (int off = 1; off < 16; off <<= 1)
#pragma unroll
      for (int r = 0; r < 4; ++r) rs[r] += __shfl_xor(rs[r], off);
#pragma unroll
    for (int r = 0; r < 4; ++r) l[r] = l[r] * fv[r] + rs[r];
    o0 *= fv; o1 *= fv; o2 *= fv; o3 *= fv;

#pragma unroll
    for (int r = 0; r < 4; ++r) {
      Pw[(lg * 4 + r) * 32 + lr] = f2bf(p0[r]);
      Pw[(lg * 4 + r) * 32 + 16 + lr] = f2bf(p1[r]);
    }
    const bf16x8 pa = *reinterpret_cast<const bf16x8*>(Pw + lr * 32 + lg * 8);
    const u16* vb = Vh + j0 + lg * 8;
    o0 = mfma16x32(pa, *reinterpret_cast<const bf16x8*>(vb + (0 + lr) * NSEQ), o0);
    o1 = mfma16x32(pa, *reinterpret_cast<const bf16x8*>(vb + (16 + lr) * NSEQ), o1);
    o2 = mfma16x32(pa, *reinterpret_cast<const bf16x8*>(vb + (32 + lr) * NSEQ), o2);
    o3 = mfma16x32(pa, *reinterpret_cast<const bf16x8*>(vb + (48 + lr) * NSEQ), o3);
  }

#pragma unroll
  for (int r = 0; r < 4; ++r) {
    const int row = q0 + lg * 4 + r;
    const float invl = 1.0f / l[r];
    u16* orow = O + (size_t)row * DMODEL + hh * DHEAD;
    orow[0 * 16 + lr] = f2bf(o0[r] * invl);
    orow[1 * 16 + lr] = f2bf(o1[r] * invl);
    orow[2 * 16 + lr] = f2bf(o2[r] * invl);
    orow[3 * 16 + lr] = f2bf(o3[r] * invl);
  }
}

// ---------------------------------------------------------------- launch

extern "C" void kernel_launch(void* const* d_in, const int* in_sizes, int n_in,
                              void* d_out, int out_size, void* d_ws, size_t ws_size,
                              hipStream_t stream) {
  (void)in_sizes; (void)n_in;
  const int* x = (const int*)d_in[0];
  const float* emb = (const float*)d_in[1];
  const float* attn_gamma = (const float*)d_in[2];
  const float* w_qkv = (const float*)d_in[3];
  const float* w_attn_out = (const float*)d_in[4];
  const float* ff_gamma = (const float*)d_in[5];
  const float* w_ff1 = (const float*)d_in[6];
  const float* b_ff1 = (const float*)d_in[7];
  const float* w_ff2 = (const float*)d_in[8];
  const float* b_ff2 = (const float*)d_in[9];
  const float* final_gamma = (const float*)d_in[10];
  const float* w_logits = (const float*)d_in[11];
  float* out = (float*)d_out;

  const size_t EARLY_NEED = 176ull << 20;
  const size_t FINAL_NEED = 72ull << 20;
  char* earlyBase;
  char* finalBase;
  if (ws_size >= EARLY_NEED + FINAL_NEED) {
    earlyBase = (char*)d_ws;
    finalBase = (char*)d_ws + EARLY_NEED;
  } else if (ws_size >= FINAL_NEED && (size_t)out_size * 4 >= EARLY_NEED) {
    earlyBase = (char*)d_out;
    finalBase = (char*)d_ws;
  } else {
    return;
  }
  size_t eoff = 0, foff = 0;
  auto ealloc = [&](size_t b) { void* p = earlyBase + eoff; eoff += (b + 255) & ~(size_t)255; return p; };
  auto falloc = [&](size_t b) { void* p = finalBase + foff; foff += (b + 255) & ~(size_t)255; return p; };

  u16* wqkvT = (u16*)ealloc((size_t)NLAYER * 3072 * DMODEL * 2);
  u16* wattnT = (u16*)ealloc((size_t)NLAYER * DMODEL * DMODEL * 2);
  u16* wff1T = (u16*)ealloc((size_t)NLAYER * FFD * DMODEL * 2);
  u16* wff2T = (u16*)ealloc((size_t)NLAYER * DMODEL * FFD * 2);
  float* h = (float*)ealloc((size_t)NSEQ * DMODEL * 4);
  u16* Qr = (u16*)ealloc((size_t)NH * NSEQ * DHEAD * 2);
  u16* Kr = (u16*)ealloc((size_t)NH * NSEQ * DHEAD * 2);
  u16* VTb = (u16*)ealloc((size_t)NH * NSEQ * DHEAD * 2);
  u16* Ob = (u16*)ealloc((size_t)NSEQ * DMODEL * 2);
  u16* ff1b = (u16*)ealloc((size_t)NSEQ * FFD * 2);
  float* ct = (float*)ealloc((size_t)NSEQ * 32 * 4);
  float* st = (float*)ealloc((size_t)NSEQ * 32 * 4);
  u16* wlogT = (u16*)falloc((size_t)VOC * DMODEL * 2);
  u16* xn = (u16*)falloc((size_t)NSEQ * DMODEL * 2);

  k_rope<<<dim3(NSEQ), dim3(32), 0, stream>>>(ct, st);
  k_transpose<<<dim3(16, 48, NLAYER), 256, 0, stream>>>(
      w_qkv, wqkvT, DMODEL, 3072, (size_t)DMODEL * 3072, (size_t)3072 * DMODEL);
  k_transpose<<<dim3(16, 16, NLAYER), 256, 0, stream>>>(
      w_attn_out, wattnT, DMODEL, DMODEL, (size_t)DMODEL * DMODEL, (size_t)DMODEL * DMODEL);
  k_transpose<<<dim3(16, 64, NLAYER), 256, 0, stream>>>(
      w_ff1, wff1T, DMODEL, FFD, (size_t)DMODEL * FFD, (size_t)FFD * DMODEL);
  k_transpose<<<dim3(64, 16, NLAYER), 256, 0, stream>>>(
      w_ff2, wff2T, FFD, DMODEL, (size_t)FFD * DMODEL, (size_t)DMODEL * FFD);
  k_transpose<<<dim3(16, 500, 1), 256, 0, stream>>>(
      w_logits, wlogT, DMODEL, VOC, 0, 0);

  k_embed<<<dim3(NSEQ), 256, 0, stream>>>(x, emb, h);

  for (int lyr = 0; lyr < NLAYER; ++lyr) {
    k_rmsnorm<<<dim3(NSEQ), 256, 0, stream>>>(h, attn_gamma + (size_t)lyr * DMODEL, xn);
    k_gemmT<EPI_QKV, 128><<<dim3(16 * 24), 256, 0, stream>>>(
        xn, wqkvT + (size_t)lyr * 3072 * DMODEL, DMODEL, 3072, 16,
        nullptr, nullptr, nullptr, nullptr, Qr, Kr, VTb, ct, st);
    k_attn<<<dim3(NSEQ / 64, NH), 256, 0, stream>>>(Qr, Kr, VTb, Ob);
    k_gemmT<EPI_ADD, 64><<<dim3(32 * 8), 256, 0, stream>>>(
        Ob, wattnT + (size_t)lyr * DMODEL * DMODEL, DMODEL, DMODEL, 32,
        nullptr, h, h, nullptr, nullptr, nullptr, nullptr, nullptr, nullptr);
    k_rmsnorm<<<dim3(NSEQ), 256, 0, stream>>>(h, ff_gamma + (size_t)lyr * DMODEL, xn);
    k_gemmW<EPI_GELU><<<dim3(16 * 16), 256, 0, stream>>>(
        xn, wff1T + (size_t)lyr * FFD * DMODEL, DMODEL, FFD,
        b_ff1 + (size_t)lyr * FFD, nullptr, ff1b);
    k_gemmT<EPI_BIAS_ADD, 64><<<dim3(32 * 8), 256, 0, stream>>>(
        ff1b, wff2T + (size_t)lyr * DMODEL * FFD, FFD, DMODEL, 32,
        b_ff2 + (size_t)lyr * DMODEL, h, h, nullptr,
        nullptr, nullptr, nullptr, nullptr, nullptr);
  }

  k_rmsnorm<<<dim3(NSEQ), 256, 0, stream>>>(h, final_gamma, xn);
  k_gemmW<EPI_STORE><<<dim3(16 * 125), 256, 0, stream>>>(
      xn, wlogT, DMODEL, VOC, nullptr, out, nullptr);
}

// Round 10
// 1312.721 us; speedup vs baseline: 1.2580x; 1.0442x over previous
//
#include <hip/hip_runtime.h>
#include <math.h>

// Decoder forward, MI355X gfx950. Round 10: QUAD-buffered k_gemmT (prefetch
// lead 2 iterations ~1200cyc > HBM latency). Iteration t stages tile t+3;
// boundary vmcnt(2*SL) retires exactly tile t+1. BM=128 (64KB LDS, 2 blk/CU)
// for qkv/ff1/logits; BM=64 (48KB, 3 blk/CU) for attn_out/ff2.
//
// Dims (fixed): V=32000 D=1024 DEPTH=4 H=16 DH=64 FF=4096 B=1 N=2048

#define NSEQ 2048
#define DMODEL 1024
#define NH 16
#define DHEAD 64
#define FFD 4096
#define VOC 32000
#define NLAYER 4

typedef unsigned short u16;
typedef short bf16x8 __attribute__((ext_vector_type(8)));   // 8 bf16 in 4 VGPRs
typedef float f32x4 __attribute__((ext_vector_type(4)));

__device__ __forceinline__ u16 f2bf(float f) {
  unsigned int u = __builtin_bit_cast(unsigned int, f);
  u += 0x7fffu + ((u >> 16) & 1u);   // RNE
  return (u16)(u >> 16);
}

__device__ __forceinline__ void gload16(const void* g, void* l) {
  __builtin_amdgcn_global_load_lds((__attribute__((address_space(1))) void*)g,
                                   (__attribute__((address_space(3))) void*)l,
                                   16, 0, 0);
}

__device__ __forceinline__ f32x4 mfma16x32(bf16x8 a, bf16x8 b, f32x4 c) {
  return __builtin_amdgcn_mfma_f32_16x16x32_bf16(a, b, c, 0, 0, 0);
}

template <int N>
__device__ __forceinline__ void waitvm() {
  if constexpr (N == 0) asm volatile("s_waitcnt vmcnt(0)" ::: "memory");
  else if constexpr (N == 3) asm volatile("s_waitcnt vmcnt(3)" ::: "memory");
  else if constexpr (N == 4) asm volatile("s_waitcnt vmcnt(4)" ::: "memory");
  else if constexpr (N == 6) asm volatile("s_waitcnt vmcnt(6)" ::: "memory");
  else if constexpr (N == 8) asm volatile("s_waitcnt vmcnt(8)" ::: "memory");
}

// ---------------------------------------------------------------- prep kernels

__global__ __launch_bounds__(256) void k_embed(const int* __restrict__ x,
                                               const float* __restrict__ emb,
                                               float* __restrict__ h) {
  const int n = blockIdx.x, t = threadIdx.x;
  const int tok = x[n];
  reinterpret_cast<float4*>(h + (size_t)n * DMODEL)[t] =
      reinterpret_cast<const float4*>(emb + (size_t)tok * DMODEL)[t];
}

__global__ void k_rope(float* __restrict__ ct, float* __restrict__ st) {
  const int n = blockIdx.x, p = threadIdx.x;  // 32 freq pairs
  const double inv = exp(-(double)(2 * p) / 64.0 * log(10000.0));
  const double a = (double)n * inv;
  ct[n * 32 + p] = (float)cos(a);
  st[n * 32 + p] = (float)sin(a);
}

// f32 [K][Nc] -> bf16 [Nc][K]; 64x64 tiles, float4 reads, ushort4 writes.
__global__ __launch_bounds__(256) void k_transpose(const float* __restrict__ in0,
                                                   u16* __restrict__ out0,
                                                   int K, int Nc,
                                                   size_t ls_in, size_t ls_out) {
  const float* in = in0 + blockIdx.z * ls_in;
  u16* out = out0 + blockIdx.z * ls_out;
  __shared__ float tile[64][65];
  const int kb = blockIdx.x * 64, nb = blockIdx.y * 64;
  const int tr = threadIdx.x >> 4;       // 0..15
  const int tc = threadIdx.x & 15;       // 0..15
#pragma unroll
  for (int r = 0; r < 64; r += 16) {
    const float4 v = *reinterpret_cast<const float4*>(
        &in[(size_t)(kb + r + tr) * Nc + nb + tc * 4]);
    tile[r + tr][tc * 4 + 0] = v.x;
    tile[r + tr][tc * 4 + 1] = v.y;
    tile[r + tr][tc * 4 + 2] = v.z;
    tile[r + tr][tc * 4 + 3] = v.w;
  }
  __syncthreads();
#pragma unroll
  for (int r = 0; r < 64; r += 16) {
    const int n = r + tr;
    ushort4 o;
    o.x = f2bf(tile[tc * 4 + 0][n]);
    o.y = f2bf(tile[tc * 4 + 1][n]);
    o.z = f2bf(tile[tc * 4 + 2][n]);
    o.w = f2bf(tile[tc * 4 + 3][n]);
    *reinterpret_cast<ushort4*>(&out[(size_t)(nb + n) * K + kb + tc * 4]) = o;
  }
}

// rms_norm(h)*gamma -> bf16 (GEMM A input). One row per block (256 thr, float4).
__global__ __launch_bounds__(256) void k_rmsnorm(const float* __restrict__ h,
                                                 const float* __restrict__ gamma,
                                                 u16* __restrict__ out) {
  __shared__ float red[4];
  const int n = blockIdx.x, t = threadIdx.x;
  const float4 v = reinterpret_cast<const float4*>(h + (size_t)n * DMODEL)[t];
  float ss = v.x * v.x + v.y * v.y + v.z * v.z + v.w * v.w;
#pragma unroll
  for (int off = 32; off; off >>= 1) ss += __shfl_down(ss, off);
  if ((t & 63) == 0) red[t >> 6] = ss;
  __syncthreads();
  const float tot = red[0] + red[1] + red[2] + red[3];
  const float inv = 32.0f / fmaxf(sqrtf(tot), 1e-12f);  // sqrt(1024)=32
  const float4 g = reinterpret_cast<const float4*>(gamma)[t];
  ushort4 o;
  o.x = f2bf(v.x * inv * g.x);
  o.y = f2bf(v.y * inv * g.y);
  o.z = f2bf(v.z * inv * g.z);
  o.w = f2bf(v.w * inv * g.w);
  reinterpret_cast<ushort4*>(out + (size_t)n * DMODEL)[t] = o;
}

// ---------------------------------------------------------------- GEMM epilogues
#define EPI_STORE 0
#define EPI_ADD 1
#define EPI_GELU 2
#define EPI_BIAS_ADD 3
#define EPI_QKV 4

// 64B rows = 4 slots of 16B; 2-level swizzle on SOURCE and READ (both sides).
__device__ __forceinline__ bf16x8 ldsfragT(const char* base, int row, int lg) {
  return *reinterpret_cast<const bf16x8*>(
      base + row * 64 + (((lg ^ (row & 3) ^ ((row >> 2) & 3)) & 3) << 4));
}

// ---------------- k_gemmT: BMx128xBK32, QUAD-buffer, counted vmcnt -----------
// Tile t staged at iteration t-3 (lead 2 iterations ~1200cyc > HBM latency).
// Iteration t: read buf[t%4]; stage tile t+3 into buf[(t+3)%4] (free: its last
// reader was tile t-1, done at the t-1 boundary barrier). Boundary waits:
//   t+3<nt: vmcnt(2*SL)  (3 tiles in flight -> retire t+1)
//   t+2<nt: vmcnt(SL)    (2 in flight -> retire t+1)
//   else:   vmcnt(0)
// SL = loads/stage (BM128: 4, BM64: 3). Staging dest lane-linear tid*16 (m104).
template <int EPI, int BM>
__global__ __launch_bounds__(256) void k_gemmT(
    const u16* __restrict__ A, const u16* __restrict__ BT, int K, int Nc,
    int NMB, const float* __restrict__ bias, const float* __restrict__ add,
    float* __restrict__ outf, u16* __restrict__ outb,
    u16* __restrict__ Qr, u16* __restrict__ Kr, u16* __restrict__ VT,
    const float* __restrict__ ct, const float* __restrict__ st) {
  constexpr int MFR = BM / 32;            // A frags per wave
  constexpr int ABYTES = BM * 64;         // BM rows x 32 k x 2B
  constexpr int BUFB = ABYTES + 8192;
  constexpr int SL = (BM == 128) ? 4 : 3; // loads per stage
  __shared__ alignas(16) char sm[4 * BUFB];
  const int nt = K >> 5;
  const int nwg = gridDim.x;
  int swz = blockIdx.x;
  if ((nwg & 7) == 0) swz = (swz & 7) * (nwg >> 3) + (swz >> 3);
  const int mb = swz % NMB, nb = swz / NMB;  // m-fast: B panel L2-resident
  const int m0 = mb * BM, n0 = nb * 128;

  const int tid = threadIdx.x, w = tid >> 6, lane = tid & 63;
  const int wr = w >> 1, wc = w & 1;
  const int lr = lane & 15, lg = lane >> 4;

  const int srow = tid >> 2;
  const int gslot = (tid & 3) ^ (srow & 3) ^ ((srow >> 2) & 3);
  const u16* ga0 = A + (size_t)(m0 + srow) * K + gslot * 8;
  const u16* ga1 = A + (size_t)(m0 + (BM == 128 ? 64 : 0) + srow) * K + gslot * 8;
  const u16* gb0 = BT + (size_t)(n0 + srow) * K + gslot * 8;
  const u16* gb1 = BT + (size_t)(n0 + 64 + srow) * K + gslot * 8;
  const int ldOff = tid * 16;             // lane-linear dest (m104)

  auto stage = [&](int b) {
    char* base = sm + b * BUFB;
    gload16(ga0, base + ldOff);
    if constexpr (BM == 128) gload16(ga1, base + 4096 + ldOff);
    gload16(gb0, base + ABYTES + ldOff);
    gload16(gb1, base + ABYTES + 4096 + ldOff);
    ga0 += 32; gb0 += 32; gb1 += 32;
    if constexpr (BM == 128) ga1 += 32;
  };

  stage(0);
  stage(1);
  stage(2);
  waitvm<2 * SL>();                        // tile0 landed; 1,2 in flight
  __builtin_amdgcn_s_barrier();

  f32x4 acc[MFR][4] = {};
  int cur = 0;
  for (int t = 0; t < nt; ++t) {
    const char* Ab = sm + cur * BUFB;
    const char* Bb = Ab + ABYTES;
    bf16x8 af[MFR], bf[4];
#pragma unroll
    for (int i = 0; i < MFR; ++i)
      af[i] = ldsfragT(Ab, wr * (BM / 2) + i * 16 + lr, lg);
#pragma unroll
    for (int i = 0; i < 4; ++i)
      bf[i] = ldsfragT(Bb, wc * 64 + i * 16 + lr, lg);
    if (t + 3 < nt) stage((cur + 3) & 3);
    __builtin_amdgcn_s_setprio(1);
#pragma unroll
    for (int mi = 0; mi < MFR; ++mi)
#pragma unroll
      for (int nj = 0; nj < 4; ++nj)
        acc[mi][nj] = mfma16x32(af[mi], bf[nj], acc[mi][nj]);
    __builtin_amdgcn_s_setprio(0);
    if (t + 1 < nt) {
      __builtin_amdgcn_sched_barrier(0);
      if (t + 3 < nt)      waitvm<2 * SL>();
      else if (t + 2 < nt) waitvm<SL>();
      else                 waitvm<0>();
      __builtin_amdgcn_s_barrier();
      __builtin_amdgcn_sched_barrier(0);
    }
    cur = (cur + 1) & 3;
  }

  if constexpr (EPI == EPI_QKV) {
    // qkv: Nc=3072; wave tile = one head (64 cols). which = col block /1024.
    const int which = n0 >> 10;
    const int hh = ((n0 & 1023) >> 6) + wc;
#pragma unroll
    for (int mi = 0; mi < MFR; ++mi) {
#pragma unroll
      for (int nj = 0; nj < 4; ++nj) {
        const int d = nj * 16 + lr;
#pragma unroll
        for (int r = 0; r < 4; ++r) {
          const int row = m0 + wr * (BM / 2) + mi * 16 + lg * 4 + r;
          const float v = acc[mi][nj][r];
          if (which == 2) {
            VT[((size_t)hh * DHEAD + d) * NSEQ + row] = f2bf(v);
          } else {
            const float part = __shfl_xor(v, 1);
            const float sgn = (d & 1) ? 1.0f : -1.0f;
            const float c = ct[row * 32 + (d >> 1)];
            const float s_ = st[row * 32 + (d >> 1)];
            const u16 o = f2bf(v * c + sgn * part * s_);
            u16* dst = (which == 0) ? Qr : Kr;
            dst[((size_t)hh * NSEQ + row) * DHEAD + d] = o;
          }
        }
      }
    }
    return;
  }
#pragma unroll
  for (int mi = 0; mi < MFR; ++mi) {
#pragma unroll
    for (int nj = 0; nj < 4; ++nj) {
      const int col = n0 + wc * 64 + nj * 16 + lr;
#pragma unroll
      for (int r = 0; r < 4; ++r) {
        const int row = m0 + wr * (BM / 2) + mi * 16 + lg * 4 + r;
        const size_t idx = (size_t)row * Nc + col;
        float v = acc[mi][nj][r];
        if (EPI == EPI_GELU) {
          v += bias[col];
          v = 0.5f * v * (1.0f + erff(v * 0.70710678118654752f));
          outb[idx] = f2bf(v);
        } else if (EPI == EPI_ADD) {
          outf[idx] = v + add[idx];
        } else if (EPI == EPI_BIAS_ADD) {
          outf[idx] = v + bias[col] + add[idx];
        } else {
          outf[idx] = v;
        }
      }
    }
  }
}

// ---------------------------------------------------------------- attention
__global__ __launch_bounds__(256) void k_attn(const u16* __restrict__ Qr,
                                              const u16* __restrict__ Kr,
                                              const u16* __restrict__ VT,
                                              u16* __restrict__ O) {
  __shared__ alignas(16) u16 Pl[4][16 * 32];
  const int hh = blockIdx.y;
  const int w = threadIdx.x >> 6, lane = threadIdx.x & 63;
  const int lr = lane & 15, lg = lane >> 4;
  const int q0 = blockIdx.x * 64 + w * 16;
  const u16* Qh = Qr + (size_t)hh * NSEQ * DHEAD;
  const u16* Kh = Kr + (size_t)hh * NSEQ * DHEAD;
  const u16* Vh = VT + (size_t)hh * DHEAD * NSEQ;
  u16* Pw = Pl[w];

  const bf16x8 aq0 = *reinterpret_cast<const bf16x8*>(Qh + (q0 + lr) * DHEAD + lg * 8);
  const bf16x8 aq1 = *reinterpret_cast<const bf16x8*>(Qh + (q0 + lr) * DHEAD + 32 + lg * 8);

  f32x4 o0 = {}, o1 = {}, o2 = {}, o3 = {};
  float m[4], l[4];
#pragma unroll
  for (int r = 0; r < 4; ++r) { m[r] = -1e30f; l[r] = 0.0f; }

  const int jend = q0 + 15;
  for (int j0 = 0; j0 <= jend; j0 += 32) {
    f32x4 s0 = {}, s1 = {};
    {
      bf16x8 bk;
      bk = *reinterpret_cast<const bf16x8*>(Kh + (j0 + lr) * DHEAD + lg * 8);
      s0 = mfma16x32(aq0, bk, s0);
      bk = *reinterpret_cast<const bf16x8*>(Kh + (j0 + lr) * DHEAD + 32 + lg * 8);
      s0 = mfma16x32(aq1, bk, s0);
      bk = *reinterpret_cast<const bf16x8*>(Kh + (j0 + 16 + lr) * DHEAD + lg * 8);
      s1 = mfma16x32(aq0, bk, s1);
      bk = *reinterpret_cast<const bf16x8*>(Kh + (j0 + 16 + lr) * DHEAD + 32 + lg * 8);
      s1 = mfma16x32(aq1, bk, s1);
    }
    float sv0[4], sv1[4], pm[4];
#pragma unroll
    for (int r = 0; r < 4; ++r) {
      const int irow = q0 + lg * 4 + r;
      sv0[r] = (j0 + lr > irow) ? -1e30f : s0[r] * 0.125f;
      sv1[r] = (j0 + 16 + lr > irow) ? -1e30f : s1[r] * 0.125f;
      pm[r] = fmaxf(sv0[r], sv1[r]);
    }
#pragma unroll
    for (int off = 1; off < 16; off <<= 1)
#pragma unroll
      for (int r = 0; r < 4; ++r) pm[r] = fmaxf(pm[r], __shfl_xor(pm[r], off));
    float p0[4], p1[4], rs[4];
    f32x4 fv;
#pragma unroll
    for (int r = 0; r < 4; ++r) {
      const float mn = fmaxf(m[r], pm[r]);
      fv[r] = __expf(m[r] - mn);
      m[r] = mn;
      p0[r] = __expf(sv0[r] - mn);
      p1[r] = __expf(sv1[r] - mn);
      rs[r] = p0[r] + p1[r];
    }
#pragma unroll
    for (int off = 1; off < 16; off <<= 1)
#pragma unroll
      for (int r = 0; r < 4; ++r) rs[r] += __shfl_xor(rs[r], off);
#pragma unroll
    for (int r = 0; r < 4; ++r) l[r] = l[r] * fv[r] + rs[r];
    o0 *= fv; o1 *= fv; o2 *= fv; o3 *= fv;

#pragma unroll
    for (int r = 0; r < 4; ++r) {
      Pw[(lg * 4 + r) * 32 + lr] = f2bf(p0[r]);
      Pw[(lg * 4 + r) * 32 + 16 + lr] = f2bf(p1[r]);
    }
    const bf16x8 pa = *reinterpret_cast<const bf16x8*>(Pw + lr * 32 + lg * 8);
    const u16* vb = Vh + j0 + lg * 8;
    o0 = mfma16x32(pa, *reinterpret_cast<const bf16x8*>(vb + (0 + lr) * NSEQ), o0);
    o1 = mfma16x32(pa, *reinterpret_cast<const bf16x8*>(vb + (16 + lr) * NSEQ), o1);
    o2 = mfma16x32(pa, *reinterpret_cast<const bf16x8*>(vb + (32 + lr) * NSEQ), o2);
    o3 = mfma16x32(pa, *reinterpret_cast<const bf16x8*>(vb + (48 + lr) * NSEQ), o3);
  }

#pragma unroll
  for (int r = 0; r < 4; ++r) {
    const int row = q0 + lg * 4 + r;
    const float invl = 1.0f / l[r];
    u16* orow = O + (size_t)row * DMODEL + hh * DHEAD;
    orow[0 * 16 + lr] = f2bf(o0[r] * invl);
    orow[1 * 16 + lr] = f2bf(o1[r] * invl);
    orow[2 * 16 + lr] = f2bf(o2[r] * invl);
    orow[3 * 16 + lr] = f2bf(o3[r] * invl);
  }
}

// ---------------------------------------------------------------- launch

extern "C" void kernel_launch(void* const* d_in, const int* in_sizes, int n_in,
                              void* d_out, int out_size, void* d_ws, size_t ws_size,
                              hipStream_t stream) {
  (void)in_sizes; (void)n_in;
  const int* x = (const int*)d_in[0];
  const float* emb = (const float*)d_in[1];
  const float* attn_gamma = (const float*)d_in[2];
  const float* w_qkv = (const float*)d_in[3];
  const float* w_attn_out = (const float*)d_in[4];
  const float* ff_gamma = (const float*)d_in[5];
  const float* w_ff1 = (const float*)d_in[6];
  const float* b_ff1 = (const float*)d_in[7];
  const float* w_ff2 = (const float*)d_in[8];
  const float* b_ff2 = (const float*)d_in[9];
  const float* final_gamma = (const float*)d_in[10];
  const float* w_logits = (const float*)d_in[11];
  float* out = (float*)d_out;

  const size_t EARLY_NEED = 176ull << 20;
  const size_t FINAL_NEED = 72ull << 20;
  char* earlyBase;
  char* finalBase;
  if (ws_size >= EARLY_NEED + FINAL_NEED) {
    earlyBase = (char*)d_ws;
    finalBase = (char*)d_ws + EARLY_NEED;
  } else if (ws_size >= FINAL_NEED && (size_t)out_size * 4 >= EARLY_NEED) {
    earlyBase = (char*)d_out;
    finalBase = (char*)d_ws;
  } else {
    return;
  }
  size_t eoff = 0, foff = 0;
  auto ealloc = [&](size_t b) { void* p = earlyBase + eoff; eoff += (b + 255) & ~(size_t)255; return p; };
  auto falloc = [&](size_t b) { void* p = finalBase + foff; foff += (b + 255) & ~(size_t)255; return p; };

  u16* wqkvT = (u16*)ealloc((size_t)NLAYER * 3072 * DMODEL * 2);
  u16* wattnT = (u16*)ealloc((size_t)NLAYER * DMODEL * DMODEL * 2);
  u16* wff1T = (u16*)ealloc((size_t)NLAYER * FFD * DMODEL * 2);
  u16* wff2T = (u16*)ealloc((size_t)NLAYER * DMODEL * FFD * 2);
  float* h = (float*)ealloc((size_t)NSEQ * DMODEL * 4);
  u16* Qr = (u16*)ealloc((size_t)NH * NSEQ * DHEAD * 2);
  u16* Kr = (u16*)ealloc((size_t)NH * NSEQ * DHEAD * 2);
  u16* VTb = (u16*)ealloc((size_t)NH * NSEQ * DHEAD * 2);
  u16* Ob = (u16*)ealloc((size_t)NSEQ * DMODEL * 2);
  u16* ff1b = (u16*)ealloc((size_t)NSEQ * FFD * 2);
  float* ct = (float*)ealloc((size_t)NSEQ * 32 * 4);
  float* st = (float*)ealloc((size_t)NSEQ * 32 * 4);
  u16* wlogT = (u16*)falloc((size_t)VOC * DMODEL * 2);
  u16* xn = (u16*)falloc((size_t)NSEQ * DMODEL * 2);

  k_rope<<<dim3(NSEQ), dim3(32), 0, stream>>>(ct, st);
  k_transpose<<<dim3(16, 48, NLAYER), 256, 0, stream>>>(
      w_qkv, wqkvT, DMODEL, 3072, (size_t)DMODEL * 3072, (size_t)3072 * DMODEL);
  k_transpose<<<dim3(16, 16, NLAYER), 256, 0, stream>>>(
      w_attn_out, wattnT, DMODEL, DMODEL, (size_t)DMODEL * DMODEL, (size_t)DMODEL * DMODEL);
  k_transpose<<<dim3(16, 64, NLAYER), 256, 0, stream>>>(
      w_ff1, wff1T, DMODEL, FFD, (size_t)DMODEL * FFD, (size_t)FFD * DMODEL);
  k_transpose<<<dim3(64, 16, NLAYER), 256, 0, stream>>>(
      w_ff2, wff2T, FFD, DMODEL, (size_t)FFD * DMODEL, (size_t)DMODEL * FFD);
  k_transpose<<<dim3(16, 500, 1), 256, 0, stream>>>(
      w_logits, wlogT, DMODEL, VOC, 0, 0);

  k_embed<<<dim3(NSEQ), 256, 0, stream>>>(x, emb, h);

  for (int lyr = 0; lyr < NLAYER; ++lyr) {
    k_rmsnorm<<<dim3(NSEQ), 256, 0, stream>>>(h, attn_gamma + (size_t)lyr * DMODEL, xn);
    k_gemmT<EPI_QKV, 128><<<dim3(16 * 24), 256, 0, stream>>>(
        xn, wqkvT + (size_t)lyr * 3072 * DMODEL, DMODEL, 3072, 16,
        nullptr, nullptr, nullptr, nullptr, Qr, Kr, VTb, ct, st);
    k_attn<<<dim3(NSEQ / 64, NH), 256, 0, stream>>>(Qr, Kr, VTb, Ob);
    k_gemmT<EPI_ADD, 64><<<dim3(32 * 8), 256, 0, stream>>>(
        Ob, wattnT + (size_t)lyr * DMODEL * DMODEL, DMODEL, DMODEL, 32,
        nullptr, h, h, nullptr, nullptr, nullptr, nullptr, nullptr, nullptr);
    k_rmsnorm<<<dim3(NSEQ), 256, 0, stream>>>(h, ff_gamma + (size_t)lyr * DMODEL, xn);
    k_gemmT<EPI_GELU, 128><<<dim3(16 * 32), 256, 0, stream>>>(
        xn, wff1T + (size_t)lyr * FFD * DMODEL, DMODEL, FFD, 16,
        b_ff1 + (size_t)lyr * FFD, nullptr, nullptr, ff1b,
        nullptr, nullptr, nullptr, nullptr, nullptr);
    k_gemmT<EPI_BIAS_ADD, 64><<<dim3(32 * 8), 256, 0, stream>>>(
        ff1b, wff2T + (size_t)lyr * DMODEL * FFD, FFD, DMODEL, 32,
        b_ff2 + (size_t)lyr * DMODEL, h, h, nullptr,
        nullptr, nullptr, nullptr, nullptr, nullptr);
  }

  k_rmsnorm<<<dim3(NSEQ), 256, 0, stream>>>(h, final_gamma, xn);
  k_gemmT<EPI_STORE, 128><<<dim3(16 * 250), 256, 0, stream>>>(
      xn, wlogT, DMODEL, VOC, 16,
      nullptr, nullptr, out, nullptr, nullptr, nullptr, nullptr, nullptr, nullptr);
}

// Round 11
// 1277.723 us; speedup vs baseline: 1.2925x; 1.0274x over previous
//
#include <hip/hip_runtime.h>
#include <math.h>

// Decoder forward, MI355X gfx950. Round 11: logits back to k_gemmW (R9 exact,
// cache-friendly 2000-block grid); qkv to BM=64 quad (768 blocks = 3/CU
// exact); k_attn gets next-iteration K/V register prefetch.
//
// Dims (fixed): V=32000 D=1024 DEPTH=4 H=16 DH=64 FF=4096 B=1 N=2048

#define NSEQ 2048
#define DMODEL 1024
#define NH 16
#define DHEAD 64
#define FFD 4096
#define VOC 32000
#define NLAYER 4

typedef unsigned short u16;
typedef short bf16x8 __attribute__((ext_vector_type(8)));   // 8 bf16 in 4 VGPRs
typedef float f32x4 __attribute__((ext_vector_type(4)));

__device__ __forceinline__ u16 f2bf(float f) {
  unsigned int u = __builtin_bit_cast(unsigned int, f);
  u += 0x7fffu + ((u >> 16) & 1u);   // RNE
  return (u16)(u >> 16);
}

__device__ __forceinline__ void gload16(const void* g, void* l) {
  __builtin_amdgcn_global_load_lds((__attribute__((address_space(1))) void*)g,
                                   (__attribute__((address_space(3))) void*)l,
                                   16, 0, 0);
}

__device__ __forceinline__ f32x4 mfma16x32(bf16x8 a, bf16x8 b, f32x4 c) {
  return __builtin_amdgcn_mfma_f32_16x16x32_bf16(a, b, c, 0, 0, 0);
}

template <int N>
__device__ __forceinline__ void waitvm() {
  if constexpr (N == 0) asm volatile("s_waitcnt vmcnt(0)" ::: "memory");
  else if constexpr (N == 3) asm volatile("s_waitcnt vmcnt(3)" ::: "memory");
  else if constexpr (N == 4) asm volatile("s_waitcnt vmcnt(4)" ::: "memory");
  else if constexpr (N == 6) asm volatile("s_waitcnt vmcnt(6)" ::: "memory");
  else if constexpr (N == 8) asm volatile("s_waitcnt vmcnt(8)" ::: "memory");
}

// ---------------------------------------------------------------- prep kernels

__global__ __launch_bounds__(256) void k_embed(const int* __restrict__ x,
                                               const float* __restrict__ emb,
                                               float* __restrict__ h) {
  const int n = blockIdx.x, t = threadIdx.x;
  const int tok = x[n];
  reinterpret_cast<float4*>(h + (size_t)n * DMODEL)[t] =
      reinterpret_cast<const float4*>(emb + (size_t)tok * DMODEL)[t];
}

__global__ void k_rope(float* __restrict__ ct, float* __restrict__ st) {
  const int n = blockIdx.x, p = threadIdx.x;  // 32 freq pairs
  const double inv = exp(-(double)(2 * p) / 64.0 * log(10000.0));
  const double a = (double)n * inv;
  ct[n * 32 + p] = (float)cos(a);
  st[n * 32 + p] = (float)sin(a);
}

// f32 [K][Nc] -> bf16 [Nc][K]; 64x64 tiles, float4 reads, ushort4 writes.
__global__ __launch_bounds__(256) void k_transpose(const float* __restrict__ in0,
                                                   u16* __restrict__ out0,
                                                   int K, int Nc,
                                                   size_t ls_in, size_t ls_out) {
  const float* in = in0 + blockIdx.z * ls_in;
  u16* out = out0 + blockIdx.z * ls_out;
  __shared__ float tile[64][65];
  const int kb = blockIdx.x * 64, nb = blockIdx.y * 64;
  const int tr = threadIdx.x >> 4;       // 0..15
  const int tc = threadIdx.x & 15;       // 0..15
#pragma unroll
  for (int r = 0; r < 64; r += 16) {
    const float4 v = *reinterpret_cast<const float4*>(
        &in[(size_t)(kb + r + tr) * Nc + nb + tc * 4]);
    tile[r + tr][tc * 4 + 0] = v.x;
    tile[r + tr][tc * 4 + 1] = v.y;
    tile[r + tr][tc * 4 + 2] = v.z;
    tile[r + tr][tc * 4 + 3] = v.w;
  }
  __syncthreads();
#pragma unroll
  for (int r = 0; r < 64; r += 16) {
    const int n = r + tr;
    ushort4 o;
    o.x = f2bf(tile[tc * 4 + 0][n]);
    o.y = f2bf(tile[tc * 4 + 1][n]);
    o.z = f2bf(tile[tc * 4 + 2][n]);
    o.w = f2bf(tile[tc * 4 + 3][n]);
    *reinterpret_cast<ushort4*>(&out[(size_t)(nb + n) * K + kb + tc * 4]) = o;
  }
}

// rms_norm(h)*gamma -> bf16 (GEMM A input). One row per block (256 thr, float4).
__global__ __launch_bounds__(256) void k_rmsnorm(const float* __restrict__ h,
                                                 const float* __restrict__ gamma,
                                                 u16* __restrict__ out) {
  __shared__ float red[4];
  const int n = blockIdx.x, t = threadIdx.x;
  const float4 v = reinterpret_cast<const float4*>(h + (size_t)n * DMODEL)[t];
  float ss = v.x * v.x + v.y * v.y + v.z * v.z + v.w * v.w;
#pragma unroll
  for (int off = 32; off; off >>= 1) ss += __shfl_down(ss, off);
  if ((t & 63) == 0) red[t >> 6] = ss;
  __syncthreads();
  const float tot = red[0] + red[1] + red[2] + red[3];
  const float inv = 32.0f / fmaxf(sqrtf(tot), 1e-12f);  // sqrt(1024)=32
  const float4 g = reinterpret_cast<const float4*>(gamma)[t];
  ushort4 o;
  o.x = f2bf(v.x * inv * g.x);
  o.y = f2bf(v.y * inv * g.y);
  o.z = f2bf(v.z * inv * g.z);
  o.w = f2bf(v.w * inv * g.w);
  reinterpret_cast<ushort4*>(out + (size_t)n * DMODEL)[t] = o;
}

// ---------------------------------------------------------------- GEMM epilogues
#define EPI_STORE 0
#define EPI_ADD 1
#define EPI_GELU 2
#define EPI_BIAS_ADD 3
#define EPI_QKV 4

// 64B rows = 4 slots of 16B; 2-level swizzle on SOURCE and READ (both sides).
__device__ __forceinline__ bf16x8 ldsfragT(const char* base, int row, int lg) {
  return *reinterpret_cast<const bf16x8*>(
      base + row * 64 + (((lg ^ (row & 3) ^ ((row >> 2) & 3)) & 3) << 4));
}

// ---------------- k_gemmT: BMx128xBK32, QUAD-buffer, counted vmcnt -----------
// Tile t staged at iteration t-3 (lead 2 iterations ~1200cyc > HBM latency).
// Boundary waits: t+3<nt: vmcnt(2*SL); t+2<nt: vmcnt(SL); else vmcnt(0).
// SL = loads/stage (BM128: 4, BM64: 3). Staging dest lane-linear tid*16 (m104).
template <int EPI, int BM>
__global__ __launch_bounds__(256) void k_gemmT(
    const u16* __restrict__ A, const u16* __restrict__ BT, int K, int Nc,
    int NMB, const float* __restrict__ bias, const float* __restrict__ add,
    float* __restrict__ outf, u16* __restrict__ outb,
    u16* __restrict__ Qr, u16* __restrict__ Kr, u16* __restrict__ VT,
    const float* __restrict__ ct, const float* __restrict__ st) {
  constexpr int MFR = BM / 32;            // A frags per wave
  constexpr int ABYTES = BM * 64;         // BM rows x 32 k x 2B
  constexpr int BUFB = ABYTES + 8192;
  constexpr int SL = (BM == 128) ? 4 : 3; // loads per stage
  __shared__ alignas(16) char sm[4 * BUFB];
  const int nt = K >> 5;
  const int nwg = gridDim.x;
  int swz = blockIdx.x;
  if ((nwg & 7) == 0) swz = (swz & 7) * (nwg >> 3) + (swz >> 3);
  const int mb = swz % NMB, nb = swz / NMB;  // m-fast: B panel L2-resident
  const int m0 = mb * BM, n0 = nb * 128;

  const int tid = threadIdx.x, w = tid >> 6, lane = tid & 63;
  const int wr = w >> 1, wc = w & 1;
  const int lr = lane & 15, lg = lane >> 4;

  const int srow = tid >> 2;
  const int gslot = (tid & 3) ^ (srow & 3) ^ ((srow >> 2) & 3);
  const u16* ga0 = A + (size_t)(m0 + srow) * K + gslot * 8;
  const u16* ga1 = A + (size_t)(m0 + (BM == 128 ? 64 : 0) + srow) * K + gslot * 8;
  const u16* gb0 = BT + (size_t)(n0 + srow) * K + gslot * 8;
  const u16* gb1 = BT + (size_t)(n0 + 64 + srow) * K + gslot * 8;
  const int ldOff = tid * 16;             // lane-linear dest (m104)

  auto stage = [&](int b) {
    char* base = sm + b * BUFB;
    gload16(ga0, base + ldOff);
    if constexpr (BM == 128) gload16(ga1, base + 4096 + ldOff);
    gload16(gb0, base + ABYTES + ldOff);
    gload16(gb1, base + ABYTES + 4096 + ldOff);
    ga0 += 32; gb0 += 32; gb1 += 32;
    if constexpr (BM == 128) ga1 += 32;
  };

  stage(0);
  stage(1);
  stage(2);
  waitvm<2 * SL>();                        // tile0 landed; 1,2 in flight
  __builtin_amdgcn_s_barrier();

  f32x4 acc[MFR][4] = {};
  int cur = 0;
  for (int t = 0; t < nt; ++t) {
    const char* Ab = sm + cur * BUFB;
    const char* Bb = Ab + ABYTES;
    bf16x8 af[MFR], bf[4];
#pragma unroll
    for (int i = 0; i < MFR; ++i)
      af[i] = ldsfragT(Ab, wr * (BM / 2) + i * 16 + lr, lg);
#pragma unroll
    for (int i = 0; i < 4; ++i)
      bf[i] = ldsfragT(Bb, wc * 64 + i * 16 + lr, lg);
    if (t + 3 < nt) stage((cur + 3) & 3);
    __builtin_amdgcn_s_setprio(1);
#pragma unroll
    for (int mi = 0; mi < MFR; ++mi)
#pragma unroll
      for (int nj = 0; nj < 4; ++nj)
        acc[mi][nj] = mfma16x32(af[mi], bf[nj], acc[mi][nj]);
    __builtin_amdgcn_s_setprio(0);
    if (t + 1 < nt) {
      __builtin_amdgcn_sched_barrier(0);
      if (t + 3 < nt)      waitvm<2 * SL>();
      else if (t + 2 < nt) waitvm<SL>();
      else                 waitvm<0>();
      __builtin_amdgcn_s_barrier();
      __builtin_amdgcn_sched_barrier(0);
    }
    cur = (cur + 1) & 3;
  }

  if constexpr (EPI == EPI_QKV) {
    // qkv: Nc=3072; wave tile = one head (64 cols). which = col block /1024.
    const int which = n0 >> 10;
    const int hh = ((n0 & 1023) >> 6) + wc;
#pragma unroll
    for (int mi = 0; mi < MFR; ++mi) {
#pragma unroll
      for (int nj = 0; nj < 4; ++nj) {
        const int d = nj * 16 + lr;
#pragma unroll
        for (int r = 0; r < 4; ++r) {
          const int row = m0 + wr * (BM / 2) + mi * 16 + lg * 4 + r;
          const float v = acc[mi][nj][r];
          if (which == 2) {
            VT[((size_t)hh * DHEAD + d) * NSEQ + row] = f2bf(v);
          } else {
            const float part = __shfl_xor(v, 1);
            const float sgn = (d & 1) ? 1.0f : -1.0f;
            const float c = ct[row * 32 + (d >> 1)];
            const float s_ = st[row * 32 + (d >> 1)];
            const u16 o = f2bf(v * c + sgn * part * s_);
            u16* dst = (which == 0) ? Qr : Kr;
            dst[((size_t)hh * NSEQ + row) * DHEAD + d] = o;
          }
        }
      }
    }
    return;
  }
#pragma unroll
  for (int mi = 0; mi < MFR; ++mi) {
#pragma unroll
    for (int nj = 0; nj < 4; ++nj) {
      const int col = n0 + wc * 64 + nj * 16 + lr;
#pragma unroll
      for (int r = 0; r < 4; ++r) {
        const int row = m0 + wr * (BM / 2) + mi * 16 + lg * 4 + r;
        const size_t idx = (size_t)row * Nc + col;
        float v = acc[mi][nj][r];
        if (EPI == EPI_GELU) {
          v += bias[col];
          v = 0.5f * v * (1.0f + erff(v * 0.70710678118654752f));
          outb[idx] = f2bf(v);
        } else if (EPI == EPI_ADD) {
          outf[idx] = v + add[idx];
        } else if (EPI == EPI_BIAS_ADD) {
          outf[idx] = v + bias[col] + add[idx];
        } else {
          outf[idx] = v;
        }
      }
    }
  }
}

// ---------------- k_gemmW: 128x256xBK32, wave tile 64x128 (R9 exact) ---------
// Tri-buffer 72KB (2 blk/CU); fewer blocks -> less A re-fetch under the 256MB
// logits write stream. Best measured logits kernel (176us, R9).
template <int EPI>
__global__ __launch_bounds__(256, 2) void k_gemmW(
    const u16* __restrict__ A, const u16* __restrict__ BT, int K, int Nc,
    const float* __restrict__ bias, float* __restrict__ outf,
    u16* __restrict__ outb) {
  constexpr int ABYTES = 8192;            // 128 rows x 32 k x 2B
  constexpr int BUFB = ABYTES + 16384;    // + 256 rows B
  __shared__ alignas(16) char sm[3 * BUFB];
  const int nt = K >> 5;
  const int NMB = 16;
  const int nwg = gridDim.x;
  int swz = blockIdx.x;
  if ((nwg & 7) == 0) swz = (swz & 7) * (nwg >> 3) + (swz >> 3);
  const int mb = swz % NMB, nb = swz / NMB;
  const int m0 = mb * 128, n0 = nb * 256;

  const int tid = threadIdx.x, w = tid >> 6, lane = tid & 63;
  const int wr = w >> 1, wc = w & 1;      // wave tile 64 x 128
  const int lr = lane & 15, lg = lane >> 4;

  const int srow = tid >> 2;
  const int gslot = (tid & 3) ^ (srow & 3) ^ ((srow >> 2) & 3);
  const u16* ga0 = A + (size_t)(m0 + srow) * K + gslot * 8;
  const u16* ga1 = A + (size_t)(m0 + 64 + srow) * K + gslot * 8;
  const u16* gb0 = BT + (size_t)(n0 + srow) * K + gslot * 8;
  const u16* gb1 = BT + (size_t)(n0 + 64 + srow) * K + gslot * 8;
  const u16* gb2 = BT + (size_t)(n0 + 128 + srow) * K + gslot * 8;
  const u16* gb3 = BT + (size_t)(n0 + 192 + srow) * K + gslot * 8;
  const int ldOff = tid * 16;

  auto stage = [&](int b) {
    char* base = sm + b * BUFB;
    gload16(ga0, base + ldOff);
    gload16(ga1, base + 4096 + ldOff);
    gload16(gb0, base + ABYTES + ldOff);
    gload16(gb1, base + ABYTES + 4096 + ldOff);
    gload16(gb2, base + ABYTES + 8192 + ldOff);
    gload16(gb3, base + ABYTES + 12288 + ldOff);
    ga0 += 32; ga1 += 32; gb0 += 32; gb1 += 32; gb2 += 32; gb3 += 32;
  };

  stage(0);
  stage(1);
  waitvm<6>();
  __builtin_amdgcn_s_barrier();

  f32x4 acc[4][8] = {};
  int cur = 0, nx2 = 2;
  for (int t = 0; t < nt; ++t) {
    const char* Ab = sm + cur * BUFB;
    const char* Bb = Ab + ABYTES;
    const bool pf = (t + 2 < nt);
    bf16x8 af[4], bf[8];
#pragma unroll
    for (int i = 0; i < 4; ++i)
      af[i] = ldsfragT(Ab, wr * 64 + i * 16 + lr, lg);
#pragma unroll
    for (int i = 0; i < 8; ++i)
      bf[i] = ldsfragT(Bb, wc * 128 + i * 16 + lr, lg);
    if (pf) stage(nx2);
    __builtin_amdgcn_s_setprio(1);
#pragma unroll
    for (int mi = 0; mi < 4; ++mi)
#pragma unroll
      for (int nj = 0; nj < 8; ++nj)
        acc[mi][nj] = mfma16x32(af[mi], bf[nj], acc[mi][nj]);
    __builtin_amdgcn_s_setprio(0);
    if (t + 1 < nt) {
      __builtin_amdgcn_sched_barrier(0);
      if (pf) waitvm<6>();
      else    waitvm<0>();
      __builtin_amdgcn_s_barrier();
      __builtin_amdgcn_sched_barrier(0);
    }
    cur = (cur == 2) ? 0 : cur + 1;
    nx2 = (nx2 == 2) ? 0 : nx2 + 1;
  }

#pragma unroll
  for (int mi = 0; mi < 4; ++mi) {
#pragma unroll
    for (int nj = 0; nj < 8; ++nj) {
      const int col = n0 + wc * 128 + nj * 16 + lr;
#pragma unroll
      for (int r = 0; r < 4; ++r) {
        const int row = m0 + wr * 64 + mi * 16 + lg * 4 + r;
        const size_t idx = (size_t)row * Nc + col;
        float v = acc[mi][nj][r];
        if (EPI == EPI_GELU) {
          v += bias[col];
          v = 0.5f * v * (1.0f + erff(v * 0.70710678118654752f));
          outb[idx] = f2bf(v);
        } else {
          outf[idx] = v;
        }
      }
    }
  }
}

// ---------------------------------------------------------------- attention
// Per (head, 64 q-rows) block; wave w owns 16 rows. NEW: next iteration's
// K and V fragments are loaded into registers BEFORE the current softmax/PV,
// hiding L2 latency under ~300cyc of dependent work.
__global__ __launch_bounds__(256) void k_attn(const u16* __restrict__ Qr,
                                              const u16* __restrict__ Kr,
                                              const u16* __restrict__ VT,
                                              u16* __restrict__ O) {
  __shared__ alignas(16) u16 Pl[4][16 * 32];
  const int hh = blockIdx.y;
  const int w = threadIdx.x >> 6, lane = threadIdx.x & 63;
  const int lr = lane & 15, lg = lane >> 4;
  const int q0 = blockIdx.x * 64 + w * 16;
  const u16* Qh = Qr + (size_t)hh * NSEQ * DHEAD;
  const u16* Kh = Kr + (size_t)hh * NSEQ * DHEAD;
  const u16* Vh = VT + (size_t)hh * DHEAD * NSEQ;
  u16* Pw = Pl[w];

  const bf16x8 aq0 = *reinterpret_cast<const bf16x8*>(Qh + (q0 + lr) * DHEAD + lg * 8);
  const bf16x8 aq1 = *reinterpret_cast<const bf16x8*>(Qh + (q0 + lr) * DHEAD + 32 + lg * 8);

  f32x4 o0 = {}, o1 = {}, o2 = {}, o3 = {};
  float m[4], l[4];
#pragma unroll
  for (int r = 0; r < 4; ++r) { m[r] = -1e30f; l[r] = 0.0f; }

  const int jend = q0 + 15;

  auto loadK = [&](int j0, bf16x8* bk) {
    bk[0] = *reinterpret_cast<const bf16x8*>(Kh + (j0 + lr) * DHEAD + lg * 8);
    bk[1] = *reinterpret_cast<const bf16x8*>(Kh + (j0 + lr) * DHEAD + 32 + lg * 8);
    bk[2] = *reinterpret_cast<const bf16x8*>(Kh + (j0 + 16 + lr) * DHEAD + lg * 8);
    bk[3] = *reinterpret_cast<const bf16x8*>(Kh + (j0 + 16 + lr) * DHEAD + 32 + lg * 8);
  };
  auto loadV = [&](int j0, bf16x8* vv) {
    const u16* vb = Vh + j0 + lg * 8;
    vv[0] = *reinterpret_cast<const bf16x8*>(vb + (0 + lr) * NSEQ);
    vv[1] = *reinterpret_cast<const bf16x8*>(vb + (16 + lr) * NSEQ);
    vv[2] = *reinterpret_cast<const bf16x8*>(vb + (32 + lr) * NSEQ);
    vv[3] = *reinterpret_cast<const bf16x8*>(vb + (48 + lr) * NSEQ);
  };

  bf16x8 bk[4], vv[4], bkN[4], vvN[4];
  loadK(0, bk);
  loadV(0, vv);

  for (int j0 = 0; j0 <= jend; j0 += 32) {
    // prefetch next tile's K/V while this tile computes
    if (j0 + 32 <= jend) { loadK(j0 + 32, bkN); loadV(j0 + 32, vvN); }

    f32x4 s0 = {}, s1 = {};
    s0 = mfma16x32(aq0, bk[0], s0);
    s0 = mfma16x32(aq1, bk[1], s0);
    s1 = mfma16x32(aq0, bk[2], s1);
    s1 = mfma16x32(aq1, bk[3], s1);

    float sv0[4], sv1[4], pm[4];
#pragma unroll
    for (int r = 0; r < 4; ++r) {
      const int irow = q0 + lg * 4 + r;
      sv0[r] = (j0 + lr > irow) ? -1e30f : s0[r] * 0.125f;
      sv1[r] = (j0 + 16 + lr > irow) ? -1e30f : s1[r] * 0.125f;
      pm[r] = fmaxf(sv0[r], sv1[r]);
    }
#pragma unroll
    for (int off = 1; off < 16; off <<= 1)
#pragma unroll
      for (int r = 0; r < 4; ++r) pm[r] = fmaxf(pm[r], __shfl_xor(pm[r], off));
    float p0[4], p1[4], rs[4];
    f32x4 fv;
#pragma unroll
    for (int r = 0; r < 4; ++r) {
      const float mn = fmaxf(m[r], pm[r]);
      fv[r] = __expf(m[r] - mn);
      m[r] = mn;
      p0[r] = __expf(sv0[r] - mn);
      p1[r] = __expf(sv1[r] - mn);
      rs[r] = p0[r] + p1[r];
    }
#pragma unroll
    for (int off = 1; off < 16; off <<= 1)
#pragma unroll
      for (int r = 0; r < 4; ++r) rs[r] += __shfl_xor(rs[r], off);
#pragma unroll
    for (int r = 0; r < 4; ++r) l[r] = l[r] * fv[r] + rs[r];
    o0 *= fv; o1 *= fv; o2 *= fv; o3 *= fv;

#pragma unroll
    for (int r = 0; r < 4; ++r) {
      Pw[(lg * 4 + r) * 32 + lr] = f2bf(p0[r]);
      Pw[(lg * 4 + r) * 32 + 16 + lr] = f2bf(p1[r]);
    }
    const bf16x8 pa = *reinterpret_cast<const bf16x8*>(Pw + lr * 32 + lg * 8);
    o0 = mfma16x32(pa, vv[0], o0);
    o1 = mfma16x32(pa, vv[1], o1);
    o2 = mfma16x32(pa, vv[2], o2);
    o3 = mfma16x32(pa, vv[3], o3);

#pragma unroll
    for (int i = 0; i < 4; ++i) { bk[i] = bkN[i]; vv[i] = vvN[i]; }
  }

#pragma unroll
  for (int r = 0; r < 4; ++r) {
    const int row = q0 + lg * 4 + r;
    const float invl = 1.0f / l[r];
    u16* orow = O + (size_t)row * DMODEL + hh * DHEAD;
    orow[0 * 16 + lr] = f2bf(o0[r] * invl);
    orow[1 * 16 + lr] = f2bf(o1[r] * invl);
    orow[2 * 16 + lr] = f2bf(o2[r] * invl);
    orow[3 * 16 + lr] = f2bf(o3[r] * invl);
  }
}

// ---------------------------------------------------------------- launch

extern "C" void kernel_launch(void* const* d_in, const int* in_sizes, int n_in,
                              void* d_out, int out_size, void* d_ws, size_t ws_size,
                              hipStream_t stream) {
  (void)in_sizes; (void)n_in;
  const int* x = (const int*)d_in[0];
  const float* emb = (const float*)d_in[1];
  const float* attn_gamma = (const float*)d_in[2];
  const float* w_qkv = (const float*)d_in[3];
  const float* w_attn_out = (const float*)d_in[4];
  const float* ff_gamma = (const float*)d_in[5];
  const float* w_ff1 = (const float*)d_in[6];
  const float* b_ff1 = (const float*)d_in[7];
  const float* w_ff2 = (const float*)d_in[8];
  const float* b_ff2 = (const float*)d_in[9];
  const float* final_gamma = (const float*)d_in[10];
  const float* w_logits = (const float*)d_in[11];
  float* out = (float*)d_out;

  const size_t EARLY_NEED = 176ull << 20;
  const size_t FINAL_NEED = 72ull << 20;
  char* earlyBase;
  char* finalBase;
  if (ws_size >= EARLY_NEED + FINAL_NEED) {
    earlyBase = (char*)d_ws;
    finalBase = (char*)d_ws + EARLY_NEED;
  } else if (ws_size >= FINAL_NEED && (size_t)out_size * 4 >= EARLY_NEED) {
    earlyBase = (char*)d_out;
    finalBase = (char*)d_ws;
  } else {
    return;
  }
  size_t eoff = 0, foff = 0;
  auto ealloc = [&](size_t b) { void* p = earlyBase + eoff; eoff += (b + 255) & ~(size_t)255; return p; };
  auto falloc = [&](size_t b) { void* p = finalBase + foff; foff += (b + 255) & ~(size_t)255; return p; };

  u16* wqkvT = (u16*)ealloc((size_t)NLAYER * 3072 * DMODEL * 2);
  u16* wattnT = (u16*)ealloc((size_t)NLAYER * DMODEL * DMODEL * 2);
  u16* wff1T = (u16*)ealloc((size_t)NLAYER * FFD * DMODEL * 2);
  u16* wff2T = (u16*)ealloc((size_t)NLAYER * DMODEL * FFD * 2);
  float* h = (float*)ealloc((size_t)NSEQ * DMODEL * 4);
  u16* Qr = (u16*)ealloc((size_t)NH * NSEQ * DHEAD * 2);
  u16* Kr = (u16*)ealloc((size_t)NH * NSEQ * DHEAD * 2);
  u16* VTb = (u16*)ealloc((size_t)NH * NSEQ * DHEAD * 2);
  u16* Ob = (u16*)ealloc((size_t)NSEQ * DMODEL * 2);
  u16* ff1b = (u16*)ealloc((size_t)NSEQ * FFD * 2);
  float* ct = (float*)ealloc((size_t)NSEQ * 32 * 4);
  float* st = (float*)ealloc((size_t)NSEQ * 32 * 4);
  u16* wlogT = (u16*)falloc((size_t)VOC * DMODEL * 2);
  u16* xn = (u16*)falloc((size_t)NSEQ * DMODEL * 2);

  k_rope<<<dim3(NSEQ), dim3(32), 0, stream>>>(ct, st);
  k_transpose<<<dim3(16, 48, NLAYER), 256, 0, stream>>>(
      w_qkv, wqkvT, DMODEL, 3072, (size_t)DMODEL * 3072, (size_t)3072 * DMODEL);
  k_transpose<<<dim3(16, 16, NLAYER), 256, 0, stream>>>(
      w_attn_out, wattnT, DMODEL, DMODEL, (size_t)DMODEL * DMODEL, (size_t)DMODEL * DMODEL);
  k_transpose<<<dim3(16, 64, NLAYER), 256, 0, stream>>>(
      w_ff1, wff1T, DMODEL, FFD, (size_t)DMODEL * FFD, (size_t)FFD * DMODEL);
  k_transpose<<<dim3(64, 16, NLAYER), 256, 0, stream>>>(
      w_ff2, wff2T, FFD, DMODEL, (size_t)FFD * DMODEL, (size_t)DMODEL * FFD);
  k_transpose<<<dim3(16, 500, 1), 256, 0, stream>>>(
      w_logits, wlogT, DMODEL, VOC, 0, 0);

  k_embed<<<dim3(NSEQ), 256, 0, stream>>>(x, emb, h);

  for (int lyr = 0; lyr < NLAYER; ++lyr) {
    k_rmsnorm<<<dim3(NSEQ), 256, 0, stream>>>(h, attn_gamma + (size_t)lyr * DMODEL, xn);
    k_gemmT<EPI_QKV, 64><<<dim3(32 * 24), 256, 0, stream>>>(
        xn, wqkvT + (size_t)lyr * 3072 * DMODEL, DMODEL, 3072, 32,
        nullptr, nullptr, nullptr, nullptr, Qr, Kr, VTb, ct, st);
    k_attn<<<dim3(NSEQ / 64, NH), 256, 0, stream>>>(Qr, Kr, VTb, Ob);
    k_gemmT<EPI_ADD, 64><<<dim3(32 * 8), 256, 0, stream>>>(
        Ob, wattnT + (size_t)lyr * DMODEL * DMODEL, DMODEL, DMODEL, 32,
        nullptr, h, h, nullptr, nullptr, nullptr, nullptr, nullptr, nullptr);
    k_rmsnorm<<<dim3(NSEQ), 256, 0, stream>>>(h, ff_gamma + (size_t)lyr * DMODEL, xn);
    k_gemmT<EPI_GELU, 128><<<dim3(16 * 32), 256, 0, stream>>>(
        xn, wff1T + (size_t)lyr * FFD * DMODEL, DMODEL, FFD, 16,
        b_ff1 + (size_t)lyr * FFD, nullptr, nullptr, ff1b,
        nullptr, nullptr, nullptr, nullptr, nullptr);
    k_gemmT<EPI_BIAS_ADD, 64><<<dim3(32 * 8), 256, 0, stream>>>(
        ff1b, wff2T + (size_t)lyr * DMODEL * FFD, FFD, DMODEL, 32,
        b_ff2 + (size_t)lyr * DMODEL, h, h, nullptr,
        nullptr, nullptr, nullptr, nullptr, nullptr);
  }

  k_rmsnorm<<<dim3(NSEQ), 256, 0, stream>>>(h, final_gamma, xn);
  k_gemmW<EPI_STORE><<<dim3(16 * 125), 256, 0, stream>>>(
      xn, wlogT, DMODEL, VOC, nullptr, out, nullptr);
}

// Round 12
// 1205.016 us; speedup vs baseline: 1.3705x; 1.0603x over previous
//
#include <hip/hip_runtime.h>
#include <math.h>

// Decoder forward, MI355X gfx950. Round 12: attn complementary-qb pairing
// (uniform per-CU work under static block->CU assignment); k_gemmT gains BN
// template — BN=64 tiles for attn_out/ff2 (512-block grids, 4 blk/CU);
// ff1 -> BM64/BN128 (1024 blocks, 3 blk/CU). Logits stays on k_gemmW.
//
// Dims (fixed): V=32000 D=1024 DEPTH=4 H=16 DH=64 FF=4096 B=1 N=2048

#define NSEQ 2048
#define DMODEL 1024
#define NH 16
#define DHEAD 64
#define FFD 4096
#define VOC 32000
#define NLAYER 4

typedef unsigned short u16;
typedef short bf16x8 __attribute__((ext_vector_type(8)));   // 8 bf16 in 4 VGPRs
typedef float f32x4 __attribute__((ext_vector_type(4)));

__device__ __forceinline__ u16 f2bf(float f) {
  unsigned int u = __builtin_bit_cast(unsigned int, f);
  u += 0x7fffu + ((u >> 16) & 1u);   // RNE
  return (u16)(u >> 16);
}

__device__ __forceinline__ void gload16(const void* g, void* l) {
  __builtin_amdgcn_global_load_lds((__attribute__((address_space(1))) void*)g,
                                   (__attribute__((address_space(3))) void*)l,
                                   16, 0, 0);
}

__device__ __forceinline__ f32x4 mfma16x32(bf16x8 a, bf16x8 b, f32x4 c) {
  return __builtin_amdgcn_mfma_f32_16x16x32_bf16(a, b, c, 0, 0, 0);
}

template <int N>
__device__ __forceinline__ void waitvm() {
  if constexpr (N == 0) asm volatile("s_waitcnt vmcnt(0)" ::: "memory");
  else if constexpr (N == 2) asm volatile("s_waitcnt vmcnt(2)" ::: "memory");
  else if constexpr (N == 3) asm volatile("s_waitcnt vmcnt(3)" ::: "memory");
  else if constexpr (N == 4) asm volatile("s_waitcnt vmcnt(4)" ::: "memory");
  else if constexpr (N == 6) asm volatile("s_waitcnt vmcnt(6)" ::: "memory");
  else if constexpr (N == 8) asm volatile("s_waitcnt vmcnt(8)" ::: "memory");
}

// ---------------------------------------------------------------- prep kernels

__global__ __launch_bounds__(256) void k_embed(const int* __restrict__ x,
                                               const float* __restrict__ emb,
                                               float* __restrict__ h) {
  const int n = blockIdx.x, t = threadIdx.x;
  const int tok = x[n];
  reinterpret_cast<float4*>(h + (size_t)n * DMODEL)[t] =
      reinterpret_cast<const float4*>(emb + (size_t)tok * DMODEL)[t];
}

__global__ void k_rope(float* __restrict__ ct, float* __restrict__ st) {
  const int n = blockIdx.x, p = threadIdx.x;  // 32 freq pairs
  const double inv = exp(-(double)(2 * p) / 64.0 * log(10000.0));
  const double a = (double)n * inv;
  ct[n * 32 + p] = (float)cos(a);
  st[n * 32 + p] = (float)sin(a);
}

// f32 [K][Nc] -> bf16 [Nc][K]; 64x64 tiles, float4 reads, ushort4 writes.
__global__ __launch_bounds__(256) void k_transpose(const float* __restrict__ in0,
                                                   u16* __restrict__ out0,
                                                   int K, int Nc,
                                                   size_t ls_in, size_t ls_out) {
  const float* in = in0 + blockIdx.z * ls_in;
  u16* out = out0 + blockIdx.z * ls_out;
  __shared__ float tile[64][65];
  const int kb = blockIdx.x * 64, nb = blockIdx.y * 64;
  const int tr = threadIdx.x >> 4;       // 0..15
  const int tc = threadIdx.x & 15;       // 0..15
#pragma unroll
  for (int r = 0; r < 64; r += 16) {
    const float4 v = *reinterpret_cast<const float4*>(
        &in[(size_t)(kb + r + tr) * Nc + nb + tc * 4]);
    tile[r + tr][tc * 4 + 0] = v.x;
    tile[r + tr][tc * 4 + 1] = v.y;
    tile[r + tr][tc * 4 + 2] = v.z;
    tile[r + tr][tc * 4 + 3] = v.w;
  }
  __syncthreads();
#pragma unroll
  for (int r = 0; r < 64; r += 16) {
    const int n = r + tr;
    ushort4 o;
    o.x = f2bf(tile[tc * 4 + 0][n]);
    o.y = f2bf(tile[tc * 4 + 1][n]);
    o.z = f2bf(tile[tc * 4 + 2][n]);
    o.w = f2bf(tile[tc * 4 + 3][n]);
    *reinterpret_cast<ushort4*>(&out[(size_t)(nb + n) * K + kb + tc * 4]) = o;
  }
}

// rms_norm(h)*gamma -> bf16 (GEMM A input). One row per block (256 thr, float4).
__global__ __launch_bounds__(256) void k_rmsnorm(const float* __restrict__ h,
                                                 const float* __restrict__ gamma,
                                                 u16* __restrict__ out) {
  __shared__ float red[4];
  const int n = blockIdx.x, t = threadIdx.x;
  const float4 v = reinterpret_cast<const float4*>(h + (size_t)n * DMODEL)[t];
  float ss = v.x * v.x + v.y * v.y + v.z * v.z + v.w * v.w;
#pragma unroll
  for (int off = 32; off; off >>= 1) ss += __shfl_down(ss, off);
  if ((t & 63) == 0) red[t >> 6] = ss;
  __syncthreads();
  const float tot = red[0] + red[1] + red[2] + red[3];
  const float inv = 32.0f / fmaxf(sqrtf(tot), 1e-12f);  // sqrt(1024)=32
  const float4 g = reinterpret_cast<const float4*>(gamma)[t];
  ushort4 o;
  o.x = f2bf(v.x * inv * g.x);
  o.y = f2bf(v.y * inv * g.y);
  o.z = f2bf(v.z * inv * g.z);
  o.w = f2bf(v.w * inv * g.w);
  reinterpret_cast<ushort4*>(out + (size_t)n * DMODEL)[t] = o;
}

// ---------------------------------------------------------------- GEMM epilogues
#define EPI_STORE 0
#define EPI_ADD 1
#define EPI_GELU 2
#define EPI_BIAS_ADD 3
#define EPI_QKV 4

// 64B rows = 4 slots of 16B; 2-level swizzle on SOURCE and READ (both sides).
__device__ __forceinline__ bf16x8 ldsfragT(const char* base, int row, int lg) {
  return *reinterpret_cast<const bf16x8*>(
      base + row * 64 + (((lg ^ (row & 3) ^ ((row >> 2) & 3)) & 3) << 4));
}

// ---------------- k_gemmT: BMxBNxBK32, QUAD-buffer, counted vmcnt ------------
// Tile t staged at iteration t-3 (lead 2 iterations ~1200cyc > HBM latency).
// Boundary waits: t+3<nt: vmcnt(2*SL); t+2<nt: vmcnt(SL); else vmcnt(0).
// SL = BM/64 + BN/64 loads per stage. Staging dest lane-linear tid*16 (m104).
// 4 waves 2x2, wave tile (BM/2)x(BN/2).
template <int EPI, int BM, int BN>
__global__ __launch_bounds__(256) void k_gemmT(
    const u16* __restrict__ A, const u16* __restrict__ BT, int K, int Nc,
    int NMB, const float* __restrict__ bias, const float* __restrict__ add,
    float* __restrict__ outf, u16* __restrict__ outb,
    u16* __restrict__ Qr, u16* __restrict__ Kr, u16* __restrict__ VT,
    const float* __restrict__ ct, const float* __restrict__ st) {
  constexpr int MFR = BM / 32;            // A frags per wave
  constexpr int NFR = BN / 32;            // B frags per wave
  constexpr int ABYTES = BM * 64;         // BM rows x 32 k x 2B
  constexpr int BBYTES = BN * 64;
  constexpr int BUFB = ABYTES + BBYTES;
  constexpr int SL = BM / 64 + BN / 64;   // loads per stage
  __shared__ alignas(16) char sm[4 * BUFB];
  const int nt = K >> 5;
  const int nwg = gridDim.x;
  int swz = blockIdx.x;
  if ((nwg & 7) == 0) swz = (swz & 7) * (nwg >> 3) + (swz >> 3);
  const int mb = swz % NMB, nb = swz / NMB;  // m-fast: B panel L2-resident
  const int m0 = mb * BM, n0 = nb * BN;

  const int tid = threadIdx.x, w = tid >> 6, lane = tid & 63;
  const int wr = w >> 1, wc = w & 1;
  const int lr = lane & 15, lg = lane >> 4;

  const int srow = tid >> 2;
  const int gslot = (tid & 3) ^ (srow & 3) ^ ((srow >> 2) & 3);
  const u16* ga0 = A + (size_t)(m0 + srow) * K + gslot * 8;
  const u16* ga1 = A + (size_t)(m0 + (BM == 128 ? 64 : 0) + srow) * K + gslot * 8;
  const u16* gb0 = BT + (size_t)(n0 + srow) * K + gslot * 8;
  const u16* gb1 = BT + (size_t)(n0 + (BN == 128 ? 64 : 0) + srow) * K + gslot * 8;
  const int ldOff = tid * 16;             // lane-linear dest (m104)

  auto stage = [&](int b) {
    char* base = sm + b * BUFB;
    gload16(ga0, base + ldOff);
    if constexpr (BM == 128) gload16(ga1, base + 4096 + ldOff);
    gload16(gb0, base + ABYTES + ldOff);
    if constexpr (BN == 128) gload16(gb1, base + ABYTES + 4096 + ldOff);
    ga0 += 32; gb0 += 32;
    if constexpr (BM == 128) ga1 += 32;
    if constexpr (BN == 128) gb1 += 32;
  };

  stage(0);
  stage(1);
  stage(2);
  waitvm<2 * SL>();                        // tile0 landed; 1,2 in flight
  __builtin_amdgcn_s_barrier();

  f32x4 acc[MFR][NFR] = {};
  int cur = 0;
  for (int t = 0; t < nt; ++t) {
    const char* Ab = sm + cur * BUFB;
    const char* Bb = Ab + ABYTES;
    bf16x8 af[MFR], bf[NFR];
#pragma unroll
    for (int i = 0; i < MFR; ++i)
      af[i] = ldsfragT(Ab, wr * (BM / 2) + i * 16 + lr, lg);
#pragma unroll
    for (int i = 0; i < NFR; ++i)
      bf[i] = ldsfragT(Bb, wc * (BN / 2) + i * 16 + lr, lg);
    if (t + 3 < nt) stage((cur + 3) & 3);
    __builtin_amdgcn_s_setprio(1);
#pragma unroll
    for (int mi = 0; mi < MFR; ++mi)
#pragma unroll
      for (int nj = 0; nj < NFR; ++nj)
        acc[mi][nj] = mfma16x32(af[mi], bf[nj], acc[mi][nj]);
    __builtin_amdgcn_s_setprio(0);
    if (t + 1 < nt) {
      __builtin_amdgcn_sched_barrier(0);
      if (t + 3 < nt)      waitvm<2 * SL>();
      else if (t + 2 < nt) waitvm<SL>();
      else                 waitvm<0>();
      __builtin_amdgcn_s_barrier();
      __builtin_amdgcn_sched_barrier(0);
    }
    cur = (cur + 1) & 3;
  }

  if constexpr (EPI == EPI_QKV) {
    // qkv: BN=128; wave tile cols 64 = one head. which = col block /1024.
    const int which = n0 >> 10;
    const int hh = ((n0 & 1023) >> 6) + wc;
#pragma unroll
    for (int mi = 0; mi < MFR; ++mi) {
#pragma unroll
      for (int nj = 0; nj < NFR; ++nj) {
        const int d = nj * 16 + lr;
#pragma unroll
        for (int r = 0; r < 4; ++r) {
          const int row = m0 + wr * (BM / 2) + mi * 16 + lg * 4 + r;
          const float v = acc[mi][nj][r];
          if (which == 2) {
            VT[((size_t)hh * DHEAD + d) * NSEQ + row] = f2bf(v);
          } else {
            const float part = __shfl_xor(v, 1);
            const float sgn = (d & 1) ? 1.0f : -1.0f;
            const float c = ct[row * 32 + (d >> 1)];
            const float s_ = st[row * 32 + (d >> 1)];
            const u16 o = f2bf(v * c + sgn * part * s_);
            u16* dst = (which == 0) ? Qr : Kr;
            dst[((size_t)hh * NSEQ + row) * DHEAD + d] = o;
          }
        }
      }
    }
    return;
  }
#pragma unroll
  for (int mi = 0; mi < MFR; ++mi) {
#pragma unroll
    for (int nj = 0; nj < NFR; ++nj) {
      const int col = n0 + wc * (BN / 2) + nj * 16 + lr;
#pragma unroll
      for (int r = 0; r < 4; ++r) {
        const int row = m0 + wr * (BM / 2) + mi * 16 + lg * 4 + r;
        const size_t idx = (size_t)row * Nc + col;
        float v = acc[mi][nj][r];
        if (EPI == EPI_GELU) {
          v += bias[col];
          v = 0.5f * v * (1.0f + erff(v * 0.70710678118654752f));
          outb[idx] = f2bf(v);
        } else if (EPI == EPI_ADD) {
          outf[idx] = v + add[idx];
        } else if (EPI == EPI_BIAS_ADD) {
          outf[idx] = v + bias[col] + add[idx];
        } else {
          outf[idx] = v;
        }
      }
    }
  }
}

// ---------------- k_gemmW: 128x256xBK32, wave tile 64x128 (R9 exact) ---------
// Tri-buffer 72KB (2 blk/CU); best measured logits kernel (175us).
template <int EPI>
__global__ __launch_bounds__(256, 2) void k_gemmW(
    const u16* __restrict__ A, const u16* __restrict__ BT, int K, int Nc,
    const float* __restrict__ bias, float* __restrict__ outf,
    u16* __restrict__ outb) {
  constexpr int ABYTES = 8192;            // 128 rows x 32 k x 2B
  constexpr int BUFB = ABYTES + 16384;    // + 256 rows B
  __shared__ alignas(16) char sm[3 * BUFB];
  const int nt = K >> 5;
  const int NMB = 16;
  const int nwg = gridDim.x;
  int swz = blockIdx.x;
  if ((nwg & 7) == 0) swz = (swz & 7) * (nwg >> 3) + (swz >> 3);
  const int mb = swz % NMB, nb = swz / NMB;
  const int m0 = mb * 128, n0 = nb * 256;

  const int tid = threadIdx.x, w = tid >> 6, lane = tid & 63;
  const int wr = w >> 1, wc = w & 1;      // wave tile 64 x 128
  const int lr = lane & 15, lg = lane >> 4;

  const int srow = tid >> 2;
  const int gslot = (tid & 3) ^ (srow & 3) ^ ((srow >> 2) & 3);
  const u16* ga0 = A + (size_t)(m0 + srow) * K + gslot * 8;
  const u16* ga1 = A + (size_t)(m0 + 64 + srow) * K + gslot * 8;
  const u16* gb0 = BT + (size_t)(n0 + srow) * K + gslot * 8;
  const u16* gb1 = BT + (size_t)(n0 + 64 + srow) * K + gslot * 8;
  const u16* gb2 = BT + (size_t)(n0 + 128 + srow) * K + gslot * 8;
  const u16* gb3 = BT + (size_t)(n0 + 192 + srow) * K + gslot * 8;
  const int ldOff = tid * 16;

  auto stage = [&](int b) {
    char* base = sm + b * BUFB;
    gload16(ga0, base + ldOff);
    gload16(ga1, base + 4096 + ldOff);
    gload16(gb0, base + ABYTES + ldOff);
    gload16(gb1, base + ABYTES + 4096 + ldOff);
    gload16(gb2, base + ABYTES + 8192 + ldOff);
    gload16(gb3, base + ABYTES + 12288 + ldOff);
    ga0 += 32; ga1 += 32; gb0 += 32; gb1 += 32; gb2 += 32; gb3 += 32;
  };

  stage(0);
  stage(1);
  waitvm<6>();
  __builtin_amdgcn_s_barrier();

  f32x4 acc[4][8] = {};
  int cur = 0, nx2 = 2;
  for (int t = 0; t < nt; ++t) {
    const char* Ab = sm + cur * BUFB;
    const char* Bb = Ab + ABYTES;
    const bool pf = (t + 2 < nt);
    bf16x8 af[4], bf[8];
#pragma unroll
    for (int i = 0; i < 4; ++i)
      af[i] = ldsfragT(Ab, wr * 64 + i * 16 + lr, lg);
#pragma unroll
    for (int i = 0; i < 8; ++i)
      bf[i] = ldsfragT(Bb, wc * 128 + i * 16 + lr, lg);
    if (pf) stage(nx2);
    __builtin_amdgcn_s_setprio(1);
#pragma unroll
    for (int mi = 0; mi < 4; ++mi)
#pragma unroll
      for (int nj = 0; nj < 8; ++nj)
        acc[mi][nj] = mfma16x32(af[mi], bf[nj], acc[mi][nj]);
    __builtin_amdgcn_s_setprio(0);
    if (t + 1 < nt) {
      __builtin_amdgcn_sched_barrier(0);
      if (pf) waitvm<6>();
      else    waitvm<0>();
      __builtin_amdgcn_s_barrier();
      __builtin_amdgcn_sched_barrier(0);
    }
    cur = (cur == 2) ? 0 : cur + 1;
    nx2 = (nx2 == 2) ? 0 : nx2 + 1;
  }

#pragma unroll
  for (int mi = 0; mi < 4; ++mi) {
#pragma unroll
    for (int nj = 0; nj < 8; ++nj) {
      const int col = n0 + wc * 128 + nj * 16 + lr;
#pragma unroll
      for (int r = 0; r < 4; ++r) {
        const int row = m0 + wr * 64 + mi * 16 + lg * 4 + r;
        const size_t idx = (size_t)row * Nc + col;
        float v = acc[mi][nj][r];
        if (EPI == EPI_GELU) {
          v += bias[col];
          v = 0.5f * v * (1.0f + erff(v * 0.70710678118654752f));
          outb[idx] = f2bf(v);
        } else {
          outf[idx] = v;
        }
      }
    }
  }
}

// ---------------------------------------------------------------- attention
// 512 blocks, 1-D grid remapped so blocks id and id+256 (which land on the
// same CU under round-robin assignment) get COMPLEMENTARY causal weights
// (qb and 31-qb) -> uniform ~64 j-iterations per CU instead of up to ~124.
// Next-iteration K/V register prefetch hides L2 latency.
__global__ __launch_bounds__(256) void k_attn(const u16* __restrict__ Qr,
                                              const u16* __restrict__ Kr,
                                              const u16* __restrict__ VT,
                                              u16* __restrict__ O) {
  __shared__ alignas(16) u16 Pl[4][16 * 32];
  const int id = blockIdx.x;
  int qb, hh;
  if (id < 256) { qb = id & 31; hh = id >> 5; }
  else          { qb = 31 - (id & 31); hh = 8 + ((id - 256) >> 5); }
  const int w = threadIdx.x >> 6, lane = threadIdx.x & 63;
  const int lr = lane & 15, lg = lane >> 4;
  const int q0 = qb * 64 + w * 16;
  const u16* Qh = Qr + (size_t)hh * NSEQ * DHEAD;
  const u16* Kh = Kr + (size_t)hh * NSEQ * DHEAD;
  const u16* Vh = VT + (size_t)hh * DHEAD * NSEQ;
  u16* Pw = Pl[w];

  const bf16x8 aq0 = *reinterpret_cast<const bf16x8*>(Qh + (q0 + lr) * DHEAD + lg * 8);
  const bf16x8 aq1 = *reinterpret_cast<const bf16x8*>(Qh + (q0 + lr) * DHEAD + 32 + lg * 8);

  f32x4 o0 = {}, o1 = {}, o2 = {}, o3 = {};
  float m[4], l[4];
#pragma unroll
  for (int r = 0; r < 4; ++r) { m[r] = -1e30f; l[r] = 0.0f; }

  const int jend = q0 + 15;

  auto loadK = [&](int j0, bf16x8* bk) {
    bk[0] = *reinterpret_cast<const bf16x8*>(Kh + (j0 + lr) * DHEAD + lg * 8);
    bk[1] = *reinterpret_cast<const bf16x8*>(Kh + (j0 + lr) * DHEAD + 32 + lg * 8);
    bk[2] = *reinterpret_cast<const bf16x8*>(Kh + (j0 + 16 + lr) * DHEAD + lg * 8);
    bk[3] = *reinterpret_cast<const bf16x8*>(Kh + (j0 + 16 + lr) * DHEAD + 32 + lg * 8);
  };
  auto loadV = [&](int j0, bf16x8* vv) {
    const u16* vb = Vh + j0 + lg * 8;
    vv[0] = *reinterpret_cast<const bf16x8*>(vb + (0 + lr) * NSEQ);
    vv[1] = *reinterpret_cast<const bf16x8*>(vb + (16 + lr) * NSEQ);
    vv[2] = *reinterpret_cast<const bf16x8*>(vb + (32 + lr) * NSEQ);
    vv[3] = *reinterpret_cast<const bf16x8*>(vb + (48 + lr) * NSEQ);
  };

  bf16x8 bk[4], vv[4], bkN[4], vvN[4];
  loadK(0, bk);
  loadV(0, vv);

  for (int j0 = 0; j0 <= jend; j0 += 32) {
    if (j0 + 32 <= jend) { loadK(j0 + 32, bkN); loadV(j0 + 32, vvN); }

    f32x4 s0 = {}, s1 = {};
    s0 = mfma16x32(aq0, bk[0], s0);
    s0 = mfma16x32(aq1, bk[1], s0);
    s1 = mfma16x32(aq0, bk[2], s1);
    s1 = mfma16x32(aq1, bk[3], s1);

    float sv0[4], sv1[4], pm[4];
#pragma unroll
    for (int r = 0; r < 4; ++r) {
      const int irow = q0 + lg * 4 + r;
      sv0[r] = (j0 + lr > irow) ? -1e30f : s0[r] * 0.125f;
      sv1[r] = (j0 + 16 + lr > irow) ? -1e30f : s1[r] * 0.125f;
      pm[r] = fmaxf(sv0[r], sv1[r]);
    }
#pragma unroll
    for (int off = 1; off < 16; off <<= 1)
#pragma unroll
      for (int r = 0; r < 4; ++r) pm[r] = fmaxf(pm[r], __shfl_xor(pm[r], off));
    float p0[4], p1[4], rs[4];
    f32x4 fv;
#pragma unroll
    for (int r = 0; r < 4; ++r) {
      const float mn = fmaxf(m[r], pm[r]);
      fv[r] = __expf(m[r] - mn);
      m[r] = mn;
      p0[r] = __expf(sv0[r] - mn);
      p1[r] = __expf(sv1[r] - mn);
      rs[r] = p0[r] + p1[r];
    }
#pragma unroll
    for (int off = 1; off < 16; off <<= 1)
#pragma unroll
      for (int r = 0; r < 4; ++r) rs[r] += __shfl_xor(rs[r], off);
#pragma unroll
    for (int r = 0; r < 4; ++r) l[r] = l[r] * fv[r] + rs[r];
    o0 *= fv; o1 *= fv; o2 *= fv; o3 *= fv;

#pragma unroll
    for (int r = 0; r < 4; ++r) {
      Pw[(lg * 4 + r) * 32 + lr] = f2bf(p0[r]);
      Pw[(lg * 4 + r) * 32 + 16 + lr] = f2bf(p1[r]);
    }
    const bf16x8 pa = *reinterpret_cast<const bf16x8*>(Pw + lr * 32 + lg * 8);
    o0 = mfma16x32(pa, vv[0], o0);
    o1 = mfma16x32(pa, vv[1], o1);
    o2 = mfma16x32(pa, vv[2], o2);
    o3 = mfma16x32(pa, vv[3], o3);

#pragma unroll
    for (int i = 0; i < 4; ++i) { bk[i] = bkN[i]; vv[i] = vvN[i]; }
  }

#pragma unroll
  for (int r = 0; r < 4; ++r) {
    const int row = q0 + lg * 4 + r;
    const float invl = 1.0f / l[r];
    u16* orow = O + (size_t)row * DMODEL + hh * DHEAD;
    orow[0 * 16 + lr] = f2bf(o0[r] * invl);
    orow[1 * 16 + lr] = f2bf(o1[r] * invl);
    orow[2 * 16 + lr] = f2bf(o2[r] * invl);
    orow[3 * 16 + lr] = f2bf(o3[r] * invl);
  }
}

// ---------------------------------------------------------------- launch

extern "C" void kernel_launch(void* const* d_in, const int* in_sizes, int n_in,
                              void* d_out, int out_size, void* d_ws, size_t ws_size,
                              hipStream_t stream) {
  (void)in_sizes; (void)n_in;
  const int* x = (const int*)d_in[0];
  const float* emb = (const float*)d_in[1];
  const float* attn_gamma = (const float*)d_in[2];
  const float* w_qkv = (const float*)d_in[3];
  const float* w_attn_out = (const float*)d_in[4];
  const float* ff_gamma = (const float*)d_in[5];
  const float* w_ff1 = (const float*)d_in[6];
  const float* b_ff1 = (const float*)d_in[7];
  const float* w_ff2 = (const float*)d_in[8];
  const float* b_ff2 = (const float*)d_in[9];
  const float* final_gamma = (const float*)d_in[10];
  const float* w_logits = (const float*)d_in[11];
  float* out = (float*)d_out;

  const size_t EARLY_NEED = 176ull << 20;
  const size_t FINAL_NEED = 72ull << 20;
  char* earlyBase;
  char* finalBase;
  if (ws_size >= EARLY_NEED + FINAL_NEED) {
    earlyBase = (char*)d_ws;
    finalBase = (char*)d_ws + EARLY_NEED;
  } else if (ws_size >= FINAL_NEED && (size_t)out_size * 4 >= EARLY_NEED) {
    earlyBase = (char*)d_out;
    finalBase = (char*)d_ws;
  } else {
    return;
  }
  size_t eoff = 0, foff = 0;
  auto ealloc = [&](size_t b) { void* p = earlyBase + eoff; eoff += (b + 255) & ~(size_t)255; return p; };
  auto falloc = [&](size_t b) { void* p = finalBase + foff; foff += (b + 255) & ~(size_t)255; return p; };

  u16* wqkvT = (u16*)ealloc((size_t)NLAYER * 3072 * DMODEL * 2);
  u16* wattnT = (u16*)ealloc((size_t)NLAYER * DMODEL * DMODEL * 2);
  u16* wff1T = (u16*)ealloc((size_t)NLAYER * FFD * DMODEL * 2);
  u16* wff2T = (u16*)ealloc((size_t)NLAYER * DMODEL * FFD * 2);
  float* h = (float*)ealloc((size_t)NSEQ * DMODEL * 4);
  u16* Qr = (u16*)ealloc((size_t)NH * NSEQ * DHEAD * 2);
  u16* Kr = (u16*)ealloc((size_t)NH * NSEQ * DHEAD * 2);
  u16* VTb = (u16*)ealloc((size_t)NH * NSEQ * DHEAD * 2);
  u16* Ob = (u16*)ealloc((size_t)NSEQ * DMODEL * 2);
  u16* ff1b = (u16*)ealloc((size_t)NSEQ * FFD * 2);
  float* ct = (float*)ealloc((size_t)NSEQ * 32 * 4);
  float* st = (float*)ealloc((size_t)NSEQ * 32 * 4);
  u16* wlogT = (u16*)falloc((size_t)VOC * DMODEL * 2);
  u16* xn = (u16*)falloc((size_t)NSEQ * DMODEL * 2);

  k_rope<<<dim3(NSEQ), dim3(32), 0, stream>>>(ct, st);
  k_transpose<<<dim3(16, 48, NLAYER), 256, 0, stream>>>(
      w_qkv, wqkvT, DMODEL, 3072, (size_t)DMODEL * 3072, (size_t)3072 * DMODEL);
  k_transpose<<<dim3(16, 16, NLAYER), 256, 0, stream>>>(
      w_attn_out, wattnT, DMODEL, DMODEL, (size_t)DMODEL * DMODEL, (size_t)DMODEL * DMODEL);
  k_transpose<<<dim3(16, 64, NLAYER), 256, 0, stream>>>(
      w_ff1, wff1T, DMODEL, FFD, (size_t)DMODEL * FFD, (size_t)FFD * DMODEL);
  k_transpose<<<dim3(64, 16, NLAYER), 256, 0, stream>>>(
      w_ff2, wff2T, FFD, DMODEL, (size_t)FFD * DMODEL, (size_t)DMODEL * FFD);
  k_transpose<<<dim3(16, 500, 1), 256, 0, stream>>>(
      w_logits, wlogT, DMODEL, VOC, 0, 0);

  k_embed<<<dim3(NSEQ), 256, 0, stream>>>(x, emb, h);

  for (int lyr = 0; lyr < NLAYER; ++lyr) {
    k_rmsnorm<<<dim3(NSEQ), 256, 0, stream>>>(h, attn_gamma + (size_t)lyr * DMODEL, xn);
    k_gemmT<EPI_QKV, 64, 128><<<dim3(32 * 24), 256, 0, stream>>>(
        xn, wqkvT + (size_t)lyr * 3072 * DMODEL, DMODEL, 3072, 32,
        nullptr, nullptr, nullptr, nullptr, Qr, Kr, VTb, ct, st);
    k_attn<<<dim3(512), 256, 0, stream>>>(Qr, Kr, VTb, Ob);
    k_gemmT<EPI_ADD, 64, 64><<<dim3(32 * 16), 256, 0, stream>>>(
        Ob, wattnT + (size_t)lyr * DMODEL * DMODEL, DMODEL, DMODEL, 32,
        nullptr, h, h, nullptr, nullptr, nullptr, nullptr, nullptr, nullptr);
    k_rmsnorm<<<dim3(NSEQ), 256, 0, stream>>>(h, ff_gamma + (size_t)lyr * DMODEL, xn);
    k_gemmT<EPI_GELU, 64, 128><<<dim3(32 * 32), 256, 0, stream>>>(
        xn, wff1T + (size_t)lyr * FFD * DMODEL, DMODEL, FFD, 32,
        b_ff1 + (size_t)lyr * FFD, nullptr, nullptr, ff1b,
        nullptr, nullptr, nullptr, nullptr, nullptr);
    k_gemmT<EPI_BIAS_ADD, 64, 64><<<dim3(32 * 16), 256, 0, stream>>>(
        ff1b, wff2T + (size_t)lyr * DMODEL * FFD, FFD, DMODEL, 32,
        b_ff2 + (size_t)lyr * DMODEL, h, h, nullptr,
        nullptr, nullptr, nullptr, nullptr, nullptr);
  }

  k_rmsnorm<<<dim3(NSEQ), 256, 0, stream>>>(h, final_gamma, xn);
  k_gemmW<EPI_STORE><<<dim3(16 * 125), 256, 0, stream>>>(
      xn, wlogT, DMODEL, VOC, nullptr, out, nullptr);
}

// Round 13
// 1194.033 us; speedup vs baseline: 1.3831x; 1.0092x over previous
//
#include <hip/hip_runtime.h>
#include <math.h>

// Decoder forward, MI355X gfx950. Round 13: nontemporal stores for logits
// output + weight-transpose outputs (kill L2 write-pollution -> B panels stay
// resident); ff2 split-K=2 via f32 atomicAdd into h (1024-block grid, 64
// K-iters/block). Everything else frozen from R12.
//
// Dims (fixed): V=32000 D=1024 DEPTH=4 H=16 DH=64 FF=4096 B=1 N=2048

#define NSEQ 2048
#define DMODEL 1024
#define NH 16
#define DHEAD 64
#define FFD 4096
#define VOC 32000
#define NLAYER 4

typedef unsigned short u16;
typedef short bf16x8 __attribute__((ext_vector_type(8)));   // 8 bf16 in 4 VGPRs
typedef float f32x4 __attribute__((ext_vector_type(4)));

__device__ __forceinline__ u16 f2bf(float f) {
  unsigned int u = __builtin_bit_cast(unsigned int, f);
  u += 0x7fffu + ((u >> 16) & 1u);   // RNE
  return (u16)(u >> 16);
}

__device__ __forceinline__ void gload16(const void* g, void* l) {
  __builtin_amdgcn_global_load_lds((__attribute__((address_space(1))) void*)g,
                                   (__attribute__((address_space(3))) void*)l,
                                   16, 0, 0);
}

__device__ __forceinline__ f32x4 mfma16x32(bf16x8 a, bf16x8 b, f32x4 c) {
  return __builtin_amdgcn_mfma_f32_16x16x32_bf16(a, b, c, 0, 0, 0);
}

template <int N>
__device__ __forceinline__ void waitvm() {
  if constexpr (N == 0) asm volatile("s_waitcnt vmcnt(0)" ::: "memory");
  else if constexpr (N == 2) asm volatile("s_waitcnt vmcnt(2)" ::: "memory");
  else if constexpr (N == 3) asm volatile("s_waitcnt vmcnt(3)" ::: "memory");
  else if constexpr (N == 4) asm volatile("s_waitcnt vmcnt(4)" ::: "memory");
  else if constexpr (N == 6) asm volatile("s_waitcnt vmcnt(6)" ::: "memory");
  else if constexpr (N == 8) asm volatile("s_waitcnt vmcnt(8)" ::: "memory");
}

// ---------------------------------------------------------------- prep kernels

__global__ __launch_bounds__(256) void k_embed(const int* __restrict__ x,
                                               const float* __restrict__ emb,
                                               float* __restrict__ h) {
  const int n = blockIdx.x, t = threadIdx.x;
  const int tok = x[n];
  reinterpret_cast<float4*>(h + (size_t)n * DMODEL)[t] =
      reinterpret_cast<const float4*>(emb + (size_t)tok * DMODEL)[t];
}

__global__ void k_rope(float* __restrict__ ct, float* __restrict__ st) {
  const int n = blockIdx.x, p = threadIdx.x;  // 32 freq pairs
  const double inv = exp(-(double)(2 * p) / 64.0 * log(10000.0));
  const double a = (double)n * inv;
  ct[n * 32 + p] = (float)cos(a);
  st[n * 32 + p] = (float)sin(a);
}

// f32 [K][Nc] -> bf16 [Nc][K]; 64x64 tiles, float4 reads, nontemporal ushort4
// writes (written once, read after >L2-capacity has streamed by).
__global__ __launch_bounds__(256) void k_transpose(const float* __restrict__ in0,
                                                   u16* __restrict__ out0,
                                                   int K, int Nc,
                                                   size_t ls_in, size_t ls_out) {
  const float* in = in0 + blockIdx.z * ls_in;
  u16* out = out0 + blockIdx.z * ls_out;
  __shared__ float tile[64][65];
  const int kb = blockIdx.x * 64, nb = blockIdx.y * 64;
  const int tr = threadIdx.x >> 4;       // 0..15
  const int tc = threadIdx.x & 15;       // 0..15
#pragma unroll
  for (int r = 0; r < 64; r += 16) {
    const float4 v = *reinterpret_cast<const float4*>(
        &in[(size_t)(kb + r + tr) * Nc + nb + tc * 4]);
    tile[r + tr][tc * 4 + 0] = v.x;
    tile[r + tr][tc * 4 + 1] = v.y;
    tile[r + tr][tc * 4 + 2] = v.z;
    tile[r + tr][tc * 4 + 3] = v.w;
  }
  __syncthreads();
#pragma unroll
  for (int r = 0; r < 64; r += 16) {
    const int n = r + tr;
    ushort4 o;
    o.x = f2bf(tile[tc * 4 + 0][n]);
    o.y = f2bf(tile[tc * 4 + 1][n]);
    o.z = f2bf(tile[tc * 4 + 2][n]);
    o.w = f2bf(tile[tc * 4 + 3][n]);
    const unsigned long long ull = __builtin_bit_cast(unsigned long long, o);
    __builtin_nontemporal_store(
        ull, reinterpret_cast<unsigned long long*>(
                 &out[(size_t)(nb + n) * K + kb + tc * 4]));
  }
}

// rms_norm(h)*gamma -> bf16 (GEMM A input). One row per block (256 thr, float4).
__global__ __launch_bounds__(256) void k_rmsnorm(const float* __restrict__ h,
                                                 const float* __restrict__ gamma,
                                                 u16* __restrict__ out) {
  __shared__ float red[4];
  const int n = blockIdx.x, t = threadIdx.x;
  const float4 v = reinterpret_cast<const float4*>(h + (size_t)n * DMODEL)[t];
  float ss = v.x * v.x + v.y * v.y + v.z * v.z + v.w * v.w;
#pragma unroll
  for (int off = 32; off; off >>= 1) ss += __shfl_down(ss, off);
  if ((t & 63) == 0) red[t >> 6] = ss;
  __syncthreads();
  const float tot = red[0] + red[1] + red[2] + red[3];
  const float inv = 32.0f / fmaxf(sqrtf(tot), 1e-12f);  // sqrt(1024)=32
  const float4 g = reinterpret_cast<const float4*>(gamma)[t];
  ushort4 o;
  o.x = f2bf(v.x * inv * g.x);
  o.y = f2bf(v.y * inv * g.y);
  o.z = f2bf(v.z * inv * g.z);
  o.w = f2bf(v.w * inv * g.w);
  reinterpret_cast<ushort4*>(out + (size_t)n * DMODEL)[t] = o;
}

// ---------------------------------------------------------------- GEMM epilogues
#define EPI_STORE 0
#define EPI_ADD 1
#define EPI_GELU 2
#define EPI_BIAS_ADD 3
#define EPI_QKV 4
#define EPI_ATOM 5

// 64B rows = 4 slots of 16B; 2-level swizzle on SOURCE and READ (both sides).
__device__ __forceinline__ bf16x8 ldsfragT(const char* base, int row, int lg) {
  return *reinterpret_cast<const bf16x8*>(
      base + row * 64 + (((lg ^ (row & 3) ^ ((row >> 2) & 3)) & 3) << 4));
}

// ---------------- k_gemmT: BMxBNxBK32, QUAD-buffer, counted vmcnt ------------
// Tile t staged at iteration t-3 (lead 2 iterations ~1200cyc > HBM latency).
// Boundary waits: t+3<nt: vmcnt(2*SL); t+2<nt: vmcnt(SL); else vmcnt(0).
// SL = BM/64 + BN/64 loads per stage. Staging dest lane-linear tid*16 (m104).
// 4 waves 2x2, wave tile (BM/2)x(BN/2). KSPLIT=2: outer half of the grid
// handles k in [K, 2K) (lda = K*KSPLIT); EPI_ATOM reduces via atomicAdd.
template <int EPI, int BM, int BN, int KSPLIT>
__global__ __launch_bounds__(256) void k_gemmT(
    const u16* __restrict__ A, const u16* __restrict__ BT, int K, int Nc,
    int NMB, const float* __restrict__ bias, const float* __restrict__ add,
    float* __restrict__ outf, u16* __restrict__ outb,
    u16* __restrict__ Qr, u16* __restrict__ Kr, u16* __restrict__ VT,
    const float* __restrict__ ct, const float* __restrict__ st) {
  constexpr int MFR = BM / 32;            // A frags per wave
  constexpr int NFR = BN / 32;            // B frags per wave
  constexpr int ABYTES = BM * 64;         // BM rows x 32 k x 2B
  constexpr int BBYTES = BN * 64;
  constexpr int BUFB = ABYTES + BBYTES;
  constexpr int SL = BM / 64 + BN / 64;   // loads per stage
  __shared__ alignas(16) char sm[4 * BUFB];
  const int nt = K >> 5;
  int bid = blockIdx.x;
  int ksp = 0;
  int inner = gridDim.x;
  if constexpr (KSPLIT == 2) {
    inner = gridDim.x >> 1;
    ksp = bid / inner;
    bid = bid % inner;
  }
  int swz = bid;
  if ((inner & 7) == 0) swz = (swz & 7) * (inner >> 3) + (swz >> 3);
  const int mb = swz % NMB, nb = swz / NMB;  // m-fast: B panel L2-resident
  const int m0 = mb * BM, n0 = nb * BN;
  const int lda = K * KSPLIT;
  const size_t kofs = (size_t)ksp * K;

  const int tid = threadIdx.x, w = tid >> 6, lane = tid & 63;
  const int wr = w >> 1, wc = w & 1;
  const int lr = lane & 15, lg = lane >> 4;

  const int srow = tid >> 2;
  const int gslot = (tid & 3) ^ (srow & 3) ^ ((srow >> 2) & 3);
  const u16* ga0 = A + (size_t)(m0 + srow) * lda + kofs + gslot * 8;
  const u16* ga1 = A + (size_t)(m0 + (BM == 128 ? 64 : 0) + srow) * lda + kofs + gslot * 8;
  const u16* gb0 = BT + (size_t)(n0 + srow) * lda + kofs + gslot * 8;
  const u16* gb1 = BT + (size_t)(n0 + (BN == 128 ? 64 : 0) + srow) * lda + kofs + gslot * 8;
  const int ldOff = tid * 16;             // lane-linear dest (m104)

  auto stage = [&](int b) {
    char* base = sm + b * BUFB;
    gload16(ga0, base + ldOff);
    if constexpr (BM == 128) gload16(ga1, base + 4096 + ldOff);
    gload16(gb0, base + ABYTES + ldOff);
    if constexpr (BN == 128) gload16(gb1, base + ABYTES + 4096 + ldOff);
    ga0 += 32; gb0 += 32;
    if constexpr (BM == 128) ga1 += 32;
    if constexpr (BN == 128) gb1 += 32;
  };

  stage(0);
  stage(1);
  stage(2);
  waitvm<2 * SL>();                        // tile0 landed; 1,2 in flight
  __builtin_amdgcn_s_barrier();

  f32x4 acc[MFR][NFR] = {};
  int cur = 0;
  for (int t = 0; t < nt; ++t) {
    const char* Ab = sm + cur * BUFB;
    const char* Bb = Ab + ABYTES;
    bf16x8 af[MFR], bf[NFR];
#pragma unroll
    for (int i = 0; i < MFR; ++i)
      af[i] = ldsfragT(Ab, wr * (BM / 2) + i * 16 + lr, lg);
#pragma unroll
    for (int i = 0; i < NFR; ++i)
      bf[i] = ldsfragT(Bb, wc * (BN / 2) + i * 16 + lr, lg);
    if (t + 3 < nt) stage((cur + 3) & 3);
    __builtin_amdgcn_s_setprio(1);
#pragma unroll
    for (int mi = 0; mi < MFR; ++mi)
#pragma unroll
      for (int nj = 0; nj < NFR; ++nj)
        acc[mi][nj] = mfma16x32(af[mi], bf[nj], acc[mi][nj]);
    __builtin_amdgcn_s_setprio(0);
    if (t + 1 < nt) {
      __builtin_amdgcn_sched_barrier(0);
      if (t + 3 < nt)      waitvm<2 * SL>();
      else if (t + 2 < nt) waitvm<SL>();
      else                 waitvm<0>();
      __builtin_amdgcn_s_barrier();
      __builtin_amdgcn_sched_barrier(0);
    }
    cur = (cur + 1) & 3;
  }

  if constexpr (EPI == EPI_QKV) {
    // qkv: BN=128; wave tile cols 64 = one head. which = col block /1024.
    const int which = n0 >> 10;
    const int hh = ((n0 & 1023) >> 6) + wc;
#pragma unroll
    for (int mi = 0; mi < MFR; ++mi) {
#pragma unroll
      for (int nj = 0; nj < NFR; ++nj) {
        const int d = nj * 16 + lr;
#pragma unroll
        for (int r = 0; r < 4; ++r) {
          const int row = m0 + wr * (BM / 2) + mi * 16 + lg * 4 + r;
          const float v = acc[mi][nj][r];
          if (which == 2) {
            VT[((size_t)hh * DHEAD + d) * NSEQ + row] = f2bf(v);
          } else {
            const float part = __shfl_xor(v, 1);
            const float sgn = (d & 1) ? 1.0f : -1.0f;
            const float c = ct[row * 32 + (d >> 1)];
            const float s_ = st[row * 32 + (d >> 1)];
            const u16 o = f2bf(v * c + sgn * part * s_);
            u16* dst = (which == 0) ? Qr : Kr;
            dst[((size_t)hh * NSEQ + row) * DHEAD + d] = o;
          }
        }
      }
    }
    return;
  }
#pragma unroll
  for (int mi = 0; mi < MFR; ++mi) {
#pragma unroll
    for (int nj = 0; nj < NFR; ++nj) {
      const int col = n0 + wc * (BN / 2) + nj * 16 + lr;
#pragma unroll
      for (int r = 0; r < 4; ++r) {
        const int row = m0 + wr * (BM / 2) + mi * 16 + lg * 4 + r;
        const size_t idx = (size_t)row * Nc + col;
        float v = acc[mi][nj][r];
        if (EPI == EPI_ATOM) {
          if (ksp == 0) v += bias[col];
          atomicAdd(&outf[idx], v);
        } else if (EPI == EPI_GELU) {
          v += bias[col];
          v = 0.5f * v * (1.0f + erff(v * 0.70710678118654752f));
          outb[idx] = f2bf(v);
        } else if (EPI == EPI_ADD) {
          outf[idx] = v + add[idx];
        } else if (EPI == EPI_BIAS_ADD) {
          outf[idx] = v + bias[col] + add[idx];
        } else {
          outf[idx] = v;
        }
      }
    }
  }
}

// ---------------- k_gemmW: 128x256xBK32, wave tile 64x128 --------------------
// Tri-buffer 72KB (2 blk/CU); logits kernel. EPI_STORE uses NONTEMPORAL
// stores: the 256MB f32 output is never re-read, and keeping it out of L2
// preserves A/B panel residency (R12: 100MB of excess FETCH from pollution).
template <int EPI>
__global__ __launch_bounds__(256, 2) void k_gemmW(
    const u16* __restrict__ A, const u16* __restrict__ BT, int K, int Nc,
    const float* __restrict__ bias, float* __restrict__ outf,
    u16* __restrict__ outb) {
  constexpr int ABYTES = 8192;            // 128 rows x 32 k x 2B
  constexpr int BUFB = ABYTES + 16384;    // + 256 rows B
  __shared__ alignas(16) char sm[3 * BUFB];
  const int nt = K >> 5;
  const int NMB = 16;
  const int nwg = gridDim.x;
  int swz = blockIdx.x;
  if ((nwg & 7) == 0) swz = (swz & 7) * (nwg >> 3) + (swz >> 3);
  const int mb = swz % NMB, nb = swz / NMB;
  const int m0 = mb * 128, n0 = nb * 256;

  const int tid = threadIdx.x, w = tid >> 6, lane = tid & 63;
  const int wr = w >> 1, wc = w & 1;      // wave tile 64 x 128
  const int lr = lane & 15, lg = lane >> 4;

  const int srow = tid >> 2;
  const int gslot = (tid & 3) ^ (srow & 3) ^ ((srow >> 2) & 3);
  const u16* ga0 = A + (size_t)(m0 + srow) * K + gslot * 8;
  const u16* ga1 = A + (size_t)(m0 + 64 + srow) * K + gslot * 8;
  const u16* gb0 = BT + (size_t)(n0 + srow) * K + gslot * 8;
  const u16* gb1 = BT + (size_t)(n0 + 64 + srow) * K + gslot * 8;
  const u16* gb2 = BT + (size_t)(n0 + 128 + srow) * K + gslot * 8;
  const u16* gb3 = BT + (size_t)(n0 + 192 + srow) * K + gslot * 8;
  const int ldOff = tid * 16;

  auto stage = [&](int b) {
    char* base = sm + b * BUFB;
    gload16(ga0, base + ldOff);
    gload16(ga1, base + 4096 + ldOff);
    gload16(gb0, base + ABYTES + ldOff);
    gload16(gb1, base + ABYTES + 4096 + ldOff);
    gload16(gb2, base + ABYTES + 8192 + ldOff);
    gload16(gb3, base + ABYTES + 12288 + ldOff);
    ga0 += 32; ga1 += 32; gb0 += 32; gb1 += 32; gb2 += 32; gb3 += 32;
  };

  stage(0);
  stage(1);
  waitvm<6>();
  __builtin_amdgcn_s_barrier();

  f32x4 acc[4][8] = {};
  int cur = 0, nx2 = 2;
  for (int t = 0; t < nt; ++t) {
    const char* Ab = sm + cur * BUFB;
    const char* Bb = Ab + ABYTES;
    const bool pf = (t + 2 < nt);
    bf16x8 af[4], bf[8];
#pragma unroll
    for (int i = 0; i < 4; ++i)
      af[i] = ldsfragT(Ab, wr * 64 + i * 16 + lr, lg);
#pragma unroll
    for (int i = 0; i < 8; ++i)
      bf[i] = ldsfragT(Bb, wc * 128 + i * 16 + lr, lg);
    if (pf) stage(nx2);
    __builtin_amdgcn_s_setprio(1);
#pragma unroll
    for (int mi = 0; mi < 4; ++mi)
#pragma unroll
      for (int nj = 0; nj < 8; ++nj)
        acc[mi][nj] = mfma16x32(af[mi], bf[nj], acc[mi][nj]);
    __builtin_amdgcn_s_setprio(0);
    if (t + 1 < nt) {
      __builtin_amdgcn_sched_barrier(0);
      if (pf) waitvm<6>();
      else    waitvm<0>();
      __builtin_amdgcn_s_barrier();
      __builtin_amdgcn_sched_barrier(0);
    }
    cur = (cur == 2) ? 0 : cur + 1;
    nx2 = (nx2 == 2) ? 0 : nx2 + 1;
  }

#pragma unroll
  for (int mi = 0; mi < 4; ++mi) {
#pragma unroll
    for (int nj = 0; nj < 8; ++nj) {
      const int col = n0 + wc * 128 + nj * 16 + lr;
#pragma unroll
      for (int r = 0; r < 4; ++r) {
        const int row = m0 + wr * 64 + mi * 16 + lg * 4 + r;
        const size_t idx = (size_t)row * Nc + col;
        float v = acc[mi][nj][r];
        if (EPI == EPI_GELU) {
          v += bias[col];
          v = 0.5f * v * (1.0f + erff(v * 0.70710678118654752f));
          outb[idx] = f2bf(v);
        } else {
          __builtin_nontemporal_store(v, &outf[idx]);
        }
      }
    }
  }
}

// ---------------------------------------------------------------- attention
// 512 blocks; id and id+256 (same CU under round-robin) get COMPLEMENTARY
// causal weights (qb, 31-qb) -> uniform per-CU work. Next-iteration K/V
// register prefetch hides L2 latency.
__global__ __launch_bounds__(256) void k_attn(const u16* __restrict__ Qr,
                                              const u16* __restrict__ Kr,
                                              const u16* __restrict__ VT,
                                              u16* __restrict__ O) {
  __shared__ alignas(16) u16 Pl[4][16 * 32];
  const int id = blockIdx.x;
  int qb, hh;
  if (id < 256) { qb = id & 31; hh = id >> 5; }
  else          { qb = 31 - (id & 31); hh = 8 + ((id - 256) >> 5); }
  const int w = threadIdx.x >> 6, lane = threadIdx.x & 63;
  const int lr = lane & 15, lg = lane >> 4;
  const int q0 = qb * 64 + w * 16;
  const u16* Qh = Qr + (size_t)hh * NSEQ * DHEAD;
  const u16* Kh = Kr + (size_t)hh * NSEQ * DHEAD;
  const u16* Vh = VT + (size_t)hh * DHEAD * NSEQ;
  u16* Pw = Pl[w];

  const bf16x8 aq0 = *reinterpret_cast<const bf16x8*>(Qh + (q0 + lr) * DHEAD + lg * 8);
  const bf16x8 aq1 = *reinterpret_cast<const bf16x8*>(Qh + (q0 + lr) * DHEAD + 32 + lg * 8);

  f32x4 o0 = {}, o1 = {}, o2 = {}, o3 = {};
  float m[4], l[4];
#pragma unroll
  for (int r = 0; r < 4; ++r) { m[r] = -1e30f; l[r] = 0.0f; }

  const int jend = q0 + 15;

  auto loadK = [&](int j0, bf16x8* bk) {
    bk[0] = *reinterpret_cast<const bf16x8*>(Kh + (j0 + lr) * DHEAD + lg * 8);
    bk[1] = *reinterpret_cast<const bf16x8*>(Kh + (j0 + lr) * DHEAD + 32 + lg * 8);
    bk[2] = *reinterpret_cast<const bf16x8*>(Kh + (j0 + 16 + lr) * DHEAD + lg * 8);
    bk[3] = *reinterpret_cast<const bf16x8*>(Kh + (j0 + 16 + lr) * DHEAD + 32 + lg * 8);
  };
  auto loadV = [&](int j0, bf16x8* vv) {
    const u16* vb = Vh + j0 + lg * 8;
    vv[0] = *reinterpret_cast<const bf16x8*>(vb + (0 + lr) * NSEQ);
    vv[1] = *reinterpret_cast<const bf16x8*>(vb + (16 + lr) * NSEQ);
    vv[2] = *reinterpret_cast<const bf16x8*>(vb + (32 + lr) * NSEQ);
    vv[3] = *reinterpret_cast<const bf16x8*>(vb + (48 + lr) * NSEQ);
  };

  bf16x8 bk[4], vv[4], bkN[4], vvN[4];
  loadK(0, bk);
  loadV(0, vv);

  for (int j0 = 0; j0 <= jend; j0 += 32) {
    if (j0 + 32 <= jend) { loadK(j0 + 32, bkN); loadV(j0 + 32, vvN); }

    f32x4 s0 = {}, s1 = {};
    s0 = mfma16x32(aq0, bk[0], s0);
    s0 = mfma16x32(aq1, bk[1], s0);
    s1 = mfma16x32(aq0, bk[2], s1);
    s1 = mfma16x32(aq1, bk[3], s1);

    float sv0[4], sv1[4], pm[4];
#pragma unroll
    for (int r = 0; r < 4; ++r) {
      const int irow = q0 + lg * 4 + r;
      sv0[r] = (j0 + lr > irow) ? -1e30f : s0[r] * 0.125f;
      sv1[r] = (j0 + 16 + lr > irow) ? -1e30f : s1[r] * 0.125f;
      pm[r] = fmaxf(sv0[r], sv1[r]);
    }
#pragma unroll
    for (int off = 1; off < 16; off <<= 1)
#pragma unroll
      for (int r = 0; r < 4; ++r) pm[r] = fmaxf(pm[r], __shfl_xor(pm[r], off));
    float p0[4], p1[4], rs[4];
    f32x4 fv;
#pragma unroll
    for (int r = 0; r < 4; ++r) {
      const float mn = fmaxf(m[r], pm[r]);
      fv[r] = __expf(m[r] - mn);
      m[r] = mn;
      p0[r] = __expf(sv0[r] - mn);
      p1[r] = __expf(sv1[r] - mn);
      rs[r] = p0[r] + p1[r];
    }
#pragma unroll
    for (int off = 1; off < 16; off <<= 1)
#pragma unroll
      for (int r = 0; r < 4; ++r) rs[r] += __shfl_xor(rs[r], off);
#pragma unroll
    for (int r = 0; r < 4; ++r) l[r] = l[r] * fv[r] + rs[r];
    o0 *= fv; o1 *= fv; o2 *= fv; o3 *= fv;

#pragma unroll
    for (int r = 0; r < 4; ++r) {
      Pw[(lg * 4 + r) * 32 + lr] = f2bf(p0[r]);
      Pw[(lg * 4 + r) * 32 + 16 + lr] = f2bf(p1[r]);
    }
    const bf16x8 pa = *reinterpret_cast<const bf16x8*>(Pw + lr * 32 + lg * 8);
    o0 = mfma16x32(pa, vv[0], o0);
    o1 = mfma16x32(pa, vv[1], o1);
    o2 = mfma16x32(pa, vv[2], o2);
    o3 = mfma16x32(pa, vv[3], o3);

#pragma unroll
    for (int i = 0; i < 4; ++i) { bk[i] = bkN[i]; vv[i] = vvN[i]; }
  }

#pragma unroll
  for (int r = 0; r < 4; ++r) {
    const int row = q0 + lg * 4 + r;
    const float invl = 1.0f / l[r];
    u16* orow = O + (size_t)row * DMODEL + hh * DHEAD;
    orow[0 * 16 + lr] = f2bf(o0[r] * invl);
    orow[1 * 16 + lr] = f2bf(o1[r] * invl);
    orow[2 * 16 + lr] = f2bf(o2[r] * invl);
    orow[3 * 16 + lr] = f2bf(o3[r] * invl);
  }
}

// ---------------------------------------------------------------- launch

extern "C" void kernel_launch(void* const* d_in, const int* in_sizes, int n_in,
                              void* d_out, int out_size, void* d_ws, size_t ws_size,
                              hipStream_t stream) {
  (void)in_sizes; (void)n_in;
  const int* x = (const int*)d_in[0];
  const float* emb = (const float*)d_in[1];
  const float* attn_gamma = (const float*)d_in[2];
  const float* w_qkv = (const float*)d_in[3];
  const float* w_attn_out = (const float*)d_in[4];
  const float* ff_gamma = (const float*)d_in[5];
  const float* w_ff1 = (const float*)d_in[6];
  const float* b_ff1 = (const float*)d_in[7];
  const float* w_ff2 = (const float*)d_in[8];
  const float* b_ff2 = (const float*)d_in[9];
  const float* final_gamma = (const float*)d_in[10];
  const float* w_logits = (const float*)d_in[11];
  float* out = (float*)d_out;

  const size_t EARLY_NEED = 176ull << 20;
  const size_t FINAL_NEED = 72ull << 20;
  char* earlyBase;
  char* finalBase;
  if (ws_size >= EARLY_NEED + FINAL_NEED) {
    earlyBase = (char*)d_ws;
    finalBase = (char*)d_ws + EARLY_NEED;
  } else if (ws_size >= FINAL_NEED && (size_t)out_size * 4 >= EARLY_NEED) {
    earlyBase = (char*)d_out;
    finalBase = (char*)d_ws;
  } else {
    return;
  }
  size_t eoff = 0, foff = 0;
  auto ealloc = [&](size_t b) { void* p = earlyBase + eoff; eoff += (b + 255) & ~(size_t)255; return p; };
  auto falloc = [&](size_t b) { void* p = finalBase + foff; foff += (b + 255) & ~(size_t)255; return p; };

  u16* wqkvT = (u16*)ealloc((size_t)NLAYER * 3072 * DMODEL * 2);
  u16* wattnT = (u16*)ealloc((size_t)NLAYER * DMODEL * DMODEL * 2);
  u16* wff1T = (u16*)ealloc((size_t)NLAYER * FFD * DMODEL * 2);
  u16* wff2T = (u16*)ealloc((size_t)NLAYER * DMODEL * FFD * 2);
  float* h = (float*)ealloc((size_t)NSEQ * DMODEL * 4);
  u16* Qr = (u16*)ealloc((size_t)NH * NSEQ * DHEAD * 2);
  u16* Kr = (u16*)ealloc((size_t)NH * NSEQ * DHEAD * 2);
  u16* VTb = (u16*)ealloc((size_t)NH * NSEQ * DHEAD * 2);
  u16* Ob = (u16*)ealloc((size_t)NSEQ * DMODEL * 2);
  u16* ff1b = (u16*)ealloc((size_t)NSEQ * FFD * 2);
  float* ct = (float*)ealloc((size_t)NSEQ * 32 * 4);
  float* st = (float*)ealloc((size_t)NSEQ * 32 * 4);
  u16* wlogT = (u16*)falloc((size_t)VOC * DMODEL * 2);
  u16* xn = (u16*)falloc((size_t)NSEQ * DMODEL * 2);

  k_rope<<<dim3(NSEQ), dim3(32), 0, stream>>>(ct, st);
  k_transpose<<<dim3(16, 48, NLAYER), 256, 0, stream>>>(
      w_qkv, wqkvT, DMODEL, 3072, (size_t)DMODEL * 3072, (size_t)3072 * DMODEL);
  k_transpose<<<dim3(16, 16, NLAYER), 256, 0, stream>>>(
      w_attn_out, wattnT, DMODEL, DMODEL, (size_t)DMODEL * DMODEL, (size_t)DMODEL * DMODEL);
  k_transpose<<<dim3(16, 64, NLAYER), 256, 0, stream>>>(
      w_ff1, wff1T, DMODEL, FFD, (size_t)DMODEL * FFD, (size_t)FFD * DMODEL);
  k_transpose<<<dim3(64, 16, NLAYER), 256, 0, stream>>>(
      w_ff2, wff2T, FFD, DMODEL, (size_t)FFD * DMODEL, (size_t)DMODEL * FFD);
  k_transpose<<<dim3(16, 500, 1), 256, 0, stream>>>(
      w_logits, wlogT, DMODEL, VOC, 0, 0);

  k_embed<<<dim3(NSEQ), 256, 0, stream>>>(x, emb, h);

  for (int lyr = 0; lyr < NLAYER; ++lyr) {
    k_rmsnorm<<<dim3(NSEQ), 256, 0, stream>>>(h, attn_gamma + (size_t)lyr * DMODEL, xn);
    k_gemmT<EPI_QKV, 64, 128, 1><<<dim3(32 * 24), 256, 0, stream>>>(
        xn, wqkvT + (size_t)lyr * 3072 * DMODEL, DMODEL, 3072, 32,
        nullptr, nullptr, nullptr, nullptr, Qr, Kr, VTb, ct, st);
    k_attn<<<dim3(512), 256, 0, stream>>>(Qr, Kr, VTb, Ob);
    k_gemmT<EPI_ADD, 64, 64, 1><<<dim3(32 * 16), 256, 0, stream>>>(
        Ob, wattnT + (size_t)lyr * DMODEL * DMODEL, DMODEL, DMODEL, 32,
        nullptr, h, h, nullptr, nullptr, nullptr, nullptr, nullptr, nullptr);
    k_rmsnorm<<<dim3(NSEQ), 256, 0, stream>>>(h, ff_gamma + (size_t)lyr * DMODEL, xn);
    k_gemmT<EPI_GELU, 64, 128, 1><<<dim3(32 * 32), 256, 0, stream>>>(
        xn, wff1T + (size_t)lyr * FFD * DMODEL, DMODEL, FFD, 32,
        b_ff1 + (size_t)lyr * FFD, nullptr, nullptr, ff1b,
        nullptr, nullptr, nullptr, nullptr, nullptr);
    // ff2 split-K=2: each half does K=2048 (lda=4096); reduction via
    // atomicAdd into h (h already holds the residual; ks=0 adds bias).
    k_gemmT<EPI_ATOM, 64, 64, 2><<<dim3(32 * 16 * 2), 256, 0, stream>>>(
        ff1b, wff2T + (size_t)lyr * DMODEL * FFD, FFD / 2, DMODEL, 32,
        b_ff2 + (size_t)lyr * DMODEL, nullptr, h, nullptr,
        nullptr, nullptr, nullptr, nullptr, nullptr);
  }

  k_rmsnorm<<<dim3(NSEQ), 256, 0, stream>>>(h, final_gamma, xn);
  k_gemmW<EPI_STORE><<<dim3(16 * 125), 256, 0, stream>>>(
      xn, wlogT, DMODEL, VOC, nullptr, out, nullptr);
}